// Round 6
// baseline (3966.789 us; speedup 1.0000x reference)
//
#include <hip/hip_runtime.h>
#include <hip/hip_bf16.h>

#define HW 64
#define L4 4096
#define CC 56
#define DI 112
#define DSN 16
#define NBLK 10

typedef const float* BP;

__device__ __forceinline__ float bf(BP p, int i) { return p[i]; }
__device__ __forceinline__ float siluf(float x) { return x / (1.f + __expf(-x)); }
__device__ __forceinline__ float geluf(float x) { return 0.5f * x * (1.f + erff(x * 0.70710678f)); }
__device__ __forceinline__ float softplusf(float x) { return fmaxf(x, 0.f) + log1pf(__expf(-fabsf(x))); }

// ---- stem: pointwise 3->56 ----
__global__ void k_fea_pw(BP x, BP w, float* __restrict__ t0) {
    int tid = blockIdx.x * blockDim.x + threadIdx.x;
    if (tid >= CC * L4) return;
    int c = tid >> 12, l = tid & 4095;
    float acc = 0.f;
    for (int i = 0; i < 3; ++i) acc += bf(x, i * L4 + l) * bf(w, c * 3 + i);
    t0[tid] = acc;
}

// ---- tiled depthwise 3x3 for 64x64 maps: grid = nch*16, block 256 (16x16 px) ----
__global__ void __launch_bounds__(256) k_dw3x3t(
        const float* __restrict__ src, BP w, BP bvec, float* __restrict__ dst,
        int act, const float* __restrict__ addsrc) {
    int c = blockIdx.x >> 4;
    int tile = blockIdx.x & 15;
    int y0 = (tile >> 2) * 16, x0 = (tile & 3) * 16;
    __shared__ float sT[18 * 18];
    const float* sc = src + (size_t)c * L4;
    for (int idx = threadIdx.x; idx < 324; idx += 256) {
        int iy = idx / 18, ix = idx - iy * 18;
        int gy = y0 - 1 + iy, gx = x0 - 1 + ix;
        sT[idx] = (gy >= 0 && gy < 64 && gx >= 0 && gx < 64) ? sc[gy * 64 + gx] : 0.f;
    }
    __syncthreads();
    int py = threadIdx.x >> 4, px = threadIdx.x & 15;
    BP wr = w + c * 9;
    float acc = bvec ? bvec[c] : 0.f;
    #pragma unroll
    for (int ky = 0; ky < 3; ++ky)
        #pragma unroll
        for (int kx = 0; kx < 3; ++kx)
            acc += sT[(py + ky) * 18 + px + kx] * wr[ky * 3 + kx];
    if (act) acc = siluf(acc);
    int l = (y0 + py) * 64 + x0 + px;
    if (addsrc) acc += addsrc[(size_t)c * L4 + l];
    dst[(size_t)c * L4 + l] = acc;
}

// ---- per-pixel layernorm over channels ([c][l] layout), optional gelu ----
__global__ void k_ln_pix(const float* __restrict__ src, BP w, BP b, float* __restrict__ dst,
                         int nch, float eps, int gelu_after) {
    int l = blockIdx.x * blockDim.x + threadIdx.x;
    if (l >= L4) return;
    float s = 0.f, s2 = 0.f;
    for (int c = 0; c < nch; ++c) { float v = src[c * L4 + l]; s += v; s2 += v * v; }
    float mu = s / nch;
    float var = fmaxf(s2 / nch - mu * mu, 0.f);
    float rstd = rsqrtf(var + eps);
    for (int c = 0; c < nch; ++c) {
        float v = (src[c * L4 + l] - mu) * rstd * bf(w, c) + bf(b, c);
        if (gelu_after) v = geluf(v);
        dst[c * L4 + l] = v;
    }
}

// ---- LDS-staged channel GEMM (generic; nin % 56 == 0) ----
__global__ void __launch_bounds__(256) k_gemm(
        const float* __restrict__ src, BP w, BP bvec, const float* __restrict__ addsrc,
        float* __restrict__ dst, int nin, int nout, int out_mode) {
    int lane = threadIdx.x & 63;
    int jg = threadIdx.x >> 6;
    int l0 = blockIdx.x * 64;
    int j0 = blockIdx.y * 16;
    __shared__ __align__(16) float sS[56 * 64];
    __shared__ __align__(16) float sw[16 * 56];
    float acc[4] = {0.f, 0.f, 0.f, 0.f};

    for (int i0 = 0; i0 < nin; i0 += 56) {
        __syncthreads();
        for (int idx = threadIdx.x; idx < 56 * 64; idx += 256) {
            int ii = idx >> 6, px = idx & 63;
            sS[idx] = src[(size_t)(i0 + ii) * L4 + l0 + px];
        }
        for (int idx = threadIdx.x; idx < 16 * 56; idx += 256) {
            int jj = idx / 56, ii = idx - jj * 56;
            int j = j0 + jj;
            sw[idx] = (j < nout) ? w[(size_t)j * nin + i0 + ii] : 0.f;
        }
        __syncthreads();
        #pragma unroll
        for (int ii = 0; ii < 56; ii += 4) {
            float s0 = sS[(ii + 0) * 64 + lane];
            float s1 = sS[(ii + 1) * 64 + lane];
            float s2 = sS[(ii + 2) * 64 + lane];
            float s3 = sS[(ii + 3) * 64 + lane];
            #pragma unroll
            for (int jj = 0; jj < 4; ++jj) {
                const float4 wv = *(const float4*)&sw[(jg * 4 + jj) * 56 + ii];
                acc[jj] += s0 * wv.x + s1 * wv.y + s2 * wv.z + s3 * wv.w;
            }
        }
    }
    int l = l0 + lane;
    #pragma unroll
    for (int jj = 0; jj < 4; ++jj) {
        int j = j0 + jg * 4 + jj;
        if (j >= nout) continue;
        float v = acc[jj];
        if (bvec) v += bf(bvec, j);
        if (out_mode == 0) {
            size_t idx = (size_t)j * L4 + l;
            if (addsrc) v += addsrc[idx];
            dst[idx] = v;
        } else {
            int k = j / 36, c = j - k * 36;
            dst[((size_t)k * L4 + l) * 36 + c] = v;
        }
    }
}

// ---- in-proj GEMM with fused LN (nin = 56, single K chunk) ----
__global__ void __launch_bounds__(256) k_gemm_ln(
        const float* __restrict__ src, BP lnw, BP lnb, BP w,
        float* __restrict__ dst, int nout) {
    int lane = threadIdx.x & 63;
    int jg = threadIdx.x >> 6;
    int l0 = blockIdx.x * 64;
    int j0 = blockIdx.y * 16;
    __shared__ __align__(16) float sS[56 * 64];
    __shared__ __align__(16) float sw[16 * 56];
    __shared__ float sLw[56], sLb[56];
    float acc[4] = {0.f, 0.f, 0.f, 0.f};

    for (int idx = threadIdx.x; idx < 56 * 64; idx += 256) {
        int ii = idx >> 6, px = idx & 63;
        sS[idx] = src[(size_t)ii * L4 + l0 + px];
    }
    for (int idx = threadIdx.x; idx < 16 * 56; idx += 256) {
        int jj = idx / 56, ii = idx - jj * 56;
        int j = j0 + jj;
        sw[idx] = (j < nout) ? w[(size_t)j * 56 + ii] : 0.f;
    }
    if (threadIdx.x < 56) { sLw[threadIdx.x] = lnw[threadIdx.x]; sLb[threadIdx.x] = lnb[threadIdx.x]; }
    __syncthreads();
    if (threadIdx.x < 64) {
        int px = threadIdx.x;
        float s = 0.f, s2 = 0.f;
        for (int ii = 0; ii < 56; ++ii) { float v = sS[ii * 64 + px]; s += v; s2 += v * v; }
        float mu = s / 56.f;
        float var = fmaxf(s2 / 56.f - mu * mu, 0.f);
        float rstd = rsqrtf(var + 1e-5f);
        for (int ii = 0; ii < 56; ++ii)
            sS[ii * 64 + px] = (sS[ii * 64 + px] - mu) * rstd * sLw[ii] + sLb[ii];
    }
    __syncthreads();
    #pragma unroll
    for (int ii = 0; ii < 56; ii += 4) {
        float s0 = sS[(ii + 0) * 64 + lane];
        float s1 = sS[(ii + 1) * 64 + lane];
        float s2 = sS[(ii + 2) * 64 + lane];
        float s3 = sS[(ii + 3) * 64 + lane];
        #pragma unroll
        for (int jj = 0; jj < 4; ++jj) {
            const float4 wv = *(const float4*)&sw[(jg * 4 + jj) * 56 + ii];
            acc[jj] += s0 * wv.x + s1 * wv.y + s2 * wv.z + s3 * wv.w;
        }
    }
    int l = l0 + lane;
    #pragma unroll
    for (int jj = 0; jj < 4; ++jj) {
        int j = j0 + jg * 4 + jj;
        if (j < nout) dst[(size_t)j * L4 + l] = acc[jj];
    }
}

// ---- chunked selective scan with fused delta: one block per (k,d) pair ----
__global__ void __launch_bounds__(1024) k_scan(
        const float* __restrict__ xc, const float* __restrict__ pk,
        BP Alog, BP dtw, BP dtb, float* __restrict__ ybuf) {
    int pair = blockIdx.x;           // k*112+d
    int n = threadIdx.x & 15;        // state index
    int c = threadIdx.x >> 4;        // chunk index, 0..63
    int k = pair / DI, d = pair - k * DI;
    float a = -__expf(Alog[pair * DSN + n]);
    float w0 = dtw[pair * 4 + 0], w1 = dtw[pair * 4 + 1];
    float w2 = dtw[pair * 4 + 2], w3 = dtw[pair * 4 + 3];
    float db = dtb[pair];
    const float* xptr = xc + (size_t)d * L4;
    const float* pkk = pk + (size_t)k * L4 * 36;
    float* yptr = ybuf + (size_t)pair * L4;

    __shared__ float sP[64 * 16];
    __shared__ float sHe[64 * 16];
    __shared__ float sCar[64 * 16];

    float h = 0.f, P = 1.f;
    int t0 = c * 64;
    for (int j = 0; j < 64; ++j) {
        int t = t0 + j;
        int tt = (k >= 2) ? (4095 - t) : t;
        int p = (k & 1) ? (((tt & 63) << 6) | (tt >> 6)) : tt;
        const float* row = pkk + (size_t)p * 36;
        float dl = softplusf(db + row[0] * w0 + row[1] * w1 + row[2] * w2 + row[3] * w3);
        float xl = xptr[p];
        float Bn = row[4 + n];
        float e = __expf(dl * a);
        h = e * h + dl * xl * Bn;
        P *= e;
    }
    sP[c * 16 + n] = P;
    sHe[c * 16 + n] = h;
    __syncthreads();

    if (threadIdx.x < 16) {
        float H = 0.f;
        for (int cc = 0; cc < 64; ++cc) {
            sCar[cc * 16 + n] = H;
            H = sP[cc * 16 + n] * H + sHe[cc * 16 + n];
        }
    }
    __syncthreads();

    h = sCar[c * 16 + n];
    for (int j = 0; j < 64; ++j) {
        int t = t0 + j;
        int tt = (k >= 2) ? (4095 - t) : t;
        int p = (k & 1) ? (((tt & 63) << 6) | (tt >> 6)) : tt;
        const float* row = pkk + (size_t)p * 36;
        float dl = softplusf(db + row[0] * w0 + row[1] * w1 + row[2] * w2 + row[3] * w3);
        float xl = xptr[p];
        float Bn = row[4 + n];
        float Cn = row[20 + n];
        float e = __expf(dl * a);
        h = e * h + dl * xl * Bn;
        float y = h * Cn;
        y += __shfl_xor(y, 1, 16);
        y += __shfl_xor(y, 2, 16);
        y += __shfl_xor(y, 4, 16);
        y += __shfl_xor(y, 8, 16);
        if (n == 0) yptr[p] = y;
    }
}

// ---- combine 4 directions + D*x, LN(112, eps 1e-5, onorm), gate with silu(z) ----
__global__ void k_combine(const float* __restrict__ ybuf, const float* __restrict__ xc,
                          const float* __restrict__ zbuf, BP Dp, BP ow, BP ob,
                          float* __restrict__ gbuf) {
    int l = blockIdx.x * blockDim.x + threadIdx.x;
    if (l >= L4) return;
    float s = 0.f, s2 = 0.f;
    for (int d = 0; d < DI; ++d) {
        float Ds = bf(Dp, d) + bf(Dp, DI + d) + bf(Dp, 2 * DI + d) + bf(Dp, 3 * DI + d);
        float yv = ybuf[d * L4 + l] + ybuf[(DI + d) * L4 + l] + ybuf[(2 * DI + d) * L4 + l]
                 + ybuf[(3 * DI + d) * L4 + l] + Ds * xc[d * L4 + l];
        gbuf[d * L4 + l] = yv; s += yv; s2 += yv * yv;
    }
    float mu = s / DI;
    float var = fmaxf(s2 / DI - mu * mu, 0.f);
    float rstd = rsqrtf(var + 1e-5f);
    for (int d = 0; d < DI; ++d) {
        float v = (gbuf[d * L4 + l] - mu) * rstd * bf(ow, d) + bf(ob, d);
        gbuf[d * L4 + l] = v * siluf(zbuf[d * L4 + l]);
    }
}

// ---- SAFM pools (scales 2,4,8) ----
__global__ void k_pools(const float* __restrict__ xln, float* __restrict__ p1,
                        float* __restrict__ p2, float* __restrict__ p3) {
    int tid = blockIdx.x * blockDim.x + threadIdx.x;
    int f, S, idx, chbase; float* dst;
    if (tid < 14336)      { f = 2; S = 32; idx = tid;          chbase = 14; dst = p1; }
    else if (tid < 17920) { f = 4; S = 16; idx = tid - 14336;  chbase = 28; dst = p2; }
    else if (tid < 18816) { f = 8; S = 8;  idx = tid - 17920;  chbase = 42; dst = p3; }
    else return;
    int c = idx / (S * S); int rem = idx - c * S * S; int y = rem / S, x = rem - y * S;
    float m = -3.4e38f;
    for (int dy = 0; dy < f; ++dy)
        for (int dx = 0; dx < f; ++dx) {
            float v = xln[(chbase + c) * L4 + (y * f + dy) * HW + (x * f + dx)];
            m = fmaxf(m, v);
        }
    dst[idx] = m;
}

// ---- SAFM depthwise convs at 4 scales (fused) ----
__global__ void k_mfr(const float* __restrict__ xln, const float* __restrict__ p1,
                      const float* __restrict__ p2, const float* __restrict__ p3,
                      BP mw, BP mb, float* __restrict__ s0, float* __restrict__ s1,
                      float* __restrict__ s2, float* __restrict__ s3) {
    int tid = blockIdx.x * blockDim.x + threadIdx.x;
    int S, i, idx; const float* src; float* dst;
    if (tid < 57344)      { S = 64; i = 0; idx = tid;          src = xln; dst = s0; }
    else if (tid < 71680) { S = 32; i = 1; idx = tid - 57344;  src = p1;  dst = s1; }
    else if (tid < 75264) { S = 16; i = 2; idx = tid - 71680;  src = p2;  dst = s2; }
    else if (tid < 76160) { S = 8;  i = 3; idx = tid - 75264;  src = p3;  dst = s3; }
    else return;
    int c = idx / (S * S); int rem = idx - c * S * S; int y = rem / S, x = rem - y * S;
    int srcstride = (i == 0) ? L4 : S * S;
    float acc = bf(mb, i * 14 + c);
    BP wr = mw + (i * 14 + c) * 9;
    const float* sc = src + c * srcstride;
    for (int ky = 0; ky < 3; ++ky) {
        int yy = y + ky - 1; if (yy < 0 || yy >= S) continue;
        for (int kx = 0; kx < 3; ++kx) {
            int xx = x + kx - 1; if (xx < 0 || xx >= S) continue;
            acc += sc[yy * S + xx] * bf(wr, ky * 3 + kx);
        }
    }
    dst[idx] = acc;
}

// ---- SAFM aggregate 1x1 + gelu gate + residual, writes trunk slice ----
__global__ void k_aggr(const float* __restrict__ s0, const float* __restrict__ s1,
                       const float* __restrict__ s2, const float* __restrict__ s3,
                       const float* __restrict__ xln, const float* __restrict__ x_mid,
                       BP aw, BP ab, float* __restrict__ out) {
    int tid = blockIdx.x * blockDim.x + threadIdx.x;
    if (tid >= CC * L4) return;
    int c = tid >> 12, l = tid & 4095;
    int h = l >> 6, w = l & 63;
    int o1 = (h >> 1) * 32 + (w >> 1);
    int o2 = (h >> 2) * 16 + (w >> 2);
    int o3 = (h >> 3) * 8 + (w >> 3);
    float acc = bf(ab, c);
    BP wr = aw + c * 56;
    for (int cg = 0; cg < 14; ++cg) acc += s0[cg * 4096 + l]  * bf(wr, cg);
    for (int cg = 0; cg < 14; ++cg) acc += s1[cg * 1024 + o1] * bf(wr, 14 + cg);
    for (int cg = 0; cg < 14; ++cg) acc += s2[cg * 256 + o2]  * bf(wr, 28 + cg);
    for (int cg = 0; cg < 14; ++cg) acc += s3[cg * 64 + o3]   * bf(wr, 42 + cg);
    out[tid] = x_mid[tid] + geluf(acc) * xln[tid];
}

// ---- up conv 3x3 (56->27) + pixel shuffle x3, LDS-staged, fp32 output ----
// grid = 256 (4x4 px tiles), block 256 = 16 px x 16 og (2 outputs each)
__global__ void __launch_bounds__(256) k_up(
        const float* __restrict__ out_lr, BP uw, BP ub, float* __restrict__ out) {
    __shared__ float sIn[56 * 36];       // [c][6x6 halo]
    __shared__ float sW[27 * 56 * 9];    // 54.4 KB
    int b = blockIdx.x;
    int y0 = (b >> 4) * 4, x0 = (b & 15) * 4;
    for (int idx = threadIdx.x; idx < 56 * 36; idx += 256) {
        int cc = idx / 36; int rem = idx - cc * 36; int iy = rem / 6, ix = rem - iy * 6;
        int gy = y0 - 1 + iy, gx = x0 - 1 + ix;
        sIn[idx] = (gy >= 0 && gy < 64 && gx >= 0 && gx < 64)
                 ? out_lr[(size_t)cc * L4 + gy * 64 + gx] : 0.f;
    }
    for (int idx = threadIdx.x; idx < 27 * 56 * 9; idx += 256) sW[idx] = uw[idx];
    __syncthreads();
    int px = threadIdx.x & 15;
    int og = threadIdx.x >> 4;
    int dy = px >> 2, dx = px & 3;
    for (int oo = 0; oo < 2; ++oo) {
        int o = og * 2 + oo;
        if (o >= 27) break;
        float acc = ub[o];
        const float* wb = &sW[o * 504];
        for (int cc = 0; cc < 56; ++cc) {
            const float* ib = &sIn[cc * 36 + dy * 6 + dx];
            const float* wc = wb + cc * 9;
            acc += ib[0] * wc[0] + ib[1] * wc[1] + ib[2] * wc[2]
                 + ib[6] * wc[3] + ib[7] * wc[4] + ib[8] * wc[5]
                 + ib[12] * wc[6] + ib[13] * wc[7] + ib[14] * wc[8];
        }
        int h = y0 + dy, wv = x0 + dx;
        int ch = o / 9, rr = (o % 9) / 3, ss = o % 3;
        out[ch * 36864 + (h * 3 + rr) * 192 + (wv * 3 + ss)] = acc;
    }
}

extern "C" void kernel_launch(void* const* d_in, const int* in_sizes, int n_in,
                              void* d_out, int out_size, void* d_ws, size_t ws_size,
                              hipStream_t stream) {
    BP in0  = (BP)d_in[0];
    BP in1  = (BP)d_in[1];
    BP in2  = (BP)d_in[2];
    BP in3  = (BP)d_in[3];
    BP in4  = (BP)d_in[4];
    BP in5  = (BP)d_in[5];
    BP in6  = (BP)d_in[6];
    BP in7  = (BP)d_in[7];
    BP in8  = (BP)d_in[8];
    BP in9  = (BP)d_in[9];
    BP in10 = (BP)d_in[10];
    BP in11 = (BP)d_in[11];
    BP in12 = (BP)d_in[12];
    BP in13 = (BP)d_in[13];
    BP in14 = (BP)d_in[14];
    BP in15 = (BP)d_in[15];
    BP in16 = (BP)d_in[16];
    BP in17 = (BP)d_in[17];
    BP in18 = (BP)d_in[18];
    BP in19 = (BP)d_in[19];
    BP in20 = (BP)d_in[20];
    BP in21 = (BP)d_in[21];
    BP in22 = (BP)d_in[22];
    BP in23 = (BP)d_in[23];
    BP in24 = (BP)d_in[24];
    BP in25 = (BP)d_in[25];
    BP in26 = (BP)d_in[26];
    BP in27 = (BP)d_in[27];
    BP in28 = (BP)d_in[28];
    BP in29 = (BP)d_in[29];
    BP in30 = (BP)d_in[30];
    BP in31 = (BP)d_in[31];

    float* ws = (float*)d_ws;
    float* trunk   = ws; ws += 560 * L4;
    float* out_fea = ws; ws += CC * L4;
    float* t0      = ws; ws += CC * L4;
    float* xz      = ws; ws += 224 * L4;
    float* xc      = ws; ws += DI * L4;
    float* pk      = ws; ws += 4 * 36 * L4;
    float* ybuf    = ws; ws += 4 * DI * L4;
    float* gbuf    = ws; ws += DI * L4;
    float* x_mid   = ws; ws += CC * L4;
    float* xln     = ws; ws += CC * L4;
    float* p1      = ws; ws += 14 * 1024;
    float* p2      = ws; ws += 14 * 256;
    float* p3      = ws; ws += 14 * 64;
    float* s0      = ws; ws += 14 * 4096;
    float* s1      = ws; ws += 14 * 1024;
    float* s2      = ws; ws += 14 * 256;
    float* s3      = ws; ws += 14 * 64;
    float* bufB    = ws; ws += CC * L4;
    float* gB      = ws; ws += CC * L4;
    float* tbuf    = ws; ws += CC * L4;
    float* out_lr  = ws; ws += CC * L4;

    auto nb256 = [](int n) { return dim3((n + 255) / 256); };
    auto gemm_grid = [](int nout) { return dim3(64, (nout + 15) / 16); };

    // stem
    k_fea_pw<<<nb256(CC * L4), 256, 0, stream>>>(in0, in1, t0);
    k_dw3x3t<<<dim3(CC * 16), 256, 0, stream>>>(t0, in2, in3, out_fea, 0, nullptr);

    for (int nb = 0; nb < NBLK; ++nb) {
        const float* xin = (nb == 0) ? out_fea : trunk + (size_t)(nb - 1) * CC * L4;
        float* xout = trunk + (size_t)nb * CC * L4;
        BP ln1w = in4 + nb * 56,        ln1b = in5 + nb * 56;
        BP ipw  = in6 + nb * 224 * 56;
        BP cw   = in7 + nb * 112 * 9,   cb   = in8 + nb * 112;
        BP xpw  = in9 + nb * 4 * 36 * 112;
        BP dtw  = in10 + nb * 4 * 112 * 4, dtb = in11 + nb * 448;
        BP alog = in12 + nb * 448 * 16, Dp   = in13 + nb * 448;
        BP onw  = in14 + nb * 112,      onb  = in15 + nb * 112;
        BP opw  = in16 + nb * 56 * 112;
        BP nw   = in17 + nb * 56,       nbv  = in18 + nb * 56;
        BP mw   = in19 + nb * 4 * 14 * 9, mb = in20 + nb * 56;
        BP aw   = in21 + nb * 56 * 56,  ab   = in22 + nb * 56;

        k_gemm_ln<<<gemm_grid(224), 256, 0, stream>>>(xin, ln1w, ln1b, ipw, xz, 224);
        k_dw3x3t<<<dim3(DI * 16), 256, 0, stream>>>(xz, cw, cb, xc, 1, nullptr);
        k_gemm<<<gemm_grid(144), 256, 0, stream>>>(xc, xpw, nullptr, nullptr, pk, 112, 144, 1);
        k_scan<<<dim3(4 * DI), 1024, 0, stream>>>(xc, pk, alog, dtw, dtb, ybuf);
        k_combine<<<nb256(L4), 256, 0, stream>>>(ybuf, xc, xz + 112 * L4, Dp, onw, onb, gbuf);
        k_gemm<<<gemm_grid(56), 256, 0, stream>>>(gbuf, opw, nullptr, xin, x_mid, 112, 56, 0);
        k_ln_pix<<<nb256(L4), 256, 0, stream>>>(x_mid, nw, nbv, xln, CC, 1e-6f, 0);
        k_pools<<<nb256(18816), 256, 0, stream>>>(xln, p1, p2, p3);
        k_mfr<<<nb256(76160), 256, 0, stream>>>(xln, p1, p2, p3, mw, mb, s0, s1, s2, s3);
        k_aggr<<<nb256(CC * L4), 256, 0, stream>>>(s0, s1, s2, s3, xln, x_mid, aw, ab, xout);
    }

    // tail
    k_gemm<<<gemm_grid(56), 256, 0, stream>>>(trunk, in23, in24, nullptr, bufB, 560, 56, 0);
    k_ln_pix<<<nb256(L4), 256, 0, stream>>>(bufB, in25, in26, gB, CC, 1e-6f, 1);
    k_gemm<<<gemm_grid(56), 256, 0, stream>>>(gB, in27, nullptr, nullptr, tbuf, 56, 56, 0);
    k_dw3x3t<<<dim3(CC * 16), 256, 0, stream>>>(tbuf, in28, in29, out_lr, 0, out_fea);
    k_up<<<dim3(256), 256, 0, stream>>>(out_lr, in30, in31, (float*)d_out);
}

// Round 7
// 2093.689 us; speedup vs baseline: 1.8946x; 1.8946x over previous
//
#include <hip/hip_runtime.h>
#include <hip/hip_bf16.h>

#define HW 64
#define L4 4096
#define CC 56
#define DI 112
#define DSN 16
#define NBLK 10

typedef const float* BP;

__device__ __forceinline__ float bf(BP p, int i) { return p[i]; }
__device__ __forceinline__ float siluf(float x) { return x / (1.f + __expf(-x)); }
__device__ __forceinline__ float geluf(float x) { return 0.5f * x * (1.f + erff(x * 0.70710678f)); }

// ---- stem: pointwise 3->56 ----
__global__ void k_fea_pw(BP x, BP w, float* __restrict__ t0) {
    int tid = blockIdx.x * blockDim.x + threadIdx.x;
    if (tid >= CC * L4) return;
    int c = tid >> 12, l = tid & 4095;
    float acc = 0.f;
    for (int i = 0; i < 3; ++i) acc += bf(x, i * L4 + l) * bf(w, c * 3 + i);
    t0[tid] = acc;
}

// ---- tiled depthwise 3x3 for 64x64 maps: grid = nch*16, block 256 (16x16 px) ----
__global__ void __launch_bounds__(256) k_dw3x3t(
        const float* __restrict__ src, BP w, BP bvec, float* __restrict__ dst,
        int act, const float* __restrict__ addsrc) {
    int c = blockIdx.x >> 4;
    int tile = blockIdx.x & 15;
    int y0 = (tile >> 2) * 16, x0 = (tile & 3) * 16;
    __shared__ float sT[18 * 18];
    const float* sc = src + (size_t)c * L4;
    for (int idx = threadIdx.x; idx < 324; idx += 256) {
        int iy = idx / 18, ix = idx - iy * 18;
        int gy = y0 - 1 + iy, gx = x0 - 1 + ix;
        sT[idx] = (gy >= 0 && gy < 64 && gx >= 0 && gx < 64) ? sc[gy * 64 + gx] : 0.f;
    }
    __syncthreads();
    int py = threadIdx.x >> 4, px = threadIdx.x & 15;
    BP wr = w + c * 9;
    float acc = bvec ? bvec[c] : 0.f;
    #pragma unroll
    for (int ky = 0; ky < 3; ++ky)
        #pragma unroll
        for (int kx = 0; kx < 3; ++kx)
            acc += sT[(py + ky) * 18 + px + kx] * wr[ky * 3 + kx];
    if (act) acc = siluf(acc);
    int l = (y0 + py) * 64 + x0 + px;
    if (addsrc) acc += addsrc[(size_t)c * L4 + l];
    dst[(size_t)c * L4 + l] = acc;
}

// ---- per-pixel layernorm over channels ([c][l] layout), optional gelu ----
__global__ void k_ln_pix(const float* __restrict__ src, BP w, BP b, float* __restrict__ dst,
                         int nch, float eps, int gelu_after) {
    int l = blockIdx.x * blockDim.x + threadIdx.x;
    if (l >= L4) return;
    float s = 0.f, s2 = 0.f;
    for (int c = 0; c < nch; ++c) { float v = src[c * L4 + l]; s += v; s2 += v * v; }
    float mu = s / nch;
    float var = fmaxf(s2 / nch - mu * mu, 0.f);
    float rstd = rsqrtf(var + eps);
    for (int c = 0; c < nch; ++c) {
        float v = (src[c * L4 + l] - mu) * rstd * bf(w, c) + bf(b, c);
        if (gelu_after) v = geluf(v);
        dst[c * L4 + l] = v;
    }
}

// ---- LDS-staged channel GEMM (generic; nin % 56 == 0) ----
__global__ void __launch_bounds__(256) k_gemm(
        const float* __restrict__ src, BP w, BP bvec, const float* __restrict__ addsrc,
        float* __restrict__ dst, int nin, int nout, int out_mode) {
    int lane = threadIdx.x & 63;
    int jg = threadIdx.x >> 6;
    int l0 = blockIdx.x * 64;
    int j0 = blockIdx.y * 16;
    __shared__ __align__(16) float sS[56 * 64];
    __shared__ __align__(16) float sw[16 * 56];
    float acc[4] = {0.f, 0.f, 0.f, 0.f};

    for (int i0 = 0; i0 < nin; i0 += 56) {
        __syncthreads();
        for (int idx = threadIdx.x; idx < 56 * 64; idx += 256) {
            int ii = idx >> 6, px = idx & 63;
            sS[idx] = src[(size_t)(i0 + ii) * L4 + l0 + px];
        }
        for (int idx = threadIdx.x; idx < 16 * 56; idx += 256) {
            int jj = idx / 56, ii = idx - jj * 56;
            int j = j0 + jj;
            sw[idx] = (j < nout) ? w[(size_t)j * nin + i0 + ii] : 0.f;
        }
        __syncthreads();
        #pragma unroll
        for (int ii = 0; ii < 56; ii += 4) {
            float s0 = sS[(ii + 0) * 64 + lane];
            float s1 = sS[(ii + 1) * 64 + lane];
            float s2 = sS[(ii + 2) * 64 + lane];
            float s3 = sS[(ii + 3) * 64 + lane];
            #pragma unroll
            for (int jj = 0; jj < 4; ++jj) {
                const float4 wv = *(const float4*)&sw[(jg * 4 + jj) * 56 + ii];
                acc[jj] += s0 * wv.x + s1 * wv.y + s2 * wv.z + s3 * wv.w;
            }
        }
    }
    int l = l0 + lane;
    #pragma unroll
    for (int jj = 0; jj < 4; ++jj) {
        int j = j0 + jg * 4 + jj;
        if (j >= nout) continue;
        float v = acc[jj];
        if (bvec) v += bf(bvec, j);
        if (out_mode == 0) {
            size_t idx = (size_t)j * L4 + l;
            if (addsrc) v += addsrc[idx];
            dst[idx] = v;
        } else {
            int k = j / 36, c = j - k * 36;
            dst[((size_t)k * L4 + l) * 36 + c] = v;
        }
    }
}

// ---- in-proj GEMM with fused LN (nin = 56, single K chunk) ----
__global__ void __launch_bounds__(256) k_gemm_ln(
        const float* __restrict__ src, BP lnw, BP lnb, BP w,
        float* __restrict__ dst, int nout) {
    int lane = threadIdx.x & 63;
    int jg = threadIdx.x >> 6;
    int l0 = blockIdx.x * 64;
    int j0 = blockIdx.y * 16;
    __shared__ __align__(16) float sS[56 * 64];
    __shared__ __align__(16) float sw[16 * 56];
    __shared__ float sLw[56], sLb[56];
    float acc[4] = {0.f, 0.f, 0.f, 0.f};

    for (int idx = threadIdx.x; idx < 56 * 64; idx += 256) {
        int ii = idx >> 6, px = idx & 63;
        sS[idx] = src[(size_t)ii * L4 + l0 + px];
    }
    for (int idx = threadIdx.x; idx < 16 * 56; idx += 256) {
        int jj = idx / 56, ii = idx - jj * 56;
        int j = j0 + jj;
        sw[idx] = (j < nout) ? w[(size_t)j * 56 + ii] : 0.f;
    }
    if (threadIdx.x < 56) { sLw[threadIdx.x] = lnw[threadIdx.x]; sLb[threadIdx.x] = lnb[threadIdx.x]; }
    __syncthreads();
    if (threadIdx.x < 64) {
        int px = threadIdx.x;
        float s = 0.f, s2 = 0.f;
        for (int ii = 0; ii < 56; ++ii) { float v = sS[ii * 64 + px]; s += v; s2 += v * v; }
        float mu = s / 56.f;
        float var = fmaxf(s2 / 56.f - mu * mu, 0.f);
        float rstd = rsqrtf(var + 1e-5f);
        for (int ii = 0; ii < 56; ++ii)
            sS[ii * 64 + px] = (sS[ii * 64 + px] - mu) * rstd * sLw[ii] + sLb[ii];
    }
    __syncthreads();
    #pragma unroll
    for (int ii = 0; ii < 56; ii += 4) {
        float s0 = sS[(ii + 0) * 64 + lane];
        float s1 = sS[(ii + 1) * 64 + lane];
        float s2 = sS[(ii + 2) * 64 + lane];
        float s3 = sS[(ii + 3) * 64 + lane];
        #pragma unroll
        for (int jj = 0; jj < 4; ++jj) {
            const float4 wv = *(const float4*)&sw[(jg * 4 + jj) * 56 + ii];
            acc[jj] += s0 * wv.x + s1 * wv.y + s2 * wv.z + s3 * wv.w;
        }
    }
    int l = l0 + lane;
    #pragma unroll
    for (int jj = 0; jj < 4; ++jj) {
        int j = j0 + jg * 4 + jj;
        if (j < nout) dst[(size_t)j * L4 + l] = acc[jj];
    }
}

// ---- chunked selective scan, delta computed ONCE cooperatively into LDS ----
__global__ void __launch_bounds__(1024) k_scan(
        const float* __restrict__ xc, const float* __restrict__ pk,
        BP Alog, BP dtw, BP dtb, float* __restrict__ ybuf) {
    int pair = blockIdx.x;           // k*112+d
    int n = threadIdx.x & 15;        // state index
    int c = threadIdx.x >> 4;        // chunk index, 0..63
    int k = pair / DI, d = pair - k * DI;
    float a = -__expf(Alog[pair * DSN + n]);
    float w0 = dtw[pair * 4 + 0], w1 = dtw[pair * 4 + 1];
    float w2 = dtw[pair * 4 + 2], w3 = dtw[pair * 4 + 3];
    float db = dtb[pair];
    const float* xptr = xc + (size_t)d * L4;
    const float* pkk = pk + (size_t)k * L4 * 36;
    float* yptr = ybuf + (size_t)pair * L4;

    __shared__ float sDl[L4];        // delta[p]
    __shared__ float sDlx[L4];       // delta[p] * x[p]
    __shared__ float sP[64 * 16];
    __shared__ float sHe[64 * 16];
    __shared__ float sCar[64 * 16];

    // phase 0: cooperative delta precompute (4 softplus per thread)
    for (int p = threadIdx.x; p < L4; p += 1024) {
        const float* row = pkk + (size_t)p * 36;
        float v = db + row[0] * w0 + row[1] * w1 + row[2] * w2 + row[3] * w3;
        float dl = fmaxf(v, 0.f) + __logf(1.f + __expf(-fabsf(v)));
        sDl[p] = dl;
        sDlx[p] = dl * xptr[p];
    }
    __syncthreads();

    // phase 1: local chunk scan from 0
    float h = 0.f, P = 1.f;
    int t0 = c * 64;
    for (int j = 0; j < 64; ++j) {
        int t = t0 + j;
        int tt = (k >= 2) ? (4095 - t) : t;
        int p = (k & 1) ? (((tt & 63) << 6) | (tt >> 6)) : tt;
        float Bn = pkk[(size_t)p * 36 + 4 + n];
        float e = __expf(sDl[p] * a);
        h = e * h + sDlx[p] * Bn;
        P *= e;
    }
    sP[c * 16 + n] = P;
    sHe[c * 16 + n] = h;
    __syncthreads();

    // phase 2: serial carry compose
    if (threadIdx.x < 16) {
        float H = 0.f;
        for (int cc = 0; cc < 64; ++cc) {
            sCar[cc * 16 + n] = H;
            H = sP[cc * 16 + n] * H + sHe[cc * 16 + n];
        }
    }
    __syncthreads();

    // phase 3: re-scan with carry, emit y
    h = sCar[c * 16 + n];
    for (int j = 0; j < 64; ++j) {
        int t = t0 + j;
        int tt = (k >= 2) ? (4095 - t) : t;
        int p = (k & 1) ? (((tt & 63) << 6) | (tt >> 6)) : tt;
        const float* row = pkk + (size_t)p * 36;
        float Bn = row[4 + n];
        float Cn = row[20 + n];
        float e = __expf(sDl[p] * a);
        h = e * h + sDlx[p] * Bn;
        float y = h * Cn;
        y += __shfl_xor(y, 1, 16);
        y += __shfl_xor(y, 2, 16);
        y += __shfl_xor(y, 4, 16);
        y += __shfl_xor(y, 8, 16);
        if (n == 0) yptr[p] = y;
    }
}

// ---- combine 4 directions + D*x, LN(112, eps 1e-5, onorm), gate with silu(z) ----
__global__ void k_combine(const float* __restrict__ ybuf, const float* __restrict__ xc,
                          const float* __restrict__ zbuf, BP Dp, BP ow, BP ob,
                          float* __restrict__ gbuf) {
    int l = blockIdx.x * blockDim.x + threadIdx.x;
    if (l >= L4) return;
    float s = 0.f, s2 = 0.f;
    for (int d = 0; d < DI; ++d) {
        float Ds = bf(Dp, d) + bf(Dp, DI + d) + bf(Dp, 2 * DI + d) + bf(Dp, 3 * DI + d);
        float yv = ybuf[d * L4 + l] + ybuf[(DI + d) * L4 + l] + ybuf[(2 * DI + d) * L4 + l]
                 + ybuf[(3 * DI + d) * L4 + l] + Ds * xc[d * L4 + l];
        gbuf[d * L4 + l] = yv; s += yv; s2 += yv * yv;
    }
    float mu = s / DI;
    float var = fmaxf(s2 / DI - mu * mu, 0.f);
    float rstd = rsqrtf(var + 1e-5f);
    for (int d = 0; d < DI; ++d) {
        float v = (gbuf[d * L4 + l] - mu) * rstd * bf(ow, d) + bf(ob, d);
        gbuf[d * L4 + l] = v * siluf(zbuf[d * L4 + l]);
    }
}

// ---- SAFM pools (scales 2,4,8) ----
__global__ void k_pools(const float* __restrict__ xln, float* __restrict__ p1,
                        float* __restrict__ p2, float* __restrict__ p3) {
    int tid = blockIdx.x * blockDim.x + threadIdx.x;
    int f, S, idx, chbase; float* dst;
    if (tid < 14336)      { f = 2; S = 32; idx = tid;          chbase = 14; dst = p1; }
    else if (tid < 17920) { f = 4; S = 16; idx = tid - 14336;  chbase = 28; dst = p2; }
    else if (tid < 18816) { f = 8; S = 8;  idx = tid - 17920;  chbase = 42; dst = p3; }
    else return;
    int c = idx / (S * S); int rem = idx - c * S * S; int y = rem / S, x = rem - y * S;
    float m = -3.4e38f;
    for (int dy = 0; dy < f; ++dy)
        for (int dx = 0; dx < f; ++dx) {
            float v = xln[(chbase + c) * L4 + (y * f + dy) * HW + (x * f + dx)];
            m = fmaxf(m, v);
        }
    dst[idx] = m;
}

// ---- SAFM depthwise convs at 4 scales (fused) ----
__global__ void k_mfr(const float* __restrict__ xln, const float* __restrict__ p1,
                      const float* __restrict__ p2, const float* __restrict__ p3,
                      BP mw, BP mb, float* __restrict__ s0, float* __restrict__ s1,
                      float* __restrict__ s2, float* __restrict__ s3) {
    int tid = blockIdx.x * blockDim.x + threadIdx.x;
    int S, i, idx; const float* src; float* dst;
    if (tid < 57344)      { S = 64; i = 0; idx = tid;          src = xln; dst = s0; }
    else if (tid < 71680) { S = 32; i = 1; idx = tid - 57344;  src = p1;  dst = s1; }
    else if (tid < 75264) { S = 16; i = 2; idx = tid - 71680;  src = p2;  dst = s2; }
    else if (tid < 76160) { S = 8;  i = 3; idx = tid - 75264;  src = p3;  dst = s3; }
    else return;
    int c = idx / (S * S); int rem = idx - c * S * S; int y = rem / S, x = rem - y * S;
    int srcstride = (i == 0) ? L4 : S * S;
    float acc = bf(mb, i * 14 + c);
    BP wr = mw + (i * 14 + c) * 9;
    const float* sc = src + c * srcstride;
    for (int ky = 0; ky < 3; ++ky) {
        int yy = y + ky - 1; if (yy < 0 || yy >= S) continue;
        for (int kx = 0; kx < 3; ++kx) {
            int xx = x + kx - 1; if (xx < 0 || xx >= S) continue;
            acc += sc[yy * S + xx] * bf(wr, ky * 3 + kx);
        }
    }
    dst[idx] = acc;
}

// ---- SAFM aggregate 1x1 + gelu gate + residual, writes trunk slice ----
__global__ void k_aggr(const float* __restrict__ s0, const float* __restrict__ s1,
                       const float* __restrict__ s2, const float* __restrict__ s3,
                       const float* __restrict__ xln, const float* __restrict__ x_mid,
                       BP aw, BP ab, float* __restrict__ out) {
    int tid = blockIdx.x * blockDim.x + threadIdx.x;
    if (tid >= CC * L4) return;
    int c = tid >> 12, l = tid & 4095;
    int h = l >> 6, w = l & 63;
    int o1 = (h >> 1) * 32 + (w >> 1);
    int o2 = (h >> 2) * 16 + (w >> 2);
    int o3 = (h >> 3) * 8 + (w >> 3);
    float acc = bf(ab, c);
    BP wr = aw + c * 56;
    for (int cg = 0; cg < 14; ++cg) acc += s0[cg * 4096 + l]  * bf(wr, cg);
    for (int cg = 0; cg < 14; ++cg) acc += s1[cg * 1024 + o1] * bf(wr, 14 + cg);
    for (int cg = 0; cg < 14; ++cg) acc += s2[cg * 256 + o2]  * bf(wr, 28 + cg);
    for (int cg = 0; cg < 14; ++cg) acc += s3[cg * 64 + o3]   * bf(wr, 42 + cg);
    out[tid] = x_mid[tid] + geluf(acc) * xln[tid];
}

// ---- up conv 3x3 (56->27) + pixel shuffle x3, LDS-staged, fp32 output ----
__global__ void __launch_bounds__(256) k_up(
        const float* __restrict__ out_lr, BP uw, BP ub, float* __restrict__ out) {
    __shared__ float sIn[56 * 36];
    __shared__ float sW[27 * 56 * 9];
    int b = blockIdx.x;
    int y0 = (b >> 4) * 4, x0 = (b & 15) * 4;
    for (int idx = threadIdx.x; idx < 56 * 36; idx += 256) {
        int cc = idx / 36; int rem = idx - cc * 36; int iy = rem / 6, ix = rem - iy * 6;
        int gy = y0 - 1 + iy, gx = x0 - 1 + ix;
        sIn[idx] = (gy >= 0 && gy < 64 && gx >= 0 && gx < 64)
                 ? out_lr[(size_t)cc * L4 + gy * 64 + gx] : 0.f;
    }
    for (int idx = threadIdx.x; idx < 27 * 56 * 9; idx += 256) sW[idx] = uw[idx];
    __syncthreads();
    int px = threadIdx.x & 15;
    int og = threadIdx.x >> 4;
    int dy = px >> 2, dx = px & 3;
    for (int oo = 0; oo < 2; ++oo) {
        int o = og * 2 + oo;
        if (o >= 27) break;
        float acc = ub[o];
        const float* wb = &sW[o * 504];
        for (int cc = 0; cc < 56; ++cc) {
            const float* ib = &sIn[cc * 36 + dy * 6 + dx];
            const float* wc = wb + cc * 9;
            acc += ib[0] * wc[0] + ib[1] * wc[1] + ib[2] * wc[2]
                 + ib[6] * wc[3] + ib[7] * wc[4] + ib[8] * wc[5]
                 + ib[12] * wc[6] + ib[13] * wc[7] + ib[14] * wc[8];
        }
        int h = y0 + dy, wv = x0 + dx;
        int ch = o / 9, rr = (o % 9) / 3, ss = o % 3;
        out[ch * 36864 + (h * 3 + rr) * 192 + (wv * 3 + ss)] = acc;
    }
}

extern "C" void kernel_launch(void* const* d_in, const int* in_sizes, int n_in,
                              void* d_out, int out_size, void* d_ws, size_t ws_size,
                              hipStream_t stream) {
    BP in0  = (BP)d_in[0];
    BP in1  = (BP)d_in[1];
    BP in2  = (BP)d_in[2];
    BP in3  = (BP)d_in[3];
    BP in4  = (BP)d_in[4];
    BP in5  = (BP)d_in[5];
    BP in6  = (BP)d_in[6];
    BP in7  = (BP)d_in[7];
    BP in8  = (BP)d_in[8];
    BP in9  = (BP)d_in[9];
    BP in10 = (BP)d_in[10];
    BP in11 = (BP)d_in[11];
    BP in12 = (BP)d_in[12];
    BP in13 = (BP)d_in[13];
    BP in14 = (BP)d_in[14];
    BP in15 = (BP)d_in[15];
    BP in16 = (BP)d_in[16];
    BP in17 = (BP)d_in[17];
    BP in18 = (BP)d_in[18];
    BP in19 = (BP)d_in[19];
    BP in20 = (BP)d_in[20];
    BP in21 = (BP)d_in[21];
    BP in22 = (BP)d_in[22];
    BP in23 = (BP)d_in[23];
    BP in24 = (BP)d_in[24];
    BP in25 = (BP)d_in[25];
    BP in26 = (BP)d_in[26];
    BP in27 = (BP)d_in[27];
    BP in28 = (BP)d_in[28];
    BP in29 = (BP)d_in[29];
    BP in30 = (BP)d_in[30];
    BP in31 = (BP)d_in[31];

    float* ws = (float*)d_ws;
    float* trunk   = ws; ws += 560 * L4;
    float* out_fea = ws; ws += CC * L4;
    float* t0      = ws; ws += CC * L4;
    float* xz      = ws; ws += 224 * L4;
    float* xc      = ws; ws += DI * L4;
    float* pk      = ws; ws += 4 * 36 * L4;
    float* ybuf    = ws; ws += 4 * DI * L4;
    float* gbuf    = ws; ws += DI * L4;
    float* x_mid   = ws; ws += CC * L4;
    float* xln     = ws; ws += CC * L4;
    float* p1      = ws; ws += 14 * 1024;
    float* p2      = ws; ws += 14 * 256;
    float* p3      = ws; ws += 14 * 64;
    float* s0      = ws; ws += 14 * 4096;
    float* s1      = ws; ws += 14 * 1024;
    float* s2      = ws; ws += 14 * 256;
    float* s3      = ws; ws += 14 * 64;
    float* bufB    = ws; ws += CC * L4;
    float* gB      = ws; ws += CC * L4;
    float* tbuf    = ws; ws += CC * L4;
    float* out_lr  = ws; ws += CC * L4;

    auto nb256 = [](int n) { return dim3((n + 255) / 256); };
    auto gemm_grid = [](int nout) { return dim3(64, (nout + 15) / 16); };

    // stem
    k_fea_pw<<<nb256(CC * L4), 256, 0, stream>>>(in0, in1, t0);
    k_dw3x3t<<<dim3(CC * 16), 256, 0, stream>>>(t0, in2, in3, out_fea, 0, nullptr);

    for (int nb = 0; nb < NBLK; ++nb) {
        const float* xin = (nb == 0) ? out_fea : trunk + (size_t)(nb - 1) * CC * L4;
        float* xout = trunk + (size_t)nb * CC * L4;
        BP ln1w = in4 + nb * 56,        ln1b = in5 + nb * 56;
        BP ipw  = in6 + nb * 224 * 56;
        BP cw   = in7 + nb * 112 * 9,   cb   = in8 + nb * 112;
        BP xpw  = in9 + nb * 4 * 36 * 112;
        BP dtw  = in10 + nb * 4 * 112 * 4, dtb = in11 + nb * 448;
        BP alog = in12 + nb * 448 * 16, Dp   = in13 + nb * 448;
        BP onw  = in14 + nb * 112,      onb  = in15 + nb * 112;
        BP opw  = in16 + nb * 56 * 112;
        BP nw   = in17 + nb * 56,       nbv  = in18 + nb * 56;
        BP mw   = in19 + nb * 4 * 14 * 9, mb = in20 + nb * 56;
        BP aw   = in21 + nb * 56 * 56,  ab   = in22 + nb * 56;

        k_gemm_ln<<<gemm_grid(224), 256, 0, stream>>>(xin, ln1w, ln1b, ipw, xz, 224);
        k_dw3x3t<<<dim3(DI * 16), 256, 0, stream>>>(xz, cw, cb, xc, 1, nullptr);
        k_gemm<<<gemm_grid(144), 256, 0, stream>>>(xc, xpw, nullptr, nullptr, pk, 112, 144, 1);
        k_scan<<<dim3(4 * DI), 1024, 0, stream>>>(xc, pk, alog, dtw, dtb, ybuf);
        k_combine<<<nb256(L4), 256, 0, stream>>>(ybuf, xc, xz + 112 * L4, Dp, onw, onb, gbuf);
        k_gemm<<<gemm_grid(56), 256, 0, stream>>>(gbuf, opw, nullptr, xin, x_mid, 112, 56, 0);
        k_ln_pix<<<nb256(L4), 256, 0, stream>>>(x_mid, nw, nbv, xln, CC, 1e-6f, 0);
        k_pools<<<nb256(18816), 256, 0, stream>>>(xln, p1, p2, p3);
        k_mfr<<<nb256(76160), 256, 0, stream>>>(xln, p1, p2, p3, mw, mb, s0, s1, s2, s3);
        k_aggr<<<nb256(CC * L4), 256, 0, stream>>>(s0, s1, s2, s3, xln, x_mid, aw, ab, xout);
    }

    // tail
    k_gemm<<<gemm_grid(56), 256, 0, stream>>>(trunk, in23, in24, nullptr, bufB, 560, 56, 0);
    k_ln_pix<<<nb256(L4), 256, 0, stream>>>(bufB, in25, in26, gB, CC, 1e-6f, 1);
    k_gemm<<<gemm_grid(56), 256, 0, stream>>>(gB, in27, nullptr, nullptr, tbuf, 56, 56, 0);
    k_dw3x3t<<<dim3(CC * 16), 256, 0, stream>>>(tbuf, in28, in29, out_lr, 0, out_fea);
    k_up<<<dim3(256), 256, 0, stream>>>(out_lr, in30, in31, (float*)d_out);
}

// Round 8
// 1588.439 us; speedup vs baseline: 2.4973x; 1.3181x over previous
//
#include <hip/hip_runtime.h>
#include <hip/hip_bf16.h>

#define HW 64
#define L4 4096
#define CC 56
#define DI 112
#define DSN 16
#define NBLK 10

typedef const float* BP;

__device__ __forceinline__ float bf(BP p, int i) { return p[i]; }
__device__ __forceinline__ float siluf(float x) { return x / (1.f + __expf(-x)); }
__device__ __forceinline__ float geluf(float x) { return 0.5f * x * (1.f + erff(x * 0.70710678f)); }

// ---- stem: pointwise 3->56 ----
__global__ void k_fea_pw(BP x, BP w, float* __restrict__ t0) {
    int tid = blockIdx.x * blockDim.x + threadIdx.x;
    if (tid >= CC * L4) return;
    int c = tid >> 12, l = tid & 4095;
    float acc = 0.f;
    for (int i = 0; i < 3; ++i) acc += bf(x, i * L4 + l) * bf(w, c * 3 + i);
    t0[tid] = acc;
}

// ---- tiled depthwise 3x3 for 64x64 maps: grid = nch*16, block 256 (16x16 px) ----
__global__ void __launch_bounds__(256) k_dw3x3t(
        const float* __restrict__ src, BP w, BP bvec, float* __restrict__ dst,
        int act, const float* __restrict__ addsrc) {
    int c = blockIdx.x >> 4;
    int tile = blockIdx.x & 15;
    int y0 = (tile >> 2) * 16, x0 = (tile & 3) * 16;
    __shared__ float sT[18 * 18];
    const float* sc = src + (size_t)c * L4;
    for (int idx = threadIdx.x; idx < 324; idx += 256) {
        int iy = idx / 18, ix = idx - iy * 18;
        int gy = y0 - 1 + iy, gx = x0 - 1 + ix;
        sT[idx] = (gy >= 0 && gy < 64 && gx >= 0 && gx < 64) ? sc[gy * 64 + gx] : 0.f;
    }
    __syncthreads();
    int py = threadIdx.x >> 4, px = threadIdx.x & 15;
    BP wr = w + c * 9;
    float acc = bvec ? bvec[c] : 0.f;
    #pragma unroll
    for (int ky = 0; ky < 3; ++ky)
        #pragma unroll
        for (int kx = 0; kx < 3; ++kx)
            acc += sT[(py + ky) * 18 + px + kx] * wr[ky * 3 + kx];
    if (act) acc = siluf(acc);
    int l = (y0 + py) * 64 + x0 + px;
    if (addsrc) acc += addsrc[(size_t)c * L4 + l];
    dst[(size_t)c * L4 + l] = acc;
}

// ---- LDS-staged per-pixel layernorm over 56 channels: grid 64, block 256 ----
__global__ void __launch_bounds__(256) k_ln56(
        const float* __restrict__ src, BP w, BP b, float* __restrict__ dst,
        float eps, int gelu_after) {
    int lane = threadIdx.x & 63;
    int cg = threadIdx.x >> 6;           // 4 groups x 14 channels
    int l0 = blockIdx.x * 64;
    __shared__ float sS[56 * 64];
    __shared__ float sPa[4][64], sPb[4][64];
    __shared__ float sMu[64], sRs[64];
    float ps = 0.f, ps2 = 0.f;
    for (int c = cg * 14; c < cg * 14 + 14; ++c) {
        float v = src[(size_t)c * L4 + l0 + lane];
        sS[c * 64 + lane] = v; ps += v; ps2 += v * v;
    }
    sPa[cg][lane] = ps; sPb[cg][lane] = ps2;
    __syncthreads();
    if (threadIdx.x < 64) {
        float s = sPa[0][lane] + sPa[1][lane] + sPa[2][lane] + sPa[3][lane];
        float s2 = sPb[0][lane] + sPb[1][lane] + sPb[2][lane] + sPb[3][lane];
        float mu = s / 56.f;
        float var = fmaxf(s2 / 56.f - mu * mu, 0.f);
        sMu[lane] = mu; sRs[lane] = rsqrtf(var + eps);
    }
    __syncthreads();
    float mu = sMu[lane], rs = sRs[lane];
    for (int c = cg * 14; c < cg * 14 + 14; ++c) {
        float v = (sS[c * 64 + lane] - mu) * rs * w[c] + b[c];
        if (gelu_after) v = geluf(v);
        dst[(size_t)c * L4 + l0 + lane] = v;
    }
}

// ---- LDS-staged channel GEMM (generic; nin % 56 == 0) ----
__global__ void __launch_bounds__(256) k_gemm(
        const float* __restrict__ src, BP w, BP bvec, const float* __restrict__ addsrc,
        float* __restrict__ dst, int nin, int nout, int out_mode) {
    int lane = threadIdx.x & 63;
    int jg = threadIdx.x >> 6;
    int l0 = blockIdx.x * 64;
    int j0 = blockIdx.y * 16;
    __shared__ __align__(16) float sS[56 * 64];
    __shared__ __align__(16) float sw[16 * 56];
    float acc[4] = {0.f, 0.f, 0.f, 0.f};

    for (int i0 = 0; i0 < nin; i0 += 56) {
        __syncthreads();
        for (int idx = threadIdx.x; idx < 56 * 64; idx += 256) {
            int ii = idx >> 6, px = idx & 63;
            sS[idx] = src[(size_t)(i0 + ii) * L4 + l0 + px];
        }
        for (int idx = threadIdx.x; idx < 16 * 56; idx += 256) {
            int jj = idx / 56, ii = idx - jj * 56;
            int j = j0 + jj;
            sw[idx] = (j < nout) ? w[(size_t)j * nin + i0 + ii] : 0.f;
        }
        __syncthreads();
        #pragma unroll
        for (int ii = 0; ii < 56; ii += 4) {
            float s0 = sS[(ii + 0) * 64 + lane];
            float s1 = sS[(ii + 1) * 64 + lane];
            float s2 = sS[(ii + 2) * 64 + lane];
            float s3 = sS[(ii + 3) * 64 + lane];
            #pragma unroll
            for (int jj = 0; jj < 4; ++jj) {
                const float4 wv = *(const float4*)&sw[(jg * 4 + jj) * 56 + ii];
                acc[jj] += s0 * wv.x + s1 * wv.y + s2 * wv.z + s3 * wv.w;
            }
        }
    }
    int l = l0 + lane;
    #pragma unroll
    for (int jj = 0; jj < 4; ++jj) {
        int j = j0 + jg * 4 + jj;
        if (j >= nout) continue;
        float v = acc[jj];
        if (bvec) v += bf(bvec, j);
        if (out_mode == 0) {
            size_t idx = (size_t)j * L4 + l;
            if (addsrc) v += addsrc[idx];
            dst[idx] = v;
        } else {
            int k = j / 36, c = j - k * 36;
            dst[((size_t)k * L4 + l) * 36 + c] = v;
        }
    }
}

// ---- in-proj GEMM with fused LN (nin = 56, single K chunk) ----
__global__ void __launch_bounds__(256) k_gemm_ln(
        const float* __restrict__ src, BP lnw, BP lnb, BP w,
        float* __restrict__ dst, int nout) {
    int lane = threadIdx.x & 63;
    int jg = threadIdx.x >> 6;
    int l0 = blockIdx.x * 64;
    int j0 = blockIdx.y * 16;
    __shared__ __align__(16) float sS[56 * 64];
    __shared__ __align__(16) float sw[16 * 56];
    __shared__ float sLw[56], sLb[56];
    float acc[4] = {0.f, 0.f, 0.f, 0.f};

    for (int idx = threadIdx.x; idx < 56 * 64; idx += 256) {
        int ii = idx >> 6, px = idx & 63;
        sS[idx] = src[(size_t)ii * L4 + l0 + px];
    }
    for (int idx = threadIdx.x; idx < 16 * 56; idx += 256) {
        int jj = idx / 56, ii = idx - jj * 56;
        int j = j0 + jj;
        sw[idx] = (j < nout) ? w[(size_t)j * 56 + ii] : 0.f;
    }
    if (threadIdx.x < 56) { sLw[threadIdx.x] = lnw[threadIdx.x]; sLb[threadIdx.x] = lnb[threadIdx.x]; }
    __syncthreads();
    if (threadIdx.x < 64) {
        int px = threadIdx.x;
        float s = 0.f, s2 = 0.f;
        for (int ii = 0; ii < 56; ++ii) { float v = sS[ii * 64 + px]; s += v; s2 += v * v; }
        float mu = s / 56.f;
        float var = fmaxf(s2 / 56.f - mu * mu, 0.f);
        float rstd = rsqrtf(var + 1e-5f);
        for (int ii = 0; ii < 56; ++ii)
            sS[ii * 64 + px] = (sS[ii * 64 + px] - mu) * rstd * sLw[ii] + sLb[ii];
    }
    __syncthreads();
    #pragma unroll
    for (int ii = 0; ii < 56; ii += 4) {
        float s0 = sS[(ii + 0) * 64 + lane];
        float s1 = sS[(ii + 1) * 64 + lane];
        float s2 = sS[(ii + 2) * 64 + lane];
        float s3 = sS[(ii + 3) * 64 + lane];
        #pragma unroll
        for (int jj = 0; jj < 4; ++jj) {
            const float4 wv = *(const float4*)&sw[(jg * 4 + jj) * 56 + ii];
            acc[jj] += s0 * wv.x + s1 * wv.y + s2 * wv.z + s3 * wv.w;
        }
    }
    int l = l0 + lane;
    #pragma unroll
    for (int jj = 0; jj < 4; ++jj) {
        int j = j0 + jg * 4 + jj;
        if (j < nout) dst[(size_t)j * L4 + l] = acc[jj];
    }
}

// ---- chunked selective scan, delta precomputed in LDS (bank-conflict-padded) ----
#define SPAD(p) ((p) + ((p) >> 5))
__global__ void __launch_bounds__(1024) k_scan(
        const float* __restrict__ xc, const float* __restrict__ pk,
        BP Alog, BP dtw, BP dtb, float* __restrict__ ybuf) {
    int pair = blockIdx.x;           // k*112+d
    int n = threadIdx.x & 15;        // state index
    int c = threadIdx.x >> 4;        // chunk index, 0..63
    int k = pair / DI, d = pair - k * DI;
    float a = -__expf(Alog[pair * DSN + n]);
    float w0 = dtw[pair * 4 + 0], w1 = dtw[pair * 4 + 1];
    float w2 = dtw[pair * 4 + 2], w3 = dtw[pair * 4 + 3];
    float db = dtb[pair];
    const float* xptr = xc + (size_t)d * L4;
    const float* pkk = pk + (size_t)k * L4 * 36;
    float* yptr = ybuf + (size_t)pair * L4;

    __shared__ float sDl[4224];      // delta[p], padded
    __shared__ float sDlx[4224];     // delta[p]*x[p], padded
    __shared__ float sP[64 * 16];
    __shared__ float sHe[64 * 16];
    __shared__ float sCar[64 * 16];

    // phase 0: cooperative delta precompute (4 softplus per thread)
    for (int p = threadIdx.x; p < L4; p += 1024) {
        const float* row = pkk + (size_t)p * 36;
        float v = db + row[0] * w0 + row[1] * w1 + row[2] * w2 + row[3] * w3;
        float dl = fmaxf(v, 0.f) + __logf(1.f + __expf(-fabsf(v)));
        sDl[SPAD(p)] = dl;
        sDlx[SPAD(p)] = dl * xptr[p];
    }
    __syncthreads();

    // phase 1: local chunk scan from 0
    float h = 0.f, P = 1.f;
    int t0 = c * 64;
    for (int j = 0; j < 64; ++j) {
        int t = t0 + j;
        int tt = (k >= 2) ? (4095 - t) : t;
        int p = (k & 1) ? (((tt & 63) << 6) | (tt >> 6)) : tt;
        float Bn = pkk[(size_t)p * 36 + 4 + n];
        float e = __expf(sDl[SPAD(p)] * a);
        h = e * h + sDlx[SPAD(p)] * Bn;
        P *= e;
    }
    sP[c * 16 + n] = P;
    sHe[c * 16 + n] = h;
    __syncthreads();

    // phase 2: serial carry compose
    if (threadIdx.x < 16) {
        float H = 0.f;
        for (int cc = 0; cc < 64; ++cc) {
            sCar[cc * 16 + n] = H;
            H = sP[cc * 16 + n] * H + sHe[cc * 16 + n];
        }
    }
    __syncthreads();

    // phase 3: re-scan with carry, emit y
    h = sCar[c * 16 + n];
    for (int j = 0; j < 64; ++j) {
        int t = t0 + j;
        int tt = (k >= 2) ? (4095 - t) : t;
        int p = (k & 1) ? (((tt & 63) << 6) | (tt >> 6)) : tt;
        const float* row = pkk + (size_t)p * 36;
        float Bn = row[4 + n];
        float Cn = row[20 + n];
        float e = __expf(sDl[SPAD(p)] * a);
        h = e * h + sDlx[SPAD(p)] * Bn;
        float y = h * Cn;
        y += __shfl_xor(y, 1, 16);
        y += __shfl_xor(y, 2, 16);
        y += __shfl_xor(y, 4, 16);
        y += __shfl_xor(y, 8, 16);
        if (n == 0) yptr[p] = y;
    }
}

// ---- combine 4 dirs + D*x, LN(112), gate silu(z): LDS-staged, grid 64 ----
__global__ void __launch_bounds__(256) k_combine(
        const float* __restrict__ ybuf, const float* __restrict__ xc,
        const float* __restrict__ zbuf, BP Dp, BP ow, BP ob,
        float* __restrict__ gbuf) {
    int lane = threadIdx.x & 63;
    int cg = threadIdx.x >> 6;           // 4 groups x 28 channels
    int l0 = blockIdx.x * 64;
    __shared__ float sY[112 * 64];
    __shared__ float sPa[4][64], sPb[4][64];
    __shared__ float sMu[64], sRs[64];
    float ps = 0.f, ps2 = 0.f;
    for (int d = cg * 28; d < cg * 28 + 28; ++d) {
        float Ds = Dp[d] + Dp[DI + d] + Dp[2 * DI + d] + Dp[3 * DI + d];
        float v = ybuf[(size_t)d * L4 + l0 + lane]
                + ybuf[(size_t)(DI + d) * L4 + l0 + lane]
                + ybuf[(size_t)(2 * DI + d) * L4 + l0 + lane]
                + ybuf[(size_t)(3 * DI + d) * L4 + l0 + lane]
                + Ds * xc[(size_t)d * L4 + l0 + lane];
        sY[d * 64 + lane] = v; ps += v; ps2 += v * v;
    }
    sPa[cg][lane] = ps; sPb[cg][lane] = ps2;
    __syncthreads();
    if (threadIdx.x < 64) {
        float s = sPa[0][lane] + sPa[1][lane] + sPa[2][lane] + sPa[3][lane];
        float s2 = sPb[0][lane] + sPb[1][lane] + sPb[2][lane] + sPb[3][lane];
        float mu = s / 112.f;
        float var = fmaxf(s2 / 112.f - mu * mu, 0.f);
        sMu[lane] = mu; sRs[lane] = rsqrtf(var + 1e-5f);
    }
    __syncthreads();
    float mu = sMu[lane], rs = sRs[lane];
    for (int d = cg * 28; d < cg * 28 + 28; ++d) {
        float v = (sY[d * 64 + lane] - mu) * rs * ow[d] + ob[d];
        float z = zbuf[(size_t)d * L4 + l0 + lane];
        gbuf[(size_t)d * L4 + l0 + lane] = v * siluf(z);
    }
}

// ---- SAFM pools (scales 2,4,8) ----
__global__ void k_pools(const float* __restrict__ xln, float* __restrict__ p1,
                        float* __restrict__ p2, float* __restrict__ p3) {
    int tid = blockIdx.x * blockDim.x + threadIdx.x;
    int f, S, idx, chbase; float* dst;
    if (tid < 14336)      { f = 2; S = 32; idx = tid;          chbase = 14; dst = p1; }
    else if (tid < 17920) { f = 4; S = 16; idx = tid - 14336;  chbase = 28; dst = p2; }
    else if (tid < 18816) { f = 8; S = 8;  idx = tid - 17920;  chbase = 42; dst = p3; }
    else return;
    int c = idx / (S * S); int rem = idx - c * S * S; int y = rem / S, x = rem - y * S;
    float m = -3.4e38f;
    for (int dy = 0; dy < f; ++dy)
        for (int dx = 0; dx < f; ++dx) {
            float v = xln[(chbase + c) * L4 + (y * f + dy) * HW + (x * f + dx)];
            m = fmaxf(m, v);
        }
    dst[idx] = m;
}

// ---- SAFM depthwise convs at 4 scales (fused) ----
__global__ void k_mfr(const float* __restrict__ xln, const float* __restrict__ p1,
                      const float* __restrict__ p2, const float* __restrict__ p3,
                      BP mw, BP mb, float* __restrict__ s0, float* __restrict__ s1,
                      float* __restrict__ s2, float* __restrict__ s3) {
    int tid = blockIdx.x * blockDim.x + threadIdx.x;
    int S, i, idx; const float* src; float* dst;
    if (tid < 57344)      { S = 64; i = 0; idx = tid;          src = xln; dst = s0; }
    else if (tid < 71680) { S = 32; i = 1; idx = tid - 57344;  src = p1;  dst = s1; }
    else if (tid < 75264) { S = 16; i = 2; idx = tid - 71680;  src = p2;  dst = s2; }
    else if (tid < 76160) { S = 8;  i = 3; idx = tid - 75264;  src = p3;  dst = s3; }
    else return;
    int c = idx / (S * S); int rem = idx - c * S * S; int y = rem / S, x = rem - y * S;
    int srcstride = (i == 0) ? L4 : S * S;
    float acc = bf(mb, i * 14 + c);
    BP wr = mw + (i * 14 + c) * 9;
    const float* sc = src + c * srcstride;
    for (int ky = 0; ky < 3; ++ky) {
        int yy = y + ky - 1; if (yy < 0 || yy >= S) continue;
        for (int kx = 0; kx < 3; ++kx) {
            int xx = x + kx - 1; if (xx < 0 || xx >= S) continue;
            acc += sc[yy * S + xx] * bf(wr, ky * 3 + kx);
        }
    }
    dst[idx] = acc;
}

// ---- SAFM aggregate 1x1 + gelu gate + residual, writes trunk slice ----
__global__ void k_aggr(const float* __restrict__ s0, const float* __restrict__ s1,
                       const float* __restrict__ s2, const float* __restrict__ s3,
                       const float* __restrict__ xln, const float* __restrict__ x_mid,
                       BP aw, BP ab, float* __restrict__ out) {
    int tid = blockIdx.x * blockDim.x + threadIdx.x;
    if (tid >= CC * L4) return;
    int c = tid >> 12, l = tid & 4095;
    int h = l >> 6, w = l & 63;
    int o1 = (h >> 1) * 32 + (w >> 1);
    int o2 = (h >> 2) * 16 + (w >> 2);
    int o3 = (h >> 3) * 8 + (w >> 3);
    float acc = bf(ab, c);
    BP wr = aw + c * 56;
    for (int cg = 0; cg < 14; ++cg) acc += s0[cg * 4096 + l]  * bf(wr, cg);
    for (int cg = 0; cg < 14; ++cg) acc += s1[cg * 1024 + o1] * bf(wr, 14 + cg);
    for (int cg = 0; cg < 14; ++cg) acc += s2[cg * 256 + o2]  * bf(wr, 28 + cg);
    for (int cg = 0; cg < 14; ++cg) acc += s3[cg * 64 + o3]   * bf(wr, 42 + cg);
    out[tid] = x_mid[tid] + geluf(acc) * xln[tid];
}

// ---- up conv 3x3 (56->27) + pixel shuffle x3, LDS-staged, fp32 output ----
__global__ void __launch_bounds__(256) k_up(
        const float* __restrict__ out_lr, BP uw, BP ub, float* __restrict__ out) {
    __shared__ float sIn[56 * 36];
    __shared__ float sW[27 * 56 * 9];
    int b = blockIdx.x;
    int y0 = (b >> 4) * 4, x0 = (b & 15) * 4;
    for (int idx = threadIdx.x; idx < 56 * 36; idx += 256) {
        int cc = idx / 36; int rem = idx - cc * 36; int iy = rem / 6, ix = rem - iy * 6;
        int gy = y0 - 1 + iy, gx = x0 - 1 + ix;
        sIn[idx] = (gy >= 0 && gy < 64 && gx >= 0 && gx < 64)
                 ? out_lr[(size_t)cc * L4 + gy * 64 + gx] : 0.f;
    }
    for (int idx = threadIdx.x; idx < 27 * 56 * 9; idx += 256) sW[idx] = uw[idx];
    __syncthreads();
    int px = threadIdx.x & 15;
    int og = threadIdx.x >> 4;
    int dy = px >> 2, dx = px & 3;
    for (int oo = 0; oo < 2; ++oo) {
        int o = og * 2 + oo;
        if (o >= 27) break;
        float acc = ub[o];
        const float* wb = &sW[o * 504];
        for (int cc = 0; cc < 56; ++cc) {
            const float* ib = &sIn[cc * 36 + dy * 6 + dx];
            const float* wc = wb + cc * 9;
            acc += ib[0] * wc[0] + ib[1] * wc[1] + ib[2] * wc[2]
                 + ib[6] * wc[3] + ib[7] * wc[4] + ib[8] * wc[5]
                 + ib[12] * wc[6] + ib[13] * wc[7] + ib[14] * wc[8];
        }
        int h = y0 + dy, wv = x0 + dx;
        int ch = o / 9, rr = (o % 9) / 3, ss = o % 3;
        out[ch * 36864 + (h * 3 + rr) * 192 + (wv * 3 + ss)] = acc;
    }
}

extern "C" void kernel_launch(void* const* d_in, const int* in_sizes, int n_in,
                              void* d_out, int out_size, void* d_ws, size_t ws_size,
                              hipStream_t stream) {
    BP in0  = (BP)d_in[0];
    BP in1  = (BP)d_in[1];
    BP in2  = (BP)d_in[2];
    BP in3  = (BP)d_in[3];
    BP in4  = (BP)d_in[4];
    BP in5  = (BP)d_in[5];
    BP in6  = (BP)d_in[6];
    BP in7  = (BP)d_in[7];
    BP in8  = (BP)d_in[8];
    BP in9  = (BP)d_in[9];
    BP in10 = (BP)d_in[10];
    BP in11 = (BP)d_in[11];
    BP in12 = (BP)d_in[12];
    BP in13 = (BP)d_in[13];
    BP in14 = (BP)d_in[14];
    BP in15 = (BP)d_in[15];
    BP in16 = (BP)d_in[16];
    BP in17 = (BP)d_in[17];
    BP in18 = (BP)d_in[18];
    BP in19 = (BP)d_in[19];
    BP in20 = (BP)d_in[20];
    BP in21 = (BP)d_in[21];
    BP in22 = (BP)d_in[22];
    BP in23 = (BP)d_in[23];
    BP in24 = (BP)d_in[24];
    BP in25 = (BP)d_in[25];
    BP in26 = (BP)d_in[26];
    BP in27 = (BP)d_in[27];
    BP in28 = (BP)d_in[28];
    BP in29 = (BP)d_in[29];
    BP in30 = (BP)d_in[30];
    BP in31 = (BP)d_in[31];

    float* ws = (float*)d_ws;
    float* trunk   = ws; ws += 560 * L4;
    float* out_fea = ws; ws += CC * L4;
    float* t0      = ws; ws += CC * L4;
    float* xz      = ws; ws += 224 * L4;
    float* xc      = ws; ws += DI * L4;
    float* pk      = ws; ws += 4 * 36 * L4;
    float* ybuf    = ws; ws += 4 * DI * L4;
    float* gbuf    = ws; ws += DI * L4;
    float* x_mid   = ws; ws += CC * L4;
    float* xln     = ws; ws += CC * L4;
    float* p1      = ws; ws += 14 * 1024;
    float* p2      = ws; ws += 14 * 256;
    float* p3      = ws; ws += 14 * 64;
    float* s0      = ws; ws += 14 * 4096;
    float* s1      = ws; ws += 14 * 1024;
    float* s2      = ws; ws += 14 * 256;
    float* s3      = ws; ws += 14 * 64;
    float* bufB    = ws; ws += CC * L4;
    float* gB      = ws; ws += CC * L4;
    float* tbuf    = ws; ws += CC * L4;
    float* out_lr  = ws; ws += CC * L4;

    auto nb256 = [](int n) { return dim3((n + 255) / 256); };
    auto gemm_grid = [](int nout) { return dim3(64, (nout + 15) / 16); };

    // stem
    k_fea_pw<<<nb256(CC * L4), 256, 0, stream>>>(in0, in1, t0);
    k_dw3x3t<<<dim3(CC * 16), 256, 0, stream>>>(t0, in2, in3, out_fea, 0, nullptr);

    for (int nb = 0; nb < NBLK; ++nb) {
        const float* xin = (nb == 0) ? out_fea : trunk + (size_t)(nb - 1) * CC * L4;
        float* xout = trunk + (size_t)nb * CC * L4;
        BP ln1w = in4 + nb * 56,        ln1b = in5 + nb * 56;
        BP ipw  = in6 + nb * 224 * 56;
        BP cw   = in7 + nb * 112 * 9,   cb   = in8 + nb * 112;
        BP xpw  = in9 + nb * 4 * 36 * 112;
        BP dtw  = in10 + nb * 4 * 112 * 4, dtb = in11 + nb * 448;
        BP alog = in12 + nb * 448 * 16, Dp   = in13 + nb * 448;
        BP onw  = in14 + nb * 112,      onb  = in15 + nb * 112;
        BP opw  = in16 + nb * 56 * 112;
        BP nw   = in17 + nb * 56,       nbv  = in18 + nb * 56;
        BP mw   = in19 + nb * 4 * 14 * 9, mb = in20 + nb * 56;
        BP aw   = in21 + nb * 56 * 56,  ab   = in22 + nb * 56;

        k_gemm_ln<<<gemm_grid(224), 256, 0, stream>>>(xin, ln1w, ln1b, ipw, xz, 224);
        k_dw3x3t<<<dim3(DI * 16), 256, 0, stream>>>(xz, cw, cb, xc, 1, nullptr);
        k_gemm<<<gemm_grid(144), 256, 0, stream>>>(xc, xpw, nullptr, nullptr, pk, 112, 144, 1);
        k_scan<<<dim3(4 * DI), 1024, 0, stream>>>(xc, pk, alog, dtw, dtb, ybuf);
        k_combine<<<dim3(64), 256, 0, stream>>>(ybuf, xc, xz + 112 * L4, Dp, onw, onb, gbuf);
        k_gemm<<<gemm_grid(56), 256, 0, stream>>>(gbuf, opw, nullptr, xin, x_mid, 112, 56, 0);
        k_ln56<<<dim3(64), 256, 0, stream>>>(x_mid, nw, nbv, xln, 1e-6f, 0);
        k_pools<<<nb256(18816), 256, 0, stream>>>(xln, p1, p2, p3);
        k_mfr<<<nb256(76160), 256, 0, stream>>>(xln, p1, p2, p3, mw, mb, s0, s1, s2, s3);
        k_aggr<<<nb256(CC * L4), 256, 0, stream>>>(s0, s1, s2, s3, xln, x_mid, aw, ab, xout);
    }

    // tail
    k_gemm<<<gemm_grid(56), 256, 0, stream>>>(trunk, in23, in24, nullptr, bufB, 560, 56, 0);
    k_ln56<<<dim3(64), 256, 0, stream>>>(bufB, in25, in26, gB, 1e-6f, 1);
    k_gemm<<<gemm_grid(56), 256, 0, stream>>>(gB, in27, nullptr, nullptr, tbuf, 56, 56, 0);
    k_dw3x3t<<<dim3(CC * 16), 256, 0, stream>>>(tbuf, in28, in29, out_lr, 0, out_fea);
    k_up<<<dim3(256), 256, 0, stream>>>(out_lr, in30, in31, (float*)d_out);
}

// Round 9
// 1482.437 us; speedup vs baseline: 2.6759x; 1.0715x over previous
//
#include <hip/hip_runtime.h>
#include <hip/hip_bf16.h>

#define HW 64
#define L4 4096
#define CC 56
#define DI 112
#define DSN 16
#define NBLK 10

typedef const float* BP;

__device__ __forceinline__ float bf(BP p, int i) { return p[i]; }
__device__ __forceinline__ float siluf(float x) { return x / (1.f + __expf(-x)); }
__device__ __forceinline__ float geluf(float x) { return 0.5f * x * (1.f + erff(x * 0.70710678f)); }

// ---- stem: pointwise 3->56 ----
__global__ void k_fea_pw(BP x, BP w, float* __restrict__ t0) {
    int tid = blockIdx.x * blockDim.x + threadIdx.x;
    if (tid >= CC * L4) return;
    int c = tid >> 12, l = tid & 4095;
    float acc = 0.f;
    for (int i = 0; i < 3; ++i) acc += bf(x, i * L4 + l) * bf(w, c * 3 + i);
    t0[tid] = acc;
}

// ---- tiled depthwise 3x3 for 64x64 maps: grid = nch*16, block 256 (16x16 px) ----
__global__ void __launch_bounds__(256) k_dw3x3t(
        const float* __restrict__ src, BP w, BP bvec, float* __restrict__ dst,
        int act, const float* __restrict__ addsrc) {
    int c = blockIdx.x >> 4;
    int tile = blockIdx.x & 15;
    int y0 = (tile >> 2) * 16, x0 = (tile & 3) * 16;
    __shared__ float sT[18 * 18];
    const float* sc = src + (size_t)c * L4;
    for (int idx = threadIdx.x; idx < 324; idx += 256) {
        int iy = idx / 18, ix = idx - iy * 18;
        int gy = y0 - 1 + iy, gx = x0 - 1 + ix;
        sT[idx] = (gy >= 0 && gy < 64 && gx >= 0 && gx < 64) ? sc[gy * 64 + gx] : 0.f;
    }
    __syncthreads();
    int py = threadIdx.x >> 4, px = threadIdx.x & 15;
    BP wr = w + c * 9;
    float acc = bvec ? bvec[c] : 0.f;
    #pragma unroll
    for (int ky = 0; ky < 3; ++ky)
        #pragma unroll
        for (int kx = 0; kx < 3; ++kx)
            acc += sT[(py + ky) * 18 + px + kx] * wr[ky * 3 + kx];
    if (act) acc = siluf(acc);
    int l = (y0 + py) * 64 + x0 + px;
    if (addsrc) acc += addsrc[(size_t)c * L4 + l];
    dst[(size_t)c * L4 + l] = acc;
}

// ---- LDS-staged per-pixel layernorm over 56 channels: grid 64, block 256 ----
__global__ void __launch_bounds__(256) k_ln56(
        const float* __restrict__ src, BP w, BP b, float* __restrict__ dst,
        float eps, int gelu_after) {
    int lane = threadIdx.x & 63;
    int cg = threadIdx.x >> 6;
    int l0 = blockIdx.x * 64;
    __shared__ float sS[56 * 64];
    __shared__ float sPa[4][64], sPb[4][64];
    __shared__ float sMu[64], sRs[64];
    float ps = 0.f, ps2 = 0.f;
    for (int c = cg * 14; c < cg * 14 + 14; ++c) {
        float v = src[(size_t)c * L4 + l0 + lane];
        sS[c * 64 + lane] = v; ps += v; ps2 += v * v;
    }
    sPa[cg][lane] = ps; sPb[cg][lane] = ps2;
    __syncthreads();
    if (threadIdx.x < 64) {
        float s = sPa[0][lane] + sPa[1][lane] + sPa[2][lane] + sPa[3][lane];
        float s2 = sPb[0][lane] + sPb[1][lane] + sPb[2][lane] + sPb[3][lane];
        float mu = s / 56.f;
        float var = fmaxf(s2 / 56.f - mu * mu, 0.f);
        sMu[lane] = mu; sRs[lane] = rsqrtf(var + eps);
    }
    __syncthreads();
    float mu = sMu[lane], rs = sRs[lane];
    for (int c = cg * 14; c < cg * 14 + 14; ++c) {
        float v = (sS[c * 64 + lane] - mu) * rs * w[c] + b[c];
        if (gelu_after) v = geluf(v);
        dst[(size_t)c * L4 + l0 + lane] = v;
    }
}

// ---- LDS-staged channel GEMM (generic; nin % 56 == 0) ----
__global__ void __launch_bounds__(256) k_gemm(
        const float* __restrict__ src, BP w, BP bvec, const float* __restrict__ addsrc,
        float* __restrict__ dst, int nin, int nout, int out_mode) {
    int lane = threadIdx.x & 63;
    int jg = threadIdx.x >> 6;
    int l0 = blockIdx.x * 64;
    int j0 = blockIdx.y * 16;
    __shared__ __align__(16) float sS[56 * 64];
    __shared__ __align__(16) float sw[16 * 56];
    float acc[4] = {0.f, 0.f, 0.f, 0.f};

    for (int i0 = 0; i0 < nin; i0 += 56) {
        __syncthreads();
        for (int idx = threadIdx.x; idx < 56 * 64; idx += 256) {
            int ii = idx >> 6, px = idx & 63;
            sS[idx] = src[(size_t)(i0 + ii) * L4 + l0 + px];
        }
        for (int idx = threadIdx.x; idx < 16 * 56; idx += 256) {
            int jj = idx / 56, ii = idx - jj * 56;
            int j = j0 + jj;
            sw[idx] = (j < nout) ? w[(size_t)j * nin + i0 + ii] : 0.f;
        }
        __syncthreads();
        #pragma unroll
        for (int ii = 0; ii < 56; ii += 4) {
            float s0 = sS[(ii + 0) * 64 + lane];
            float s1 = sS[(ii + 1) * 64 + lane];
            float s2 = sS[(ii + 2) * 64 + lane];
            float s3 = sS[(ii + 3) * 64 + lane];
            #pragma unroll
            for (int jj = 0; jj < 4; ++jj) {
                const float4 wv = *(const float4*)&sw[(jg * 4 + jj) * 56 + ii];
                acc[jj] += s0 * wv.x + s1 * wv.y + s2 * wv.z + s3 * wv.w;
            }
        }
    }
    int l = l0 + lane;
    #pragma unroll
    for (int jj = 0; jj < 4; ++jj) {
        int j = j0 + jg * 4 + jj;
        if (j >= nout) continue;
        float v = acc[jj];
        if (bvec) v += bf(bvec, j);
        if (out_mode == 0) {
            size_t idx = (size_t)j * L4 + l;
            if (addsrc) v += addsrc[idx];
            dst[idx] = v;
        } else {
            int k = j / 36, c = j - k * 36;
            dst[((size_t)k * L4 + l) * 36 + c] = v;
        }
    }
}

// ---- in-proj GEMM with fused LN (nin = 56, single K chunk) ----
__global__ void __launch_bounds__(256) k_gemm_ln(
        const float* __restrict__ src, BP lnw, BP lnb, BP w,
        float* __restrict__ dst, int nout) {
    int lane = threadIdx.x & 63;
    int jg = threadIdx.x >> 6;
    int l0 = blockIdx.x * 64;
    int j0 = blockIdx.y * 16;
    __shared__ __align__(16) float sS[56 * 64];
    __shared__ __align__(16) float sw[16 * 56];
    __shared__ float sLw[56], sLb[56];
    float acc[4] = {0.f, 0.f, 0.f, 0.f};

    for (int idx = threadIdx.x; idx < 56 * 64; idx += 256) {
        int ii = idx >> 6, px = idx & 63;
        sS[idx] = src[(size_t)ii * L4 + l0 + px];
    }
    for (int idx = threadIdx.x; idx < 16 * 56; idx += 256) {
        int jj = idx / 56, ii = idx - jj * 56;
        int j = j0 + jj;
        sw[idx] = (j < nout) ? w[(size_t)j * 56 + ii] : 0.f;
    }
    if (threadIdx.x < 56) { sLw[threadIdx.x] = lnw[threadIdx.x]; sLb[threadIdx.x] = lnb[threadIdx.x]; }
    __syncthreads();
    if (threadIdx.x < 64) {
        int px = threadIdx.x;
        float s = 0.f, s2 = 0.f;
        for (int ii = 0; ii < 56; ++ii) { float v = sS[ii * 64 + px]; s += v; s2 += v * v; }
        float mu = s / 56.f;
        float var = fmaxf(s2 / 56.f - mu * mu, 0.f);
        float rstd = rsqrtf(var + 1e-5f);
        for (int ii = 0; ii < 56; ++ii)
            sS[ii * 64 + px] = (sS[ii * 64 + px] - mu) * rstd * sLw[ii] + sLb[ii];
    }
    __syncthreads();
    #pragma unroll
    for (int ii = 0; ii < 56; ii += 4) {
        float s0 = sS[(ii + 0) * 64 + lane];
        float s1 = sS[(ii + 1) * 64 + lane];
        float s2 = sS[(ii + 2) * 64 + lane];
        float s3 = sS[(ii + 3) * 64 + lane];
        #pragma unroll
        for (int jj = 0; jj < 4; ++jj) {
            const float4 wv = *(const float4*)&sw[(jg * 4 + jj) * 56 + ii];
            acc[jj] += s0 * wv.x + s1 * wv.y + s2 * wv.z + s3 * wv.w;
        }
    }
    int l = l0 + lane;
    #pragma unroll
    for (int jj = 0; jj < 4; ++jj) {
        int j = j0 + jg * 4 + jj;
        if (j < nout) dst[(size_t)j * L4 + l] = acc[jj];
    }
}

// ---- chunked selective scan; per-direction pixel walk is affine: p = p0 + j*dp ----
#define SPAD(p) ((p) + ((p) >> 5))
__global__ void __launch_bounds__(1024) k_scan(
        const float* __restrict__ xc, const float* __restrict__ pk,
        BP Alog, BP dtw, BP dtb, float* __restrict__ ybuf) {
    int pair = blockIdx.x;           // k*112+d
    int n = threadIdx.x & 15;        // state index
    int c = threadIdx.x >> 4;        // chunk index, 0..63
    int k = pair / DI, d = pair - k * DI;
    float a = -__expf(Alog[pair * DSN + n]);
    float w0 = dtw[pair * 4 + 0], w1 = dtw[pair * 4 + 1];
    float w2 = dtw[pair * 4 + 2], w3 = dtw[pair * 4 + 3];
    float db = dtb[pair];
    const float* xptr = xc + (size_t)d * L4;
    const float* pkk = pk + (size_t)k * L4 * 36;
    float* yptr = ybuf + (size_t)pair * L4;

    __shared__ float sDl[4224];
    __shared__ float sDlx[4224];
    __shared__ float sP[64 * 16];
    __shared__ float sHe[64 * 16];
    __shared__ float sCar[64 * 16];

    // phase 0: cooperative delta precompute
    for (int p = threadIdx.x; p < L4; p += 1024) {
        const float* row = pkk + (size_t)p * 36;
        float v = db + row[0] * w0 + row[1] * w1 + row[2] * w2 + row[3] * w3;
        float dl = fmaxf(v, 0.f) + __logf(1.f + __expf(-fabsf(v)));
        sDl[SPAD(p)] = dl;
        sDlx[SPAD(p)] = dl * xptr[p];
    }
    __syncthreads();

    // affine walk params
    int p0, dp;
    if (k == 0)      { p0 = c * 64;        dp = 1;   }
    else if (k == 1) { p0 = c;             dp = 64;  }
    else if (k == 2) { p0 = 4095 - c * 64; dp = -1;  }
    else             { p0 = 4095 - c;      dp = -64; }
    long rstep = (long)dp * 36;

    // phase 1: local chunk scan from 0
    float h = 0.f, P = 1.f;
    {
        int p = p0;
        const float* rB = pkk + (size_t)p0 * 36 + 4 + n;
        #pragma unroll 4
        for (int j = 0; j < 64; ++j) {
            int q = SPAD(p);
            float e = __expf(sDl[q] * a);
            h = e * h + sDlx[q] * (*rB);
            P *= e;
            p += dp; rB += rstep;
        }
    }
    sP[c * 16 + n] = P;
    sHe[c * 16 + n] = h;
    __syncthreads();

    // phase 2: serial carry compose
    if (threadIdx.x < 16) {
        float H = 0.f;
        for (int cc = 0; cc < 64; ++cc) {
            sCar[cc * 16 + n] = H;
            H = sP[cc * 16 + n] * H + sHe[cc * 16 + n];
        }
    }
    __syncthreads();

    // phase 3: re-scan with carry, emit y
    h = sCar[c * 16 + n];
    {
        int p = p0;
        const float* rB = pkk + (size_t)p0 * 36 + 4 + n;
        const float* rC = pkk + (size_t)p0 * 36 + 20 + n;
        #pragma unroll 4
        for (int j = 0; j < 64; ++j) {
            int q = SPAD(p);
            float e = __expf(sDl[q] * a);
            h = e * h + sDlx[q] * (*rB);
            float y = h * (*rC);
            y += __shfl_xor(y, 1, 16);
            y += __shfl_xor(y, 2, 16);
            y += __shfl_xor(y, 4, 16);
            y += __shfl_xor(y, 8, 16);
            if (n == 0) yptr[p] = y;
            p += dp; rB += rstep; rC += rstep;
        }
    }
}

// ---- fused: combine 4 dirs + D*x, LN(112), silu(z) gate, out-proj 112->56 + residual ----
// grid 64 (l-tiles of 64), block 256 = 64 lanes x 4 jg (14 outputs each)
__global__ void __launch_bounds__(256) k_comb_proj(
        const float* __restrict__ ybuf, const float* __restrict__ xc,
        const float* __restrict__ zbuf, BP Dp, BP ow, BP ob, BP opw,
        const float* __restrict__ xin, float* __restrict__ x_mid) {
    int lane = threadIdx.x & 63;
    int cg = threadIdx.x >> 6;
    int l0 = blockIdx.x * 64;
    __shared__ __align__(16) float sY[112 * 64];   // 28 KB
    __shared__ __align__(16) float sW[56 * 112];   // 25 KB
    __shared__ float sPa[4][64], sPb[4][64];
    __shared__ float sMu[64], sRs[64];

    float ps = 0.f, ps2 = 0.f;
    for (int d = cg * 28; d < cg * 28 + 28; ++d) {
        float Ds = Dp[d] + Dp[DI + d] + Dp[2 * DI + d] + Dp[3 * DI + d];
        float v = ybuf[(size_t)d * L4 + l0 + lane]
                + ybuf[(size_t)(DI + d) * L4 + l0 + lane]
                + ybuf[(size_t)(2 * DI + d) * L4 + l0 + lane]
                + ybuf[(size_t)(3 * DI + d) * L4 + l0 + lane]
                + Ds * xc[(size_t)d * L4 + l0 + lane];
        sY[d * 64 + lane] = v; ps += v; ps2 += v * v;
    }
    sPa[cg][lane] = ps; sPb[cg][lane] = ps2;
    for (int idx = threadIdx.x; idx < 56 * 112; idx += 256) sW[idx] = opw[idx];
    __syncthreads();
    if (threadIdx.x < 64) {
        float s = sPa[0][lane] + sPa[1][lane] + sPa[2][lane] + sPa[3][lane];
        float s2 = sPb[0][lane] + sPb[1][lane] + sPb[2][lane] + sPb[3][lane];
        float mu = s / 112.f;
        float var = fmaxf(s2 / 112.f - mu * mu, 0.f);
        sMu[lane] = mu; sRs[lane] = rsqrtf(var + 1e-5f);
    }
    __syncthreads();
    float mu = sMu[lane], rs = sRs[lane];
    for (int d = cg * 28; d < cg * 28 + 28; ++d) {
        float v = (sY[d * 64 + lane] - mu) * rs * ow[d] + ob[d];
        float z = zbuf[(size_t)d * L4 + l0 + lane];
        sY[d * 64 + lane] = v * siluf(z);
    }
    __syncthreads();

    float acc[14];
    #pragma unroll
    for (int jj = 0; jj < 14; ++jj) acc[jj] = 0.f;
    #pragma unroll 2
    for (int ii = 0; ii < 112; ii += 4) {
        float s0 = sY[(ii + 0) * 64 + lane];
        float s1 = sY[(ii + 1) * 64 + lane];
        float s2 = sY[(ii + 2) * 64 + lane];
        float s3 = sY[(ii + 3) * 64 + lane];
        #pragma unroll
        for (int jj = 0; jj < 14; ++jj) {
            const float4 wv = *(const float4*)&sW[(cg * 14 + jj) * 112 + ii];
            acc[jj] += s0 * wv.x + s1 * wv.y + s2 * wv.z + s3 * wv.w;
        }
    }
    int l = l0 + lane;
    #pragma unroll
    for (int jj = 0; jj < 14; ++jj) {
        int j = cg * 14 + jj;
        x_mid[(size_t)j * L4 + l] = acc[jj] + xin[(size_t)j * L4 + l];
    }
}

// ---- fused SAFM pools+depthwise: grid 224 (i=0 tiles) + 42 (i>=1 channels) ----
__global__ void __launch_bounds__(256) k_safm(
        const float* __restrict__ xln, BP mw, BP mb,
        float* __restrict__ s0, float* __restrict__ s1,
        float* __restrict__ s2, float* __restrict__ s3) {
    int b = blockIdx.x;
    if (b < 224) {
        // i=0: plain depthwise on channels 0..13, 16x16 tiles
        int c = b >> 4;
        int tile = b & 15;
        int y0 = (tile >> 2) * 16, x0 = (tile & 3) * 16;
        __shared__ float sT[18 * 18];
        const float* sc = xln + (size_t)c * L4;
        for (int idx = threadIdx.x; idx < 324; idx += 256) {
            int iy = idx / 18, ix = idx - iy * 18;
            int gy = y0 - 1 + iy, gx = x0 - 1 + ix;
            sT[idx] = (gy >= 0 && gy < 64 && gx >= 0 && gx < 64) ? sc[gy * 64 + gx] : 0.f;
        }
        __syncthreads();
        int py = threadIdx.x >> 4, px = threadIdx.x & 15;
        BP wr = mw + c * 9;
        float acc = mb[c];
        #pragma unroll
        for (int ky = 0; ky < 3; ++ky)
            #pragma unroll
            for (int kx = 0; kx < 3; ++kx)
                acc += sT[(py + ky) * 18 + px + kx] * wr[ky * 3 + kx];
        s0[c * L4 + (y0 + py) * 64 + x0 + px] = acc;
    } else {
        int bb = b - 224;
        int i = bb / 14 + 1;           // 1..3
        int c = bb % 14;
        int S = 64 >> i;               // 32,16,8
        int f = 1 << i;                // 2,4,8
        __shared__ float sP[34 * 34];
        int W2 = S + 2;
        for (int idx = threadIdx.x; idx < W2 * W2; idx += 256) sP[idx] = 0.f;
        __syncthreads();
        const float* sc = xln + (size_t)(i * 14 + c) * L4;
        for (int cell = threadIdx.x; cell < S * S; cell += 256) {
            int y = cell / S, x = cell - y * S;
            float m = -3.4e38f;
            for (int dy = 0; dy < f; ++dy)
                for (int dx = 0; dx < f; ++dx)
                    m = fmaxf(m, sc[(y * f + dy) * 64 + x * f + dx]);
            sP[(y + 1) * W2 + x + 1] = m;
        }
        __syncthreads();
        BP wr = mw + (i * 14 + c) * 9;
        float bias = mb[i * 14 + c];
        float* dst = (i == 1) ? s1 : (i == 2) ? s2 : s3;
        for (int cell = threadIdx.x; cell < S * S; cell += 256) {
            int y = cell / S, x = cell - y * S;
            float acc = bias;
            #pragma unroll
            for (int ky = 0; ky < 3; ++ky)
                #pragma unroll
                for (int kx = 0; kx < 3; ++kx)
                    acc += sP[(y + ky) * W2 + x + kx] * wr[ky * 3 + kx];
            dst[c * S * S + cell] = acc;
        }
    }
}

// ---- SAFM aggregate 1x1 + gelu gate + residual, writes trunk slice ----
__global__ void k_aggr(const float* __restrict__ s0, const float* __restrict__ s1,
                       const float* __restrict__ s2, const float* __restrict__ s3,
                       const float* __restrict__ xln, const float* __restrict__ x_mid,
                       BP aw, BP ab, float* __restrict__ out) {
    int tid = blockIdx.x * blockDim.x + threadIdx.x;
    if (tid >= CC * L4) return;
    int c = tid >> 12, l = tid & 4095;
    int h = l >> 6, w = l & 63;
    int o1 = (h >> 1) * 32 + (w >> 1);
    int o2 = (h >> 2) * 16 + (w >> 2);
    int o3 = (h >> 3) * 8 + (w >> 3);
    float acc = bf(ab, c);
    BP wr = aw + c * 56;
    for (int cg = 0; cg < 14; ++cg) acc += s0[cg * 4096 + l]  * bf(wr, cg);
    for (int cg = 0; cg < 14; ++cg) acc += s1[cg * 1024 + o1] * bf(wr, 14 + cg);
    for (int cg = 0; cg < 14; ++cg) acc += s2[cg * 256 + o2]  * bf(wr, 28 + cg);
    for (int cg = 0; cg < 14; ++cg) acc += s3[cg * 64 + o3]   * bf(wr, 42 + cg);
    out[tid] = x_mid[tid] + geluf(acc) * xln[tid];
}

// ---- up conv 3x3 (56->27) + pixel shuffle x3, LDS-staged, fp32 output ----
__global__ void __launch_bounds__(256) k_up(
        const float* __restrict__ out_lr, BP uw, BP ub, float* __restrict__ out) {
    __shared__ float sIn[56 * 36];
    __shared__ float sW[27 * 56 * 9];
    int b = blockIdx.x;
    int y0 = (b >> 4) * 4, x0 = (b & 15) * 4;
    for (int idx = threadIdx.x; idx < 56 * 36; idx += 256) {
        int cc = idx / 36; int rem = idx - cc * 36; int iy = rem / 6, ix = rem - iy * 6;
        int gy = y0 - 1 + iy, gx = x0 - 1 + ix;
        sIn[idx] = (gy >= 0 && gy < 64 && gx >= 0 && gx < 64)
                 ? out_lr[(size_t)cc * L4 + gy * 64 + gx] : 0.f;
    }
    for (int idx = threadIdx.x; idx < 27 * 56 * 9; idx += 256) sW[idx] = uw[idx];
    __syncthreads();
    int px = threadIdx.x & 15;
    int og = threadIdx.x >> 4;
    int dy = px >> 2, dx = px & 3;
    for (int oo = 0; oo < 2; ++oo) {
        int o = og * 2 + oo;
        if (o >= 27) break;
        float acc = ub[o];
        const float* wb = &sW[o * 504];
        for (int cc = 0; cc < 56; ++cc) {
            const float* ib = &sIn[cc * 36 + dy * 6 + dx];
            const float* wc = wb + cc * 9;
            acc += ib[0] * wc[0] + ib[1] * wc[1] + ib[2] * wc[2]
                 + ib[6] * wc[3] + ib[7] * wc[4] + ib[8] * wc[5]
                 + ib[12] * wc[6] + ib[13] * wc[7] + ib[14] * wc[8];
        }
        int h = y0 + dy, wv = x0 + dx;
        int ch = o / 9, rr = (o % 9) / 3, ss = o % 3;
        out[ch * 36864 + (h * 3 + rr) * 192 + (wv * 3 + ss)] = acc;
    }
}

extern "C" void kernel_launch(void* const* d_in, const int* in_sizes, int n_in,
                              void* d_out, int out_size, void* d_ws, size_t ws_size,
                              hipStream_t stream) {
    BP in0  = (BP)d_in[0];
    BP in1  = (BP)d_in[1];
    BP in2  = (BP)d_in[2];
    BP in3  = (BP)d_in[3];
    BP in4  = (BP)d_in[4];
    BP in5  = (BP)d_in[5];
    BP in6  = (BP)d_in[6];
    BP in7  = (BP)d_in[7];
    BP in8  = (BP)d_in[8];
    BP in9  = (BP)d_in[9];
    BP in10 = (BP)d_in[10];
    BP in11 = (BP)d_in[11];
    BP in12 = (BP)d_in[12];
    BP in13 = (BP)d_in[13];
    BP in14 = (BP)d_in[14];
    BP in15 = (BP)d_in[15];
    BP in16 = (BP)d_in[16];
    BP in17 = (BP)d_in[17];
    BP in18 = (BP)d_in[18];
    BP in19 = (BP)d_in[19];
    BP in20 = (BP)d_in[20];
    BP in21 = (BP)d_in[21];
    BP in22 = (BP)d_in[22];
    BP in23 = (BP)d_in[23];
    BP in24 = (BP)d_in[24];
    BP in25 = (BP)d_in[25];
    BP in26 = (BP)d_in[26];
    BP in27 = (BP)d_in[27];
    BP in28 = (BP)d_in[28];
    BP in29 = (BP)d_in[29];
    BP in30 = (BP)d_in[30];
    BP in31 = (BP)d_in[31];

    float* ws = (float*)d_ws;
    float* trunk   = ws; ws += 560 * L4;
    float* out_fea = ws; ws += CC * L4;
    float* t0      = ws; ws += CC * L4;
    float* xz      = ws; ws += 224 * L4;
    float* xc      = ws; ws += DI * L4;
    float* pk      = ws; ws += 4 * 36 * L4;
    float* ybuf    = ws; ws += 4 * DI * L4;
    float* x_mid   = ws; ws += CC * L4;
    float* xln     = ws; ws += CC * L4;
    float* s0      = ws; ws += 14 * 4096;
    float* s1      = ws; ws += 14 * 1024;
    float* s2      = ws; ws += 14 * 256;
    float* s3      = ws; ws += 14 * 64;
    float* bufB    = ws; ws += CC * L4;
    float* gB      = ws; ws += CC * L4;
    float* tbuf    = ws; ws += CC * L4;
    float* out_lr  = ws; ws += CC * L4;

    auto nb256 = [](int n) { return dim3((n + 255) / 256); };
    auto gemm_grid = [](int nout) { return dim3(64, (nout + 15) / 16); };

    // stem
    k_fea_pw<<<nb256(CC * L4), 256, 0, stream>>>(in0, in1, t0);
    k_dw3x3t<<<dim3(CC * 16), 256, 0, stream>>>(t0, in2, in3, out_fea, 0, nullptr);

    for (int nb = 0; nb < NBLK; ++nb) {
        const float* xin = (nb == 0) ? out_fea : trunk + (size_t)(nb - 1) * CC * L4;
        float* xout = trunk + (size_t)nb * CC * L4;
        BP ln1w = in4 + nb * 56,        ln1b = in5 + nb * 56;
        BP ipw  = in6 + nb * 224 * 56;
        BP cw   = in7 + nb * 112 * 9,   cb   = in8 + nb * 112;
        BP xpw  = in9 + nb * 4 * 36 * 112;
        BP dtw  = in10 + nb * 4 * 112 * 4, dtb = in11 + nb * 448;
        BP alog = in12 + nb * 448 * 16, Dp   = in13 + nb * 448;
        BP onw  = in14 + nb * 112,      onb  = in15 + nb * 112;
        BP opw  = in16 + nb * 56 * 112;
        BP nw   = in17 + nb * 56,       nbv  = in18 + nb * 56;
        BP mw   = in19 + nb * 4 * 14 * 9, mb = in20 + nb * 56;
        BP aw   = in21 + nb * 56 * 56,  ab   = in22 + nb * 56;

        k_gemm_ln<<<gemm_grid(224), 256, 0, stream>>>(xin, ln1w, ln1b, ipw, xz, 224);
        k_dw3x3t<<<dim3(DI * 16), 256, 0, stream>>>(xz, cw, cb, xc, 1, nullptr);
        k_gemm<<<gemm_grid(144), 256, 0, stream>>>(xc, xpw, nullptr, nullptr, pk, 112, 144, 1);
        k_scan<<<dim3(4 * DI), 1024, 0, stream>>>(xc, pk, alog, dtw, dtb, ybuf);
        k_comb_proj<<<dim3(64), 256, 0, stream>>>(ybuf, xc, xz + 112 * L4, Dp, onw, onb, opw, xin, x_mid);
        k_ln56<<<dim3(64), 256, 0, stream>>>(x_mid, nw, nbv, xln, 1e-6f, 0);
        k_safm<<<dim3(266), 256, 0, stream>>>(xln, mw, mb, s0, s1, s2, s3);
        k_aggr<<<nb256(CC * L4), 256, 0, stream>>>(s0, s1, s2, s3, xln, x_mid, aw, ab, xout);
    }

    // tail
    k_gemm<<<gemm_grid(56), 256, 0, stream>>>(trunk, in23, in24, nullptr, bufB, 560, 56, 0);
    k_ln56<<<dim3(64), 256, 0, stream>>>(bufB, in25, in26, gB, 1e-6f, 1);
    k_gemm<<<gemm_grid(56), 256, 0, stream>>>(gB, in27, nullptr, nullptr, tbuf, 56, 56, 0);
    k_dw3x3t<<<dim3(CC * 16), 256, 0, stream>>>(tbuf, in28, in29, out_lr, 0, out_fea);
    k_up<<<dim3(256), 256, 0, stream>>>(out_lr, in30, in31, (float*)d_out);
}

// Round 10
// 1440.190 us; speedup vs baseline: 2.7544x; 1.0293x over previous
//
#include <hip/hip_runtime.h>
#include <hip/hip_bf16.h>

#define HW 64
#define L4 4096
#define CC 56
#define DI 112
#define DSN 16
#define NBLK 10

typedef const float* BP;

__device__ __forceinline__ float bf(BP p, int i) { return p[i]; }
__device__ __forceinline__ float siluf(float x) { return x / (1.f + __expf(-x)); }
__device__ __forceinline__ float geluf(float x) { return 0.5f * x * (1.f + erff(x * 0.70710678f)); }

// ---- stem: pointwise 3->56 ----
__global__ void k_fea_pw(BP x, BP w, float* __restrict__ t0) {
    int tid = blockIdx.x * blockDim.x + threadIdx.x;
    if (tid >= CC * L4) return;
    int c = tid >> 12, l = tid & 4095;
    float acc = 0.f;
    for (int i = 0; i < 3; ++i) acc += bf(x, i * L4 + l) * bf(w, c * 3 + i);
    t0[tid] = acc;
}

// ---- tiled depthwise 3x3 for 64x64 maps: grid = nch*16, block 256 (16x16 px) ----
__global__ void __launch_bounds__(256) k_dw3x3t(
        const float* __restrict__ src, BP w, BP bvec, float* __restrict__ dst,
        int act, const float* __restrict__ addsrc) {
    int c = blockIdx.x >> 4;
    int tile = blockIdx.x & 15;
    int y0 = (tile >> 2) * 16, x0 = (tile & 3) * 16;
    __shared__ float sT[18 * 18];
    const float* sc = src + (size_t)c * L4;
    for (int idx = threadIdx.x; idx < 324; idx += 256) {
        int iy = idx / 18, ix = idx - iy * 18;
        int gy = y0 - 1 + iy, gx = x0 - 1 + ix;
        sT[idx] = (gy >= 0 && gy < 64 && gx >= 0 && gx < 64) ? sc[gy * 64 + gx] : 0.f;
    }
    __syncthreads();
    int py = threadIdx.x >> 4, px = threadIdx.x & 15;
    BP wr = w + c * 9;
    float acc = bvec ? bvec[c] : 0.f;
    #pragma unroll
    for (int ky = 0; ky < 3; ++ky)
        #pragma unroll
        for (int kx = 0; kx < 3; ++kx)
            acc += sT[(py + ky) * 18 + px + kx] * wr[ky * 3 + kx];
    if (act) acc = siluf(acc);
    int l = (y0 + py) * 64 + x0 + px;
    if (addsrc) acc += addsrc[(size_t)c * L4 + l];
    dst[(size_t)c * L4 + l] = acc;
}

// ---- LDS-staged per-pixel layernorm over 56 channels: grid 64, block 256 ----
__global__ void __launch_bounds__(256) k_ln56(
        const float* __restrict__ src, BP w, BP b, float* __restrict__ dst,
        float eps, int gelu_after) {
    int lane = threadIdx.x & 63;
    int cg = threadIdx.x >> 6;
    int l0 = blockIdx.x * 64;
    __shared__ float sS[56 * 64];
    __shared__ float sPa[4][64], sPb[4][64];
    __shared__ float sMu[64], sRs[64];
    float ps = 0.f, ps2 = 0.f;
    for (int c = cg * 14; c < cg * 14 + 14; ++c) {
        float v = src[(size_t)c * L4 + l0 + lane];
        sS[c * 64 + lane] = v; ps += v; ps2 += v * v;
    }
    sPa[cg][lane] = ps; sPb[cg][lane] = ps2;
    __syncthreads();
    if (threadIdx.x < 64) {
        float s = sPa[0][lane] + sPa[1][lane] + sPa[2][lane] + sPa[3][lane];
        float s2 = sPb[0][lane] + sPb[1][lane] + sPb[2][lane] + sPb[3][lane];
        float mu = s / 56.f;
        float var = fmaxf(s2 / 56.f - mu * mu, 0.f);
        sMu[lane] = mu; sRs[lane] = rsqrtf(var + eps);
    }
    __syncthreads();
    float mu = sMu[lane], rs = sRs[lane];
    for (int c = cg * 14; c < cg * 14 + 14; ++c) {
        float v = (sS[c * 64 + lane] - mu) * rs * w[c] + b[c];
        if (gelu_after) v = geluf(v);
        dst[(size_t)c * L4 + l0 + lane] = v;
    }
}

// ---- LDS-staged channel GEMM; out_mode 1 uses LDS-staged coalesced scatter ----
__global__ void __launch_bounds__(256) k_gemm(
        const float* __restrict__ src, BP w, BP bvec, const float* __restrict__ addsrc,
        float* __restrict__ dst, int nin, int nout, int out_mode) {
    int lane = threadIdx.x & 63;
    int jg = threadIdx.x >> 6;
    int l0 = blockIdx.x * 64;
    int j0 = blockIdx.y * 16;
    __shared__ __align__(16) float sS[56 * 64];
    __shared__ __align__(16) float sw[16 * 56];
    float acc[4] = {0.f, 0.f, 0.f, 0.f};

    for (int i0 = 0; i0 < nin; i0 += 56) {
        __syncthreads();
        for (int idx = threadIdx.x; idx < 56 * 64; idx += 256) {
            int ii = idx >> 6, px = idx & 63;
            sS[idx] = src[(size_t)(i0 + ii) * L4 + l0 + px];
        }
        for (int idx = threadIdx.x; idx < 16 * 56; idx += 256) {
            int jj = idx / 56, ii = idx - jj * 56;
            int j = j0 + jj;
            sw[idx] = (j < nout) ? w[(size_t)j * nin + i0 + ii] : 0.f;
        }
        __syncthreads();
        #pragma unroll
        for (int ii = 0; ii < 56; ii += 4) {
            float s0 = sS[(ii + 0) * 64 + lane];
            float s1 = sS[(ii + 1) * 64 + lane];
            float s2 = sS[(ii + 2) * 64 + lane];
            float s3 = sS[(ii + 3) * 64 + lane];
            #pragma unroll
            for (int jj = 0; jj < 4; ++jj) {
                const float4 wv = *(const float4*)&sw[(jg * 4 + jj) * 56 + ii];
                acc[jj] += s0 * wv.x + s1 * wv.y + s2 * wv.z + s3 * wv.w;
            }
        }
    }
    if (out_mode == 0) {
        int l = l0 + lane;
        #pragma unroll
        for (int jj = 0; jj < 4; ++jj) {
            int j = j0 + jg * 4 + jj;
            if (j >= nout) continue;
            float v = acc[jj];
            if (bvec) v += bf(bvec, j);
            size_t idx = (size_t)j * L4 + l;
            if (addsrc) v += addsrc[idx];
            dst[idx] = v;
        }
    } else {
        // stage to LDS, write coalesced (c-fastest)
        __syncthreads();
        #pragma unroll
        for (int jj = 0; jj < 4; ++jj)
            sS[(jg * 4 + jj) * 64 + lane] = acc[jj];
        __syncthreads();
        for (int idx = threadIdx.x; idx < 16 * 64; idx += 256) {
            int cidx = idx & 15, l2 = idx >> 4;
            int j = j0 + cidx;
            int k = j / 36, c = j - k * 36;
            dst[((size_t)k * L4 + l0 + l2) * 36 + c] = sS[cidx * 64 + l2];
        }
    }
}

// ---- in-proj GEMM with fused LN (nin = 56, single K chunk) ----
__global__ void __launch_bounds__(256) k_gemm_ln(
        const float* __restrict__ src, BP lnw, BP lnb, BP w,
        float* __restrict__ dst, int nout) {
    int lane = threadIdx.x & 63;
    int jg = threadIdx.x >> 6;
    int l0 = blockIdx.x * 64;
    int j0 = blockIdx.y * 16;
    __shared__ __align__(16) float sS[56 * 64];
    __shared__ __align__(16) float sw[16 * 56];
    __shared__ float sLw[56], sLb[56];
    float acc[4] = {0.f, 0.f, 0.f, 0.f};

    for (int idx = threadIdx.x; idx < 56 * 64; idx += 256) {
        int ii = idx >> 6, px = idx & 63;
        sS[idx] = src[(size_t)ii * L4 + l0 + px];
    }
    for (int idx = threadIdx.x; idx < 16 * 56; idx += 256) {
        int jj = idx / 56, ii = idx - jj * 56;
        int j = j0 + jj;
        sw[idx] = (j < nout) ? w[(size_t)j * 56 + ii] : 0.f;
    }
    if (threadIdx.x < 56) { sLw[threadIdx.x] = lnw[threadIdx.x]; sLb[threadIdx.x] = lnb[threadIdx.x]; }
    __syncthreads();
    if (threadIdx.x < 64) {
        int px = threadIdx.x;
        float s = 0.f, s2 = 0.f;
        for (int ii = 0; ii < 56; ++ii) { float v = sS[ii * 64 + px]; s += v; s2 += v * v; }
        float mu = s / 56.f;
        float var = fmaxf(s2 / 56.f - mu * mu, 0.f);
        float rstd = rsqrtf(var + 1e-5f);
        for (int ii = 0; ii < 56; ++ii)
            sS[ii * 64 + px] = (sS[ii * 64 + px] - mu) * rstd * sLw[ii] + sLb[ii];
    }
    __syncthreads();
    #pragma unroll
    for (int ii = 0; ii < 56; ii += 4) {
        float s0 = sS[(ii + 0) * 64 + lane];
        float s1 = sS[(ii + 1) * 64 + lane];
        float s2 = sS[(ii + 2) * 64 + lane];
        float s3 = sS[(ii + 3) * 64 + lane];
        #pragma unroll
        for (int jj = 0; jj < 4; ++jj) {
            const float4 wv = *(const float4*)&sw[(jg * 4 + jj) * 56 + ii];
            acc[jj] += s0 * wv.x + s1 * wv.y + s2 * wv.z + s3 * wv.w;
        }
    }
    int l = l0 + lane;
    #pragma unroll
    for (int jj = 0; jj < 4; ++jj) {
        int j = j0 + jg * 4 + jj;
        if (j < nout) dst[(size_t)j * L4 + l] = acc[jj];
    }
}

// ---- chunked selective scan; per-direction pixel walk is affine: p = p0 + j*dp ----
#define SPAD(p) ((p) + ((p) >> 5))
__global__ void __launch_bounds__(1024) k_scan(
        const float* __restrict__ xc, const float* __restrict__ pk,
        BP Alog, BP dtw, BP dtb, float* __restrict__ ybuf) {
    int pair = blockIdx.x;           // k*112+d
    int n = threadIdx.x & 15;        // state index
    int c = threadIdx.x >> 4;        // chunk index, 0..63
    int k = pair / DI, d = pair - k * DI;
    float a = -__expf(Alog[pair * DSN + n]);
    float w0 = dtw[pair * 4 + 0], w1 = dtw[pair * 4 + 1];
    float w2 = dtw[pair * 4 + 2], w3 = dtw[pair * 4 + 3];
    float db = dtb[pair];
    const float* xptr = xc + (size_t)d * L4;
    const float* pkk = pk + (size_t)k * L4 * 36;
    float* yptr = ybuf + (size_t)pair * L4;

    __shared__ float sDl[4224];
    __shared__ float sDlx[4224];
    __shared__ float sP[64 * 16];
    __shared__ float sHe[64 * 16];
    __shared__ float sCar[64 * 16];

    // phase 0: cooperative delta precompute
    for (int p = threadIdx.x; p < L4; p += 1024) {
        const float* row = pkk + (size_t)p * 36;
        float v = db + row[0] * w0 + row[1] * w1 + row[2] * w2 + row[3] * w3;
        float dl = fmaxf(v, 0.f) + __logf(1.f + __expf(-fabsf(v)));
        sDl[SPAD(p)] = dl;
        sDlx[SPAD(p)] = dl * xptr[p];
    }
    __syncthreads();

    // affine walk params
    int p0, dp;
    if (k == 0)      { p0 = c * 64;        dp = 1;   }
    else if (k == 1) { p0 = c;             dp = 64;  }
    else if (k == 2) { p0 = 4095 - c * 64; dp = -1;  }
    else             { p0 = 4095 - c;      dp = -64; }
    long rstep = (long)dp * 36;

    // phase 1: local chunk scan from 0
    float h = 0.f, P = 1.f;
    {
        int p = p0;
        const float* rB = pkk + (size_t)p0 * 36 + 4 + n;
        #pragma unroll 4
        for (int j = 0; j < 64; ++j) {
            int q = SPAD(p);
            float e = __expf(sDl[q] * a);
            h = e * h + sDlx[q] * (*rB);
            P *= e;
            p += dp; rB += rstep;
        }
    }
    sP[c * 16 + n] = P;
    sHe[c * 16 + n] = h;
    __syncthreads();

    // phase 2: serial carry compose
    if (threadIdx.x < 16) {
        float H = 0.f;
        for (int cc = 0; cc < 64; ++cc) {
            sCar[cc * 16 + n] = H;
            H = sP[cc * 16 + n] * H + sHe[cc * 16 + n];
        }
    }
    __syncthreads();

    // phase 3: re-scan with carry, emit y
    h = sCar[c * 16 + n];
    {
        int p = p0;
        const float* rB = pkk + (size_t)p0 * 36 + 4 + n;
        const float* rC = pkk + (size_t)p0 * 36 + 20 + n;
        #pragma unroll 4
        for (int j = 0; j < 64; ++j) {
            int q = SPAD(p);
            float e = __expf(sDl[q] * a);
            h = e * h + sDlx[q] * (*rB);
            float y = h * (*rC);
            y += __shfl_xor(y, 1, 16);
            y += __shfl_xor(y, 2, 16);
            y += __shfl_xor(y, 4, 16);
            y += __shfl_xor(y, 8, 16);
            if (n == 0) yptr[p] = y;
            p += dp; rB += rstep; rC += rstep;
        }
    }
}

// ---- fused: combine 4 dirs + D*x, LN(112), silu(z) gate, out-proj + residual, LN56 ----
// grid 64 (l-tiles of 64), block 256 = 64 lanes x 4 cg
__global__ void __launch_bounds__(256) k_comb_proj(
        const float* __restrict__ ybuf, const float* __restrict__ xc,
        const float* __restrict__ zbuf, BP Dp, BP ow, BP ob, BP opw,
        const float* __restrict__ xin, BP nw, BP nbv,
        float* __restrict__ x_mid, float* __restrict__ xln) {
    int lane = threadIdx.x & 63;
    int cg = threadIdx.x >> 6;
    int l0 = blockIdx.x * 64;
    __shared__ __align__(16) float sY[112 * 64];   // 28 KB
    __shared__ __align__(16) float sW[56 * 112];   // 25 KB
    __shared__ float sPa[4][64], sPb[4][64];
    __shared__ float sMu[64], sRs[64];

    float ps = 0.f, ps2 = 0.f;
    for (int d = cg * 28; d < cg * 28 + 28; ++d) {
        float Ds = Dp[d] + Dp[DI + d] + Dp[2 * DI + d] + Dp[3 * DI + d];
        float v = ybuf[(size_t)d * L4 + l0 + lane]
                + ybuf[(size_t)(DI + d) * L4 + l0 + lane]
                + ybuf[(size_t)(2 * DI + d) * L4 + l0 + lane]
                + ybuf[(size_t)(3 * DI + d) * L4 + l0 + lane]
                + Ds * xc[(size_t)d * L4 + l0 + lane];
        sY[d * 64 + lane] = v; ps += v; ps2 += v * v;
    }
    sPa[cg][lane] = ps; sPb[cg][lane] = ps2;
    for (int idx = threadIdx.x; idx < 56 * 112; idx += 256) sW[idx] = opw[idx];
    __syncthreads();
    if (threadIdx.x < 64) {
        float s = sPa[0][lane] + sPa[1][lane] + sPa[2][lane] + sPa[3][lane];
        float s2 = sPb[0][lane] + sPb[1][lane] + sPb[2][lane] + sPb[3][lane];
        float mu = s / 112.f;
        float var = fmaxf(s2 / 112.f - mu * mu, 0.f);
        sMu[lane] = mu; sRs[lane] = rsqrtf(var + 1e-5f);
    }
    __syncthreads();
    {
        float mu = sMu[lane], rs = sRs[lane];
        for (int d = cg * 28; d < cg * 28 + 28; ++d) {
            float v = (sY[d * 64 + lane] - mu) * rs * ow[d] + ob[d];
            float z = zbuf[(size_t)d * L4 + l0 + lane];
            sY[d * 64 + lane] = v * siluf(z);
        }
    }
    __syncthreads();

    float acc[14];
    #pragma unroll
    for (int jj = 0; jj < 14; ++jj) acc[jj] = 0.f;
    #pragma unroll 2
    for (int ii = 0; ii < 112; ii += 4) {
        float s0 = sY[(ii + 0) * 64 + lane];
        float s1 = sY[(ii + 1) * 64 + lane];
        float s2 = sY[(ii + 2) * 64 + lane];
        float s3 = sY[(ii + 3) * 64 + lane];
        #pragma unroll
        for (int jj = 0; jj < 14; ++jj) {
            const float4 wv = *(const float4*)&sW[(cg * 14 + jj) * 112 + ii];
            acc[jj] += s0 * wv.x + s1 * wv.y + s2 * wv.z + s3 * wv.w;
        }
    }
    int l = l0 + lane;
    float ps3 = 0.f, ps4 = 0.f;
    #pragma unroll
    for (int jj = 0; jj < 14; ++jj) {
        int j = cg * 14 + jj;
        float v = acc[jj] + xin[(size_t)j * L4 + l];
        acc[jj] = v;
        x_mid[(size_t)j * L4 + l] = v;
        ps3 += v; ps4 += v * v;
    }
    __syncthreads();
    sPa[cg][lane] = ps3; sPb[cg][lane] = ps4;
    __syncthreads();
    if (threadIdx.x < 64) {
        float s = sPa[0][lane] + sPa[1][lane] + sPa[2][lane] + sPa[3][lane];
        float s2 = sPb[0][lane] + sPb[1][lane] + sPb[2][lane] + sPb[3][lane];
        float mu = s / 56.f;
        float var = fmaxf(s2 / 56.f - mu * mu, 0.f);
        sMu[lane] = mu; sRs[lane] = rsqrtf(var + 1e-6f);
    }
    __syncthreads();
    {
        float mu = sMu[lane], rs = sRs[lane];
        #pragma unroll
        for (int jj = 0; jj < 14; ++jj) {
            int j = cg * 14 + jj;
            xln[(size_t)j * L4 + l] = (acc[jj] - mu) * rs * nw[j] + nbv[j];
        }
    }
}

// ---- fused SAFM pools+depthwise: grid 224 (i=0 tiles) + 42 (i>=1 channels) ----
__global__ void __launch_bounds__(256) k_safm(
        const float* __restrict__ xln, BP mw, BP mb,
        float* __restrict__ s0, float* __restrict__ s1,
        float* __restrict__ s2, float* __restrict__ s3) {
    int b = blockIdx.x;
    if (b < 224) {
        int c = b >> 4;
        int tile = b & 15;
        int y0 = (tile >> 2) * 16, x0 = (tile & 3) * 16;
        __shared__ float sT[18 * 18];
        const float* sc = xln + (size_t)c * L4;
        for (int idx = threadIdx.x; idx < 324; idx += 256) {
            int iy = idx / 18, ix = idx - iy * 18;
            int gy = y0 - 1 + iy, gx = x0 - 1 + ix;
            sT[idx] = (gy >= 0 && gy < 64 && gx >= 0 && gx < 64) ? sc[gy * 64 + gx] : 0.f;
        }
        __syncthreads();
        int py = threadIdx.x >> 4, px = threadIdx.x & 15;
        BP wr = mw + c * 9;
        float acc = mb[c];
        #pragma unroll
        for (int ky = 0; ky < 3; ++ky)
            #pragma unroll
            for (int kx = 0; kx < 3; ++kx)
                acc += sT[(py + ky) * 18 + px + kx] * wr[ky * 3 + kx];
        s0[c * L4 + (y0 + py) * 64 + x0 + px] = acc;
    } else {
        int bb = b - 224;
        int i = bb / 14 + 1;
        int c = bb % 14;
        int S = 64 >> i;
        int f = 1 << i;
        __shared__ float sP[34 * 34];
        int W2 = S + 2;
        for (int idx = threadIdx.x; idx < W2 * W2; idx += 256) sP[idx] = 0.f;
        __syncthreads();
        const float* sc = xln + (size_t)(i * 14 + c) * L4;
        for (int cell = threadIdx.x; cell < S * S; cell += 256) {
            int y = cell / S, x = cell - y * S;
            float m = -3.4e38f;
            for (int dy = 0; dy < f; ++dy)
                for (int dx = 0; dx < f; ++dx)
                    m = fmaxf(m, sc[(y * f + dy) * 64 + x * f + dx]);
            sP[(y + 1) * W2 + x + 1] = m;
        }
        __syncthreads();
        BP wr = mw + (i * 14 + c) * 9;
        float bias = mb[i * 14 + c];
        float* dst = (i == 1) ? s1 : (i == 2) ? s2 : s3;
        for (int cell = threadIdx.x; cell < S * S; cell += 256) {
            int y = cell / S, x = cell - y * S;
            float acc = bias;
            #pragma unroll
            for (int ky = 0; ky < 3; ++ky)
                #pragma unroll
                for (int kx = 0; kx < 3; ++kx)
                    acc += sP[(y + ky) * W2 + x + kx] * wr[ky * 3 + kx];
            dst[c * S * S + cell] = acc;
        }
    }
}

// ---- SAFM aggregate 1x1 + gelu gate + residual, writes trunk slice ----
__global__ void k_aggr(const float* __restrict__ s0, const float* __restrict__ s1,
                       const float* __restrict__ s2, const float* __restrict__ s3,
                       const float* __restrict__ xln, const float* __restrict__ x_mid,
                       BP aw, BP ab, float* __restrict__ out) {
    int tid = blockIdx.x * blockDim.x + threadIdx.x;
    if (tid >= CC * L4) return;
    int c = tid >> 12, l = tid & 4095;
    int h = l >> 6, w = l & 63;
    int o1 = (h >> 1) * 32 + (w >> 1);
    int o2 = (h >> 2) * 16 + (w >> 2);
    int o3 = (h >> 3) * 8 + (w >> 3);
    float acc = bf(ab, c);
    BP wr = aw + c * 56;
    for (int cg = 0; cg < 14; ++cg) acc += s0[cg * 4096 + l]  * bf(wr, cg);
    for (int cg = 0; cg < 14; ++cg) acc += s1[cg * 1024 + o1] * bf(wr, 14 + cg);
    for (int cg = 0; cg < 14; ++cg) acc += s2[cg * 256 + o2]  * bf(wr, 28 + cg);
    for (int cg = 0; cg < 14; ++cg) acc += s3[cg * 64 + o3]   * bf(wr, 42 + cg);
    out[tid] = x_mid[tid] + geluf(acc) * xln[tid];
}

// ---- up conv 3x3 (56->27) + pixel shuffle x3, LDS-staged, fp32 output ----
__global__ void __launch_bounds__(256) k_up(
        const float* __restrict__ out_lr, BP uw, BP ub, float* __restrict__ out) {
    __shared__ float sIn[56 * 36];
    __shared__ float sW[27 * 56 * 9];
    int b = blockIdx.x;
    int y0 = (b >> 4) * 4, x0 = (b & 15) * 4;
    for (int idx = threadIdx.x; idx < 56 * 36; idx += 256) {
        int cc = idx / 36; int rem = idx - cc * 36; int iy = rem / 6, ix = rem - iy * 6;
        int gy = y0 - 1 + iy, gx = x0 - 1 + ix;
        sIn[idx] = (gy >= 0 && gy < 64 && gx >= 0 && gx < 64)
                 ? out_lr[(size_t)cc * L4 + gy * 64 + gx] : 0.f;
    }
    for (int idx = threadIdx.x; idx < 27 * 56 * 9; idx += 256) sW[idx] = uw[idx];
    __syncthreads();
    int px = threadIdx.x & 15;
    int og = threadIdx.x >> 4;
    int dy = px >> 2, dx = px & 3;
    for (int oo = 0; oo < 2; ++oo) {
        int o = og * 2 + oo;
        if (o >= 27) break;
        float acc = ub[o];
        const float* wb = &sW[o * 504];
        for (int cc = 0; cc < 56; ++cc) {
            const float* ib = &sIn[cc * 36 + dy * 6 + dx];
            const float* wc = wb + cc * 9;
            acc += ib[0] * wc[0] + ib[1] * wc[1] + ib[2] * wc[2]
                 + ib[6] * wc[3] + ib[7] * wc[4] + ib[8] * wc[5]
                 + ib[12] * wc[6] + ib[13] * wc[7] + ib[14] * wc[8];
        }
        int h = y0 + dy, wv = x0 + dx;
        int ch = o / 9, rr = (o % 9) / 3, ss = o % 3;
        out[ch * 36864 + (h * 3 + rr) * 192 + (wv * 3 + ss)] = acc;
    }
}

extern "C" void kernel_launch(void* const* d_in, const int* in_sizes, int n_in,
                              void* d_out, int out_size, void* d_ws, size_t ws_size,
                              hipStream_t stream) {
    BP in0  = (BP)d_in[0];
    BP in1  = (BP)d_in[1];
    BP in2  = (BP)d_in[2];
    BP in3  = (BP)d_in[3];
    BP in4  = (BP)d_in[4];
    BP in5  = (BP)d_in[5];
    BP in6  = (BP)d_in[6];
    BP in7  = (BP)d_in[7];
    BP in8  = (BP)d_in[8];
    BP in9  = (BP)d_in[9];
    BP in10 = (BP)d_in[10];
    BP in11 = (BP)d_in[11];
    BP in12 = (BP)d_in[12];
    BP in13 = (BP)d_in[13];
    BP in14 = (BP)d_in[14];
    BP in15 = (BP)d_in[15];
    BP in16 = (BP)d_in[16];
    BP in17 = (BP)d_in[17];
    BP in18 = (BP)d_in[18];
    BP in19 = (BP)d_in[19];
    BP in20 = (BP)d_in[20];
    BP in21 = (BP)d_in[21];
    BP in22 = (BP)d_in[22];
    BP in23 = (BP)d_in[23];
    BP in24 = (BP)d_in[24];
    BP in25 = (BP)d_in[25];
    BP in26 = (BP)d_in[26];
    BP in27 = (BP)d_in[27];
    BP in28 = (BP)d_in[28];
    BP in29 = (BP)d_in[29];
    BP in30 = (BP)d_in[30];
    BP in31 = (BP)d_in[31];

    float* ws = (float*)d_ws;
    float* trunk   = ws; ws += 560 * L4;
    float* out_fea = ws; ws += CC * L4;
    float* t0      = ws; ws += CC * L4;
    float* xz      = ws; ws += 224 * L4;
    float* xc      = ws; ws += DI * L4;
    float* pk      = ws; ws += 4 * 36 * L4;
    float* ybuf    = ws; ws += 4 * DI * L4;
    float* x_mid   = ws; ws += CC * L4;
    float* xln     = ws; ws += CC * L4;
    float* s0      = ws; ws += 14 * 4096;
    float* s1      = ws; ws += 14 * 1024;
    float* s2      = ws; ws += 14 * 256;
    float* s3      = ws; ws += 14 * 64;
    float* bufB    = ws; ws += CC * L4;
    float* gB      = ws; ws += CC * L4;
    float* tbuf    = ws; ws += CC * L4;
    float* out_lr  = ws; ws += CC * L4;

    auto nb256 = [](int n) { return dim3((n + 255) / 256); };
    auto gemm_grid = [](int nout) { return dim3(64, (nout + 15) / 16); };

    // stem
    k_fea_pw<<<nb256(CC * L4), 256, 0, stream>>>(in0, in1, t0);
    k_dw3x3t<<<dim3(CC * 16), 256, 0, stream>>>(t0, in2, in3, out_fea, 0, nullptr);

    for (int nb = 0; nb < NBLK; ++nb) {
        const float* xin = (nb == 0) ? out_fea : trunk + (size_t)(nb - 1) * CC * L4;
        float* xout = trunk + (size_t)nb * CC * L4;
        BP ln1w = in4 + nb * 56,        ln1b = in5 + nb * 56;
        BP ipw  = in6 + nb * 224 * 56;
        BP cw   = in7 + nb * 112 * 9,   cb   = in8 + nb * 112;
        BP xpw  = in9 + nb * 4 * 36 * 112;
        BP dtw  = in10 + nb * 4 * 112 * 4, dtb = in11 + nb * 448;
        BP alog = in12 + nb * 448 * 16, Dp   = in13 + nb * 448;
        BP onw  = in14 + nb * 112,      onb  = in15 + nb * 112;
        BP opw  = in16 + nb * 56 * 112;
        BP nw   = in17 + nb * 56,       nbv  = in18 + nb * 56;
        BP mw   = in19 + nb * 4 * 14 * 9, mb = in20 + nb * 56;
        BP aw   = in21 + nb * 56 * 56,  ab   = in22 + nb * 56;

        k_gemm_ln<<<gemm_grid(224), 256, 0, stream>>>(xin, ln1w, ln1b, ipw, xz, 224);
        k_dw3x3t<<<dim3(DI * 16), 256, 0, stream>>>(xz, cw, cb, xc, 1, nullptr);
        k_gemm<<<gemm_grid(144), 256, 0, stream>>>(xc, xpw, nullptr, nullptr, pk, 112, 144, 1);
        k_scan<<<dim3(4 * DI), 1024, 0, stream>>>(xc, pk, alog, dtw, dtb, ybuf);
        k_comb_proj<<<dim3(64), 256, 0, stream>>>(ybuf, xc, xz + 112 * L4, Dp, onw, onb, opw,
                                                  xin, nw, nbv, x_mid, xln);
        k_safm<<<dim3(266), 256, 0, stream>>>(xln, mw, mb, s0, s1, s2, s3);
        k_aggr<<<nb256(CC * L4), 256, 0, stream>>>(s0, s1, s2, s3, xln, x_mid, aw, ab, xout);
    }

    // tail
    k_gemm<<<gemm_grid(56), 256, 0, stream>>>(trunk, in23, in24, nullptr, bufB, 560, 56, 0);
    k_ln56<<<dim3(64), 256, 0, stream>>>(bufB, in25, in26, gB, 1e-6f, 1);
    k_gemm<<<gemm_grid(56), 256, 0, stream>>>(gB, in27, nullptr, nullptr, tbuf, 56, 56, 0);
    k_dw3x3t<<<dim3(CC * 16), 256, 0, stream>>>(tbuf, in28, in29, out_lr, 0, out_fea);
    k_up<<<dim3(256), 256, 0, stream>>>(out_lr, in30, in31, (float*)d_out);
}

// Round 11
// 1407.353 us; speedup vs baseline: 2.8186x; 1.0233x over previous
//
#include <hip/hip_runtime.h>
#include <hip/hip_bf16.h>

#define HW 64
#define L4 4096
#define CC 56
#define DI 112
#define DSN 16
#define NBLK 10

typedef const float* BP;

__device__ __forceinline__ float bf(BP p, int i) { return p[i]; }
__device__ __forceinline__ float siluf(float x) { return x / (1.f + __expf(-x)); }
__device__ __forceinline__ float geluf(float x) { return 0.5f * x * (1.f + erff(x * 0.70710678f)); }

// ---- stem: pointwise 3->56 ----
__global__ void k_fea_pw(BP x, BP w, float* __restrict__ t0) {
    int tid = blockIdx.x * blockDim.x + threadIdx.x;
    if (tid >= CC * L4) return;
    int c = tid >> 12, l = tid & 4095;
    float acc = 0.f;
    for (int i = 0; i < 3; ++i) acc += bf(x, i * L4 + l) * bf(w, c * 3 + i);
    t0[tid] = acc;
}

// ---- tiled depthwise 3x3 for 64x64 maps: grid = nch*16, block 256 (16x16 px) ----
__global__ void __launch_bounds__(256) k_dw3x3t(
        const float* __restrict__ src, BP w, BP bvec, float* __restrict__ dst,
        int act, const float* __restrict__ addsrc) {
    int c = blockIdx.x >> 4;
    int tile = blockIdx.x & 15;
    int y0 = (tile >> 2) * 16, x0 = (tile & 3) * 16;
    __shared__ float sT[18 * 18];
    const float* sc = src + (size_t)c * L4;
    for (int idx = threadIdx.x; idx < 324; idx += 256) {
        int iy = idx / 18, ix = idx - iy * 18;
        int gy = y0 - 1 + iy, gx = x0 - 1 + ix;
        sT[idx] = (gy >= 0 && gy < 64 && gx >= 0 && gx < 64) ? sc[gy * 64 + gx] : 0.f;
    }
    __syncthreads();
    int py = threadIdx.x >> 4, px = threadIdx.x & 15;
    BP wr = w + c * 9;
    float acc = bvec ? bvec[c] : 0.f;
    #pragma unroll
    for (int ky = 0; ky < 3; ++ky)
        #pragma unroll
        for (int kx = 0; kx < 3; ++kx)
            acc += sT[(py + ky) * 18 + px + kx] * wr[ky * 3 + kx];
    if (act) acc = siluf(acc);
    int l = (y0 + py) * 64 + x0 + px;
    if (addsrc) acc += addsrc[(size_t)c * L4 + l];
    dst[(size_t)c * L4 + l] = acc;
}

// ---- LDS-staged per-pixel layernorm over 56 channels: grid 64, block 256 ----
__global__ void __launch_bounds__(256) k_ln56(
        const float* __restrict__ src, BP w, BP b, float* __restrict__ dst,
        float eps, int gelu_after) {
    int lane = threadIdx.x & 63;
    int cg = threadIdx.x >> 6;
    int l0 = blockIdx.x * 64;
    __shared__ float sS[56 * 64];
    __shared__ float sPa[4][64], sPb[4][64];
    __shared__ float sMu[64], sRs[64];
    float ps = 0.f, ps2 = 0.f;
    for (int c = cg * 14; c < cg * 14 + 14; ++c) {
        float v = src[(size_t)c * L4 + l0 + lane];
        sS[c * 64 + lane] = v; ps += v; ps2 += v * v;
    }
    sPa[cg][lane] = ps; sPb[cg][lane] = ps2;
    __syncthreads();
    if (threadIdx.x < 64) {
        float s = sPa[0][lane] + sPa[1][lane] + sPa[2][lane] + sPa[3][lane];
        float s2 = sPb[0][lane] + sPb[1][lane] + sPb[2][lane] + sPb[3][lane];
        float mu = s / 56.f;
        float var = fmaxf(s2 / 56.f - mu * mu, 0.f);
        sMu[lane] = mu; sRs[lane] = rsqrtf(var + eps);
    }
    __syncthreads();
    float mu = sMu[lane], rs = sRs[lane];
    for (int c = cg * 14; c < cg * 14 + 14; ++c) {
        float v = (sS[c * 64 + lane] - mu) * rs * w[c] + b[c];
        if (gelu_after) v = geluf(v);
        dst[(size_t)c * L4 + l0 + lane] = v;
    }
}

// ---- LDS-staged channel GEMM (out_mode 0 only; nin % 56 == 0) ----
__global__ void __launch_bounds__(256) k_gemm(
        const float* __restrict__ src, BP w, BP bvec, const float* __restrict__ addsrc,
        float* __restrict__ dst, int nin, int nout) {
    int lane = threadIdx.x & 63;
    int jg = threadIdx.x >> 6;
    int l0 = blockIdx.x * 64;
    int j0 = blockIdx.y * 16;
    __shared__ __align__(16) float sS[56 * 64];
    __shared__ __align__(16) float sw[16 * 56];
    float acc[4] = {0.f, 0.f, 0.f, 0.f};

    for (int i0 = 0; i0 < nin; i0 += 56) {
        __syncthreads();
        for (int idx = threadIdx.x; idx < 56 * 64; idx += 256) {
            int ii = idx >> 6, px = idx & 63;
            sS[idx] = src[(size_t)(i0 + ii) * L4 + l0 + px];
        }
        for (int idx = threadIdx.x; idx < 16 * 56; idx += 256) {
            int jj = idx / 56, ii = idx - jj * 56;
            int j = j0 + jj;
            sw[idx] = (j < nout) ? w[(size_t)j * nin + i0 + ii] : 0.f;
        }
        __syncthreads();
        #pragma unroll
        for (int ii = 0; ii < 56; ii += 4) {
            float s0 = sS[(ii + 0) * 64 + lane];
            float s1 = sS[(ii + 1) * 64 + lane];
            float s2 = sS[(ii + 2) * 64 + lane];
            float s3 = sS[(ii + 3) * 64 + lane];
            #pragma unroll
            for (int jj = 0; jj < 4; ++jj) {
                const float4 wv = *(const float4*)&sw[(jg * 4 + jj) * 56 + ii];
                acc[jj] += s0 * wv.x + s1 * wv.y + s2 * wv.z + s3 * wv.w;
            }
        }
    }
    int l = l0 + lane;
    #pragma unroll
    for (int jj = 0; jj < 4; ++jj) {
        int j = j0 + jg * 4 + jj;
        if (j >= nout) continue;
        float v = acc[jj];
        if (bvec) v += bf(bvec, j);
        size_t idx = (size_t)j * L4 + l;
        if (addsrc) v += addsrc[idx];
        dst[idx] = v;
    }
}

// ---- x-projection 112->144, 32-px tiles, single K-chunk, high TLP ----
// grid (128, 9) = 1152 blocks; block 256 = 32 px x 8 jg x 2 outputs
__global__ void __launch_bounds__(256) k_xproj(
        const float* __restrict__ src, BP w, float* __restrict__ dst) {
    int lane = threadIdx.x & 31;
    int jg = threadIdx.x >> 5;           // 0..7
    int l0 = blockIdx.x * 32;
    int j0 = blockIdx.y * 16;            // 144 = 9*16, no bounds checks
    __shared__ __align__(16) float sS[112 * 32];   // 14336 B
    __shared__ __align__(16) float sw[16 * 112];   // 7168 B
    float acc[2] = {0.f, 0.f};

    for (int idx = threadIdx.x; idx < 112 * 32; idx += 256) {
        int ii = idx >> 5, px = idx & 31;
        sS[idx] = src[(size_t)ii * L4 + l0 + px];
    }
    for (int idx = threadIdx.x; idx < 16 * 112; idx += 256) {
        int jj = idx / 112, ii = idx - jj * 112;
        sw[idx] = w[(size_t)(j0 + jj) * 112 + ii];
    }
    __syncthreads();
    #pragma unroll
    for (int ii = 0; ii < 112; ii += 4) {
        float s0 = sS[(ii + 0) * 32 + lane];
        float s1 = sS[(ii + 1) * 32 + lane];
        float s2 = sS[(ii + 2) * 32 + lane];
        float s3 = sS[(ii + 3) * 32 + lane];
        #pragma unroll
        for (int jj = 0; jj < 2; ++jj) {
            const float4 wv = *(const float4*)&sw[(jg * 2 + jj) * 112 + ii];
            acc[jj] += s0 * wv.x + s1 * wv.y + s2 * wv.z + s3 * wv.w;
        }
    }
    // stage results, write coalesced (c-fastest, 64B segments)
    __syncthreads();
    #pragma unroll
    for (int jj = 0; jj < 2; ++jj)
        sS[(jg * 2 + jj) * 32 + lane] = acc[jj];
    __syncthreads();
    for (int idx = threadIdx.x; idx < 16 * 32; idx += 256) {
        int cidx = idx & 15, l2 = idx >> 4;
        int j = j0 + cidx;
        int k = j / 36, c = j - k * 36;
        dst[((size_t)k * L4 + l0 + l2) * 36 + c] = sS[cidx * 32 + l2];
    }
}

// ---- in-proj GEMM with fused LN (nin = 56, single K chunk) ----
__global__ void __launch_bounds__(256) k_gemm_ln(
        const float* __restrict__ src, BP lnw, BP lnb, BP w,
        float* __restrict__ dst, int nout) {
    int lane = threadIdx.x & 63;
    int jg = threadIdx.x >> 6;
    int l0 = blockIdx.x * 64;
    int j0 = blockIdx.y * 16;
    __shared__ __align__(16) float sS[56 * 64];
    __shared__ __align__(16) float sw[16 * 56];
    __shared__ float sLw[56], sLb[56];
    float acc[4] = {0.f, 0.f, 0.f, 0.f};

    for (int idx = threadIdx.x; idx < 56 * 64; idx += 256) {
        int ii = idx >> 6, px = idx & 63;
        sS[idx] = src[(size_t)ii * L4 + l0 + px];
    }
    for (int idx = threadIdx.x; idx < 16 * 56; idx += 256) {
        int jj = idx / 56, ii = idx - jj * 56;
        int j = j0 + jj;
        sw[idx] = (j < nout) ? w[(size_t)j * 56 + ii] : 0.f;
    }
    if (threadIdx.x < 56) { sLw[threadIdx.x] = lnw[threadIdx.x]; sLb[threadIdx.x] = lnb[threadIdx.x]; }
    __syncthreads();
    if (threadIdx.x < 64) {
        int px = threadIdx.x;
        float s = 0.f, s2 = 0.f;
        for (int ii = 0; ii < 56; ++ii) { float v = sS[ii * 64 + px]; s += v; s2 += v * v; }
        float mu = s / 56.f;
        float var = fmaxf(s2 / 56.f - mu * mu, 0.f);
        float rstd = rsqrtf(var + 1e-5f);
        for (int ii = 0; ii < 56; ++ii)
            sS[ii * 64 + px] = (sS[ii * 64 + px] - mu) * rstd * sLw[ii] + sLb[ii];
    }
    __syncthreads();
    #pragma unroll
    for (int ii = 0; ii < 56; ii += 4) {
        float s0 = sS[(ii + 0) * 64 + lane];
        float s1 = sS[(ii + 1) * 64 + lane];
        float s2 = sS[(ii + 2) * 64 + lane];
        float s3 = sS[(ii + 3) * 64 + lane];
        #pragma unroll
        for (int jj = 0; jj < 4; ++jj) {
            const float4 wv = *(const float4*)&sw[(jg * 4 + jj) * 56 + ii];
            acc[jj] += s0 * wv.x + s1 * wv.y + s2 * wv.z + s3 * wv.w;
        }
    }
    int l = l0 + lane;
    #pragma unroll
    for (int jj = 0; jj < 4; ++jj) {
        int j = j0 + jg * 4 + jj;
        if (j < nout) dst[(size_t)j * L4 + l] = acc[jj];
    }
}

// ---- chunked selective scan; per-direction pixel walk is affine: p = p0 + j*dp ----
#define SPAD(p) ((p) + ((p) >> 5))
__global__ void __launch_bounds__(1024) k_scan(
        const float* __restrict__ xc, const float* __restrict__ pk,
        BP Alog, BP dtw, BP dtb, float* __restrict__ ybuf) {
    int pair = blockIdx.x;           // k*112+d
    int n = threadIdx.x & 15;        // state index
    int c = threadIdx.x >> 4;        // chunk index, 0..63
    int k = pair / DI, d = pair - k * DI;
    float a = -__expf(Alog[pair * DSN + n]);
    float w0 = dtw[pair * 4 + 0], w1 = dtw[pair * 4 + 1];
    float w2 = dtw[pair * 4 + 2], w3 = dtw[pair * 4 + 3];
    float db = dtb[pair];
    const float* xptr = xc + (size_t)d * L4;
    const float* pkk = pk + (size_t)k * L4 * 36;
    float* yptr = ybuf + (size_t)pair * L4;

    __shared__ float sDl[4224];
    __shared__ float sDlx[4224];
    __shared__ float sP[64 * 16];
    __shared__ float sHe[64 * 16];
    __shared__ float sCar[64 * 16];

    for (int p = threadIdx.x; p < L4; p += 1024) {
        const float* row = pkk + (size_t)p * 36;
        float v = db + row[0] * w0 + row[1] * w1 + row[2] * w2 + row[3] * w3;
        float dl = fmaxf(v, 0.f) + __logf(1.f + __expf(-fabsf(v)));
        sDl[SPAD(p)] = dl;
        sDlx[SPAD(p)] = dl * xptr[p];
    }
    __syncthreads();

    int p0, dp;
    if (k == 0)      { p0 = c * 64;        dp = 1;   }
    else if (k == 1) { p0 = c;             dp = 64;  }
    else if (k == 2) { p0 = 4095 - c * 64; dp = -1;  }
    else             { p0 = 4095 - c;      dp = -64; }
    long rstep = (long)dp * 36;

    float h = 0.f, P = 1.f;
    {
        int p = p0;
        const float* rB = pkk + (size_t)p0 * 36 + 4 + n;
        #pragma unroll 4
        for (int j = 0; j < 64; ++j) {
            int q = SPAD(p);
            float e = __expf(sDl[q] * a);
            h = e * h + sDlx[q] * (*rB);
            P *= e;
            p += dp; rB += rstep;
        }
    }
    sP[c * 16 + n] = P;
    sHe[c * 16 + n] = h;
    __syncthreads();

    if (threadIdx.x < 16) {
        float H = 0.f;
        for (int cc = 0; cc < 64; ++cc) {
            sCar[cc * 16 + n] = H;
            H = sP[cc * 16 + n] * H + sHe[cc * 16 + n];
        }
    }
    __syncthreads();

    h = sCar[c * 16 + n];
    {
        int p = p0;
        const float* rB = pkk + (size_t)p0 * 36 + 4 + n;
        const float* rC = pkk + (size_t)p0 * 36 + 20 + n;
        #pragma unroll 4
        for (int j = 0; j < 64; ++j) {
            int q = SPAD(p);
            float e = __expf(sDl[q] * a);
            h = e * h + sDlx[q] * (*rB);
            float y = h * (*rC);
            y += __shfl_xor(y, 1, 16);
            y += __shfl_xor(y, 2, 16);
            y += __shfl_xor(y, 4, 16);
            y += __shfl_xor(y, 8, 16);
            if (n == 0) yptr[p] = y;
            p += dp; rB += rstep; rC += rstep;
        }
    }
}

// ---- fused: combine 4 dirs + D*x, LN(112), silu(z) gate, out-proj + residual, LN56 ----
__global__ void __launch_bounds__(256) k_comb_proj(
        const float* __restrict__ ybuf, const float* __restrict__ xc,
        const float* __restrict__ zbuf, BP Dp, BP ow, BP ob, BP opw,
        const float* __restrict__ xin, BP nw, BP nbv,
        float* __restrict__ x_mid, float* __restrict__ xln) {
    int lane = threadIdx.x & 63;
    int cg = threadIdx.x >> 6;
    int l0 = blockIdx.x * 64;
    __shared__ __align__(16) float sY[112 * 64];
    __shared__ __align__(16) float sW[56 * 112];
    __shared__ float sPa[4][64], sPb[4][64];
    __shared__ float sMu[64], sRs[64];

    float ps = 0.f, ps2 = 0.f;
    for (int d = cg * 28; d < cg * 28 + 28; ++d) {
        float Ds = Dp[d] + Dp[DI + d] + Dp[2 * DI + d] + Dp[3 * DI + d];
        float v = ybuf[(size_t)d * L4 + l0 + lane]
                + ybuf[(size_t)(DI + d) * L4 + l0 + lane]
                + ybuf[(size_t)(2 * DI + d) * L4 + l0 + lane]
                + ybuf[(size_t)(3 * DI + d) * L4 + l0 + lane]
                + Ds * xc[(size_t)d * L4 + l0 + lane];
        sY[d * 64 + lane] = v; ps += v; ps2 += v * v;
    }
    sPa[cg][lane] = ps; sPb[cg][lane] = ps2;
    for (int idx = threadIdx.x; idx < 56 * 112; idx += 256) sW[idx] = opw[idx];
    __syncthreads();
    if (threadIdx.x < 64) {
        float s = sPa[0][lane] + sPa[1][lane] + sPa[2][lane] + sPa[3][lane];
        float s2 = sPb[0][lane] + sPb[1][lane] + sPb[2][lane] + sPb[3][lane];
        float mu = s / 112.f;
        float var = fmaxf(s2 / 112.f - mu * mu, 0.f);
        sMu[lane] = mu; sRs[lane] = rsqrtf(var + 1e-5f);
    }
    __syncthreads();
    {
        float mu = sMu[lane], rs = sRs[lane];
        for (int d = cg * 28; d < cg * 28 + 28; ++d) {
            float v = (sY[d * 64 + lane] - mu) * rs * ow[d] + ob[d];
            float z = zbuf[(size_t)d * L4 + l0 + lane];
            sY[d * 64 + lane] = v * siluf(z);
        }
    }
    __syncthreads();

    float acc[14];
    #pragma unroll
    for (int jj = 0; jj < 14; ++jj) acc[jj] = 0.f;
    #pragma unroll 2
    for (int ii = 0; ii < 112; ii += 4) {
        float s0 = sY[(ii + 0) * 64 + lane];
        float s1 = sY[(ii + 1) * 64 + lane];
        float s2 = sY[(ii + 2) * 64 + lane];
        float s3 = sY[(ii + 3) * 64 + lane];
        #pragma unroll
        for (int jj = 0; jj < 14; ++jj) {
            const float4 wv = *(const float4*)&sW[(cg * 14 + jj) * 112 + ii];
            acc[jj] += s0 * wv.x + s1 * wv.y + s2 * wv.z + s3 * wv.w;
        }
    }
    int l = l0 + lane;
    float ps3 = 0.f, ps4 = 0.f;
    #pragma unroll
    for (int jj = 0; jj < 14; ++jj) {
        int j = cg * 14 + jj;
        float v = acc[jj] + xin[(size_t)j * L4 + l];
        acc[jj] = v;
        x_mid[(size_t)j * L4 + l] = v;
        ps3 += v; ps4 += v * v;
    }
    __syncthreads();
    sPa[cg][lane] = ps3; sPb[cg][lane] = ps4;
    __syncthreads();
    if (threadIdx.x < 64) {
        float s = sPa[0][lane] + sPa[1][lane] + sPa[2][lane] + sPa[3][lane];
        float s2 = sPb[0][lane] + sPb[1][lane] + sPb[2][lane] + sPb[3][lane];
        float mu = s / 56.f;
        float var = fmaxf(s2 / 56.f - mu * mu, 0.f);
        sMu[lane] = mu; sRs[lane] = rsqrtf(var + 1e-6f);
    }
    __syncthreads();
    {
        float mu = sMu[lane], rs = sRs[lane];
        #pragma unroll
        for (int jj = 0; jj < 14; ++jj) {
            int j = cg * 14 + jj;
            xln[(size_t)j * L4 + l] = (acc[jj] - mu) * rs * nw[j] + nbv[j];
        }
    }
}

// ---- fused SAFM pools+depthwise: grid 224 (i=0 tiles) + 42 (i>=1 channels) ----
__global__ void __launch_bounds__(256) k_safm(
        const float* __restrict__ xln, BP mw, BP mb,
        float* __restrict__ s0, float* __restrict__ s1,
        float* __restrict__ s2, float* __restrict__ s3) {
    int b = blockIdx.x;
    if (b < 224) {
        int c = b >> 4;
        int tile = b & 15;
        int y0 = (tile >> 2) * 16, x0 = (tile & 3) * 16;
        __shared__ float sT[18 * 18];
        const float* sc = xln + (size_t)c * L4;
        for (int idx = threadIdx.x; idx < 324; idx += 256) {
            int iy = idx / 18, ix = idx - iy * 18;
            int gy = y0 - 1 + iy, gx = x0 - 1 + ix;
            sT[idx] = (gy >= 0 && gy < 64 && gx >= 0 && gx < 64) ? sc[gy * 64 + gx] : 0.f;
        }
        __syncthreads();
        int py = threadIdx.x >> 4, px = threadIdx.x & 15;
        BP wr = mw + c * 9;
        float acc = mb[c];
        #pragma unroll
        for (int ky = 0; ky < 3; ++ky)
            #pragma unroll
            for (int kx = 0; kx < 3; ++kx)
                acc += sT[(py + ky) * 18 + px + kx] * wr[ky * 3 + kx];
        s0[c * L4 + (y0 + py) * 64 + x0 + px] = acc;
    } else {
        int bb = b - 224;
        int i = bb / 14 + 1;
        int c = bb % 14;
        int S = 64 >> i;
        int f = 1 << i;
        __shared__ float sP[34 * 34];
        int W2 = S + 2;
        for (int idx = threadIdx.x; idx < W2 * W2; idx += 256) sP[idx] = 0.f;
        __syncthreads();
        const float* sc = xln + (size_t)(i * 14 + c) * L4;
        for (int cell = threadIdx.x; cell < S * S; cell += 256) {
            int y = cell / S, x = cell - y * S;
            float m = -3.4e38f;
            for (int dy = 0; dy < f; ++dy)
                for (int dx = 0; dx < f; ++dx)
                    m = fmaxf(m, sc[(y * f + dy) * 64 + x * f + dx]);
            sP[(y + 1) * W2 + x + 1] = m;
        }
        __syncthreads();
        BP wr = mw + (i * 14 + c) * 9;
        float bias = mb[i * 14 + c];
        float* dst = (i == 1) ? s1 : (i == 2) ? s2 : s3;
        for (int cell = threadIdx.x; cell < S * S; cell += 256) {
            int y = cell / S, x = cell - y * S;
            float acc = bias;
            #pragma unroll
            for (int ky = 0; ky < 3; ++ky)
                #pragma unroll
                for (int kx = 0; kx < 3; ++kx)
                    acc += sP[(y + ky) * W2 + x + kx] * wr[ky * 3 + kx];
            dst[c * S * S + cell] = acc;
        }
    }
}

// ---- SAFM aggregate 1x1 + gelu gate + residual, writes trunk slice ----
__global__ void k_aggr(const float* __restrict__ s0, const float* __restrict__ s1,
                       const float* __restrict__ s2, const float* __restrict__ s3,
                       const float* __restrict__ xln, const float* __restrict__ x_mid,
                       BP aw, BP ab, float* __restrict__ out) {
    int tid = blockIdx.x * blockDim.x + threadIdx.x;
    if (tid >= CC * L4) return;
    int c = tid >> 12, l = tid & 4095;
    int h = l >> 6, w = l & 63;
    int o1 = (h >> 1) * 32 + (w >> 1);
    int o2 = (h >> 2) * 16 + (w >> 2);
    int o3 = (h >> 3) * 8 + (w >> 3);
    float acc = bf(ab, c);
    BP wr = aw + c * 56;
    for (int cg = 0; cg < 14; ++cg) acc += s0[cg * 4096 + l]  * bf(wr, cg);
    for (int cg = 0; cg < 14; ++cg) acc += s1[cg * 1024 + o1] * bf(wr, 14 + cg);
    for (int cg = 0; cg < 14; ++cg) acc += s2[cg * 256 + o2]  * bf(wr, 28 + cg);
    for (int cg = 0; cg < 14; ++cg) acc += s3[cg * 64 + o3]   * bf(wr, 42 + cg);
    out[tid] = x_mid[tid] + geluf(acc) * xln[tid];
}

// ---- up conv 3x3 (56->27) + pixel shuffle x3, LDS-staged, fp32 output ----
__global__ void __launch_bounds__(256) k_up(
        const float* __restrict__ out_lr, BP uw, BP ub, float* __restrict__ out) {
    __shared__ float sIn[56 * 36];
    __shared__ float sW[27 * 56 * 9];
    int b = blockIdx.x;
    int y0 = (b >> 4) * 4, x0 = (b & 15) * 4;
    for (int idx = threadIdx.x; idx < 56 * 36; idx += 256) {
        int cc = idx / 36; int rem = idx - cc * 36; int iy = rem / 6, ix = rem - iy * 6;
        int gy = y0 - 1 + iy, gx = x0 - 1 + ix;
        sIn[idx] = (gy >= 0 && gy < 64 && gx >= 0 && gx < 64)
                 ? out_lr[(size_t)cc * L4 + gy * 64 + gx] : 0.f;
    }
    for (int idx = threadIdx.x; idx < 27 * 56 * 9; idx += 256) sW[idx] = uw[idx];
    __syncthreads();
    int px = threadIdx.x & 15;
    int og = threadIdx.x >> 4;
    int dy = px >> 2, dx = px & 3;
    for (int oo = 0; oo < 2; ++oo) {
        int o = og * 2 + oo;
        if (o >= 27) break;
        float acc = ub[o];
        const float* wb = &sW[o * 504];
        for (int cc = 0; cc < 56; ++cc) {
            const float* ib = &sIn[cc * 36 + dy * 6 + dx];
            const float* wc = wb + cc * 9;
            acc += ib[0] * wc[0] + ib[1] * wc[1] + ib[2] * wc[2]
                 + ib[6] * wc[3] + ib[7] * wc[4] + ib[8] * wc[5]
                 + ib[12] * wc[6] + ib[13] * wc[7] + ib[14] * wc[8];
        }
        int h = y0 + dy, wv = x0 + dx;
        int ch = o / 9, rr = (o % 9) / 3, ss = o % 3;
        out[ch * 36864 + (h * 3 + rr) * 192 + (wv * 3 + ss)] = acc;
    }
}

extern "C" void kernel_launch(void* const* d_in, const int* in_sizes, int n_in,
                              void* d_out, int out_size, void* d_ws, size_t ws_size,
                              hipStream_t stream) {
    BP in0  = (BP)d_in[0];
    BP in1  = (BP)d_in[1];
    BP in2  = (BP)d_in[2];
    BP in3  = (BP)d_in[3];
    BP in4  = (BP)d_in[4];
    BP in5  = (BP)d_in[5];
    BP in6  = (BP)d_in[6];
    BP in7  = (BP)d_in[7];
    BP in8  = (BP)d_in[8];
    BP in9  = (BP)d_in[9];
    BP in10 = (BP)d_in[10];
    BP in11 = (BP)d_in[11];
    BP in12 = (BP)d_in[12];
    BP in13 = (BP)d_in[13];
    BP in14 = (BP)d_in[14];
    BP in15 = (BP)d_in[15];
    BP in16 = (BP)d_in[16];
    BP in17 = (BP)d_in[17];
    BP in18 = (BP)d_in[18];
    BP in19 = (BP)d_in[19];
    BP in20 = (BP)d_in[20];
    BP in21 = (BP)d_in[21];
    BP in22 = (BP)d_in[22];
    BP in23 = (BP)d_in[23];
    BP in24 = (BP)d_in[24];
    BP in25 = (BP)d_in[25];
    BP in26 = (BP)d_in[26];
    BP in27 = (BP)d_in[27];
    BP in28 = (BP)d_in[28];
    BP in29 = (BP)d_in[29];
    BP in30 = (BP)d_in[30];
    BP in31 = (BP)d_in[31];

    float* ws = (float*)d_ws;
    float* trunk   = ws; ws += 560 * L4;
    float* out_fea = ws; ws += CC * L4;
    float* t0      = ws; ws += CC * L4;
    float* xz      = ws; ws += 224 * L4;
    float* xc      = ws; ws += DI * L4;
    float* pk      = ws; ws += 4 * 36 * L4;
    float* ybuf    = ws; ws += 4 * DI * L4;
    float* x_mid   = ws; ws += CC * L4;
    float* xln     = ws; ws += CC * L4;
    float* s0      = ws; ws += 14 * 4096;
    float* s1      = ws; ws += 14 * 1024;
    float* s2      = ws; ws += 14 * 256;
    float* s3      = ws; ws += 14 * 64;
    float* bufB    = ws; ws += CC * L4;
    float* gB      = ws; ws += CC * L4;
    float* tbuf    = ws; ws += CC * L4;
    float* out_lr  = ws; ws += CC * L4;

    auto nb256 = [](int n) { return dim3((n + 255) / 256); };
    auto gemm_grid = [](int nout) { return dim3(64, (nout + 15) / 16); };

    // stem
    k_fea_pw<<<nb256(CC * L4), 256, 0, stream>>>(in0, in1, t0);
    k_dw3x3t<<<dim3(CC * 16), 256, 0, stream>>>(t0, in2, in3, out_fea, 0, nullptr);

    for (int nb = 0; nb < NBLK; ++nb) {
        const float* xin = (nb == 0) ? out_fea : trunk + (size_t)(nb - 1) * CC * L4;
        float* xout = trunk + (size_t)nb * CC * L4;
        BP ln1w = in4 + nb * 56,        ln1b = in5 + nb * 56;
        BP ipw  = in6 + nb * 224 * 56;
        BP cw   = in7 + nb * 112 * 9,   cb   = in8 + nb * 112;
        BP xpw  = in9 + nb * 4 * 36 * 112;
        BP dtw  = in10 + nb * 4 * 112 * 4, dtb = in11 + nb * 448;
        BP alog = in12 + nb * 448 * 16, Dp   = in13 + nb * 448;
        BP onw  = in14 + nb * 112,      onb  = in15 + nb * 112;
        BP opw  = in16 + nb * 56 * 112;
        BP nw   = in17 + nb * 56,       nbv  = in18 + nb * 56;
        BP mw   = in19 + nb * 4 * 14 * 9, mb = in20 + nb * 56;
        BP aw   = in21 + nb * 56 * 56,  ab   = in22 + nb * 56;

        k_gemm_ln<<<gemm_grid(224), 256, 0, stream>>>(xin, ln1w, ln1b, ipw, xz, 224);
        k_dw3x3t<<<dim3(DI * 16), 256, 0, stream>>>(xz, cw, cb, xc, 1, nullptr);
        k_xproj<<<dim3(128, 9), 256, 0, stream>>>(xc, xpw, pk);
        k_scan<<<dim3(4 * DI), 1024, 0, stream>>>(xc, pk, alog, dtw, dtb, ybuf);
        k_comb_proj<<<dim3(64), 256, 0, stream>>>(ybuf, xc, xz + 112 * L4, Dp, onw, onb, opw,
                                                  xin, nw, nbv, x_mid, xln);
        k_safm<<<dim3(266), 256, 0, stream>>>(xln, mw, mb, s0, s1, s2, s3);
        k_aggr<<<nb256(CC * L4), 256, 0, stream>>>(s0, s1, s2, s3, xln, x_mid, aw, ab, xout);
    }

    // tail
    k_gemm<<<gemm_grid(56), 256, 0, stream>>>(trunk, in23, in24, nullptr, bufB, 560, 56);
    k_ln56<<<dim3(64), 256, 0, stream>>>(bufB, in25, in26, gB, 1e-6f, 1);
    k_gemm<<<gemm_grid(56), 256, 0, stream>>>(gB, in27, nullptr, nullptr, tbuf, 56, 56);
    k_dw3x3t<<<dim3(CC * 16), 256, 0, stream>>>(tbuf, in28, in29, out_lr, 0, out_fea);
    k_up<<<dim3(256), 256, 0, stream>>>(out_lr, in30, in31, (float*)d_out);
}

// Round 12
// 1299.534 us; speedup vs baseline: 3.0525x; 1.0830x over previous
//
#include <hip/hip_runtime.h>
#include <hip/hip_bf16.h>

#define HW 64
#define L4 4096
#define CC 56
#define DI 112
#define DSN 16
#define NBLK 10

typedef const float* BP;

__device__ __forceinline__ float bf(BP p, int i) { return p[i]; }
__device__ __forceinline__ float siluf(float x) { return x / (1.f + __expf(-x)); }
__device__ __forceinline__ float geluf(float x) { return 0.5f * x * (1.f + erff(x * 0.70710678f)); }

// ---- stem: pointwise 3->56 ----
__global__ void k_fea_pw(BP x, BP w, float* __restrict__ t0) {
    int tid = blockIdx.x * blockDim.x + threadIdx.x;
    if (tid >= CC * L4) return;
    int c = tid >> 12, l = tid & 4095;
    float acc = 0.f;
    for (int i = 0; i < 3; ++i) acc += bf(x, i * L4 + l) * bf(w, c * 3 + i);
    t0[tid] = acc;
}

// ---- tiled depthwise 3x3 for 64x64 maps: grid = nch*16, block 256 (16x16 px) ----
__global__ void __launch_bounds__(256) k_dw3x3t(
        const float* __restrict__ src, BP w, BP bvec, float* __restrict__ dst,
        int act, const float* __restrict__ addsrc) {
    int c = blockIdx.x >> 4;
    int tile = blockIdx.x & 15;
    int y0 = (tile >> 2) * 16, x0 = (tile & 3) * 16;
    __shared__ float sT[18 * 18];
    const float* sc = src + (size_t)c * L4;
    for (int idx = threadIdx.x; idx < 324; idx += 256) {
        int iy = idx / 18, ix = idx - iy * 18;
        int gy = y0 - 1 + iy, gx = x0 - 1 + ix;
        sT[idx] = (gy >= 0 && gy < 64 && gx >= 0 && gx < 64) ? sc[gy * 64 + gx] : 0.f;
    }
    __syncthreads();
    int py = threadIdx.x >> 4, px = threadIdx.x & 15;
    BP wr = w + c * 9;
    float acc = bvec ? bvec[c] : 0.f;
    #pragma unroll
    for (int ky = 0; ky < 3; ++ky)
        #pragma unroll
        for (int kx = 0; kx < 3; ++kx)
            acc += sT[(py + ky) * 18 + px + kx] * wr[ky * 3 + kx];
    if (act) acc = siluf(acc);
    int l = (y0 + py) * 64 + x0 + px;
    if (addsrc) acc += addsrc[(size_t)c * L4 + l];
    dst[(size_t)c * L4 + l] = acc;
}

// ---- tail LN56 over sum of 5 split-K partials + bias, then gelu ----
__global__ void __launch_bounds__(256) k_ln56g(
        const float* __restrict__ part, BP bias, BP w, BP b, float* __restrict__ dst) {
    int lane = threadIdx.x & 63;
    int cg = threadIdx.x >> 6;
    int l0 = blockIdx.x * 64;
    __shared__ float sS[56 * 64];
    __shared__ float sPa[4][64], sPb[4][64];
    __shared__ float sMu[64], sRs[64];
    float ps = 0.f, ps2 = 0.f;
    for (int c = cg * 14; c < cg * 14 + 14; ++c) {
        float v = bias[c];
        #pragma unroll
        for (int z = 0; z < 5; ++z)
            v += part[(size_t)(z * 56 + c) * L4 + l0 + lane];
        sS[c * 64 + lane] = v; ps += v; ps2 += v * v;
    }
    sPa[cg][lane] = ps; sPb[cg][lane] = ps2;
    __syncthreads();
    if (threadIdx.x < 64) {
        float s = sPa[0][lane] + sPa[1][lane] + sPa[2][lane] + sPa[3][lane];
        float s2 = sPb[0][lane] + sPb[1][lane] + sPb[2][lane] + sPb[3][lane];
        float mu = s / 56.f;
        float var = fmaxf(s2 / 56.f - mu * mu, 0.f);
        sMu[lane] = mu; sRs[lane] = rsqrtf(var + 1e-6f);
    }
    __syncthreads();
    float mu = sMu[lane], rs = sRs[lane];
    for (int c = cg * 14; c < cg * 14 + 14; ++c) {
        float v = (sS[c * 64 + lane] - mu) * rs * w[c] + b[c];
        dst[(size_t)c * L4 + l0 + lane] = geluf(v);
    }
}

// ---- LDS-staged channel GEMM (tail c2; nin % 56 == 0) ----
__global__ void __launch_bounds__(256) k_gemm(
        const float* __restrict__ src, BP w, BP bvec, const float* __restrict__ addsrc,
        float* __restrict__ dst, int nin, int nout) {
    int lane = threadIdx.x & 63;
    int jg = threadIdx.x >> 6;
    int l0 = blockIdx.x * 64;
    int j0 = blockIdx.y * 16;
    __shared__ __align__(16) float sS[56 * 64];
    __shared__ __align__(16) float sw[16 * 56];
    float acc[4] = {0.f, 0.f, 0.f, 0.f};

    for (int i0 = 0; i0 < nin; i0 += 56) {
        __syncthreads();
        for (int idx = threadIdx.x; idx < 56 * 64; idx += 256) {
            int ii = idx >> 6, px = idx & 63;
            sS[idx] = src[(size_t)(i0 + ii) * L4 + l0 + px];
        }
        for (int idx = threadIdx.x; idx < 16 * 56; idx += 256) {
            int jj = idx / 56, ii = idx - jj * 56;
            int j = j0 + jj;
            sw[idx] = (j < nout) ? w[(size_t)j * nin + i0 + ii] : 0.f;
        }
        __syncthreads();
        #pragma unroll
        for (int ii = 0; ii < 56; ii += 4) {
            float s0 = sS[(ii + 0) * 64 + lane];
            float s1 = sS[(ii + 1) * 64 + lane];
            float s2 = sS[(ii + 2) * 64 + lane];
            float s3 = sS[(ii + 3) * 64 + lane];
            #pragma unroll
            for (int jj = 0; jj < 4; ++jj) {
                const float4 wv = *(const float4*)&sw[(jg * 4 + jj) * 56 + ii];
                acc[jj] += s0 * wv.x + s1 * wv.y + s2 * wv.z + s3 * wv.w;
            }
        }
    }
    int l = l0 + lane;
    #pragma unroll
    for (int jj = 0; jj < 4; ++jj) {
        int j = j0 + jg * 4 + jj;
        if (j >= nout) continue;
        float v = acc[jj];
        if (bvec) v += bf(bvec, j);
        size_t idx = (size_t)j * L4 + l;
        if (addsrc) v += addsrc[idx];
        dst[idx] = v;
    }
}

// ---- tail c1 560->56 split-K: grid (64, 4, 5); z does K in [z*112, z*112+112) ----
__global__ void __launch_bounds__(256) k_c1(
        const float* __restrict__ src, BP w, float* __restrict__ part) {
    int lane = threadIdx.x & 63;
    int jg = threadIdx.x >> 6;
    int l0 = blockIdx.x * 64;
    int j0 = blockIdx.y * 16;
    int z = blockIdx.z;
    __shared__ __align__(16) float sS[56 * 64];
    __shared__ __align__(16) float sw[16 * 56];
    float acc[4] = {0.f, 0.f, 0.f, 0.f};

    for (int i0 = z * 112; i0 < z * 112 + 112; i0 += 56) {
        __syncthreads();
        for (int idx = threadIdx.x; idx < 56 * 64; idx += 256) {
            int ii = idx >> 6, px = idx & 63;
            sS[idx] = src[(size_t)(i0 + ii) * L4 + l0 + px];
        }
        for (int idx = threadIdx.x; idx < 16 * 56; idx += 256) {
            int jj = idx / 56, ii = idx - jj * 56;
            int j = j0 + jj;
            sw[idx] = (j < 56) ? w[(size_t)j * 560 + i0 + ii] : 0.f;
        }
        __syncthreads();
        #pragma unroll
        for (int ii = 0; ii < 56; ii += 4) {
            float s0 = sS[(ii + 0) * 64 + lane];
            float s1 = sS[(ii + 1) * 64 + lane];
            float s2 = sS[(ii + 2) * 64 + lane];
            float s3 = sS[(ii + 3) * 64 + lane];
            #pragma unroll
            for (int jj = 0; jj < 4; ++jj) {
                const float4 wv = *(const float4*)&sw[(jg * 4 + jj) * 56 + ii];
                acc[jj] += s0 * wv.x + s1 * wv.y + s2 * wv.z + s3 * wv.w;
            }
        }
    }
    int l = l0 + lane;
    #pragma unroll
    for (int jj = 0; jj < 4; ++jj) {
        int j = j0 + jg * 4 + jj;
        if (j < 56) part[(size_t)(z * 56 + j) * L4 + l] = acc[jj];
    }
}

// ---- x-projection 112->144, 32-px tiles, single K-chunk ----
__global__ void __launch_bounds__(256) k_xproj(
        const float* __restrict__ src, BP w, float* __restrict__ dst) {
    int lane = threadIdx.x & 31;
    int jg = threadIdx.x >> 5;
    int l0 = blockIdx.x * 32;
    int j0 = blockIdx.y * 16;
    __shared__ __align__(16) float sS[112 * 32];
    __shared__ __align__(16) float sw[16 * 112];
    float acc[2] = {0.f, 0.f};

    for (int idx = threadIdx.x; idx < 112 * 32; idx += 256) {
        int ii = idx >> 5, px = idx & 31;
        sS[idx] = src[(size_t)ii * L4 + l0 + px];
    }
    for (int idx = threadIdx.x; idx < 16 * 112; idx += 256) {
        int jj = idx / 112, ii = idx - jj * 112;
        sw[idx] = w[(size_t)(j0 + jj) * 112 + ii];
    }
    __syncthreads();
    #pragma unroll
    for (int ii = 0; ii < 112; ii += 4) {
        float s0 = sS[(ii + 0) * 32 + lane];
        float s1 = sS[(ii + 1) * 32 + lane];
        float s2 = sS[(ii + 2) * 32 + lane];
        float s3 = sS[(ii + 3) * 32 + lane];
        #pragma unroll
        for (int jj = 0; jj < 2; ++jj) {
            const float4 wv = *(const float4*)&sw[(jg * 2 + jj) * 112 + ii];
            acc[jj] += s0 * wv.x + s1 * wv.y + s2 * wv.z + s3 * wv.w;
        }
    }
    __syncthreads();
    #pragma unroll
    for (int jj = 0; jj < 2; ++jj)
        sS[(jg * 2 + jj) * 32 + lane] = acc[jj];
    __syncthreads();
    for (int idx = threadIdx.x; idx < 16 * 32; idx += 256) {
        int cidx = idx & 15, l2 = idx >> 4;
        int j = j0 + cidx;
        int k = j / 36, c = j - k * 36;
        dst[((size_t)k * L4 + l0 + l2) * 36 + c] = sS[cidx * 32 + l2];
    }
}

// ---- in-proj GEMM with fused LN (nin = 56, single K chunk) ----
__global__ void __launch_bounds__(256) k_gemm_ln(
        const float* __restrict__ src, BP lnw, BP lnb, BP w,
        float* __restrict__ dst, int nout) {
    int lane = threadIdx.x & 63;
    int jg = threadIdx.x >> 6;
    int l0 = blockIdx.x * 64;
    int j0 = blockIdx.y * 16;
    __shared__ __align__(16) float sS[56 * 64];
    __shared__ __align__(16) float sw[16 * 56];
    __shared__ float sLw[56], sLb[56];
    float acc[4] = {0.f, 0.f, 0.f, 0.f};

    for (int idx = threadIdx.x; idx < 56 * 64; idx += 256) {
        int ii = idx >> 6, px = idx & 63;
        sS[idx] = src[(size_t)ii * L4 + l0 + px];
    }
    for (int idx = threadIdx.x; idx < 16 * 56; idx += 256) {
        int jj = idx / 56, ii = idx - jj * 56;
        int j = j0 + jj;
        sw[idx] = (j < nout) ? w[(size_t)j * 56 + ii] : 0.f;
    }
    if (threadIdx.x < 56) { sLw[threadIdx.x] = lnw[threadIdx.x]; sLb[threadIdx.x] = lnb[threadIdx.x]; }
    __syncthreads();
    if (threadIdx.x < 64) {
        int px = threadIdx.x;
        float s = 0.f, s2 = 0.f;
        for (int ii = 0; ii < 56; ++ii) { float v = sS[ii * 64 + px]; s += v; s2 += v * v; }
        float mu = s / 56.f;
        float var = fmaxf(s2 / 56.f - mu * mu, 0.f);
        float rstd = rsqrtf(var + 1e-5f);
        for (int ii = 0; ii < 56; ++ii)
            sS[ii * 64 + px] = (sS[ii * 64 + px] - mu) * rstd * sLw[ii] + sLb[ii];
    }
    __syncthreads();
    #pragma unroll
    for (int ii = 0; ii < 56; ii += 4) {
        float s0 = sS[(ii + 0) * 64 + lane];
        float s1 = sS[(ii + 1) * 64 + lane];
        float s2 = sS[(ii + 2) * 64 + lane];
        float s3 = sS[(ii + 3) * 64 + lane];
        #pragma unroll
        for (int jj = 0; jj < 4; ++jj) {
            const float4 wv = *(const float4*)&sw[(jg * 4 + jj) * 56 + ii];
            acc[jj] += s0 * wv.x + s1 * wv.y + s2 * wv.z + s3 * wv.w;
        }
    }
    int l = l0 + lane;
    #pragma unroll
    for (int jj = 0; jj < 4; ++jj) {
        int j = j0 + jg * 4 + jj;
        if (j < nout) dst[(size_t)j * L4 + l] = acc[jj];
    }
}

// ---- chunked selective scan; affine pixel walk; Kogge-Stone carry compose ----
#define SPAD(p) ((p) + ((p) >> 5))
__global__ void __launch_bounds__(1024) k_scan(
        const float* __restrict__ xc, const float* __restrict__ pk,
        BP Alog, BP dtw, BP dtb, float* __restrict__ ybuf) {
    int pair = blockIdx.x;           // k*112+d
    int n = threadIdx.x & 15;        // state index
    int c = threadIdx.x >> 4;        // chunk index, 0..63
    int k = pair / DI, d = pair - k * DI;
    float a = -__expf(Alog[pair * DSN + n]);
    float w0 = dtw[pair * 4 + 0], w1 = dtw[pair * 4 + 1];
    float w2 = dtw[pair * 4 + 2], w3 = dtw[pair * 4 + 3];
    float db = dtb[pair];
    const float* xptr = xc + (size_t)d * L4;
    const float* pkk = pk + (size_t)k * L4 * 36;
    float* yptr = ybuf + (size_t)pair * L4;

    __shared__ float sDl[4224];
    __shared__ float sDlx[4224];
    __shared__ float sP[64 * 16];
    __shared__ float sHe[64 * 16];

    // phase 0: cooperative delta precompute
    for (int p = threadIdx.x; p < L4; p += 1024) {
        const float* row = pkk + (size_t)p * 36;
        float v = db + row[0] * w0 + row[1] * w1 + row[2] * w2 + row[3] * w3;
        float dl = fmaxf(v, 0.f) + __logf(1.f + __expf(-fabsf(v)));
        sDl[SPAD(p)] = dl;
        sDlx[SPAD(p)] = dl * xptr[p];
    }
    __syncthreads();

    int p0, dp;
    if (k == 0)      { p0 = c * 64;        dp = 1;   }
    else if (k == 1) { p0 = c;             dp = 64;  }
    else if (k == 2) { p0 = 4095 - c * 64; dp = -1;  }
    else             { p0 = 4095 - c;      dp = -64; }
    long rstep = (long)dp * 36;

    // phase 1: local chunk scan from 0
    float h = 0.f, P = 1.f;
    {
        int p = p0;
        const float* rB = pkk + (size_t)p0 * 36 + 4 + n;
        #pragma unroll 4
        for (int j = 0; j < 64; ++j) {
            int q = SPAD(p);
            float e = __expf(sDl[q] * a);
            h = e * h + sDlx[q] * (*rB);
            P *= e;
            p += dp; rB += rstep;
        }
    }
    int idx = c * 16 + n;
    sP[idx] = P;
    sHe[idx] = h;
    __syncthreads();

    // phase 2: Kogge-Stone inclusive scan over chunks
    for (int off = 1; off < 64; off <<= 1) {
        float pC = sP[idx], hC = sHe[idx];
        float pL = 0.f, hL = 0.f;
        if (c >= off) { pL = sP[idx - off * 16]; hL = sHe[idx - off * 16]; }
        __syncthreads();
        if (c >= off) { sP[idx] = pC * pL; sHe[idx] = pC * hL + hC; }
        __syncthreads();
    }

    // phase 3: re-scan with carry = prefix up to chunk c-1
    h = (c > 0) ? sHe[idx - 16] : 0.f;
    {
        int p = p0;
        const float* rB = pkk + (size_t)p0 * 36 + 4 + n;
        const float* rC = pkk + (size_t)p0 * 36 + 20 + n;
        #pragma unroll 4
        for (int j = 0; j < 64; ++j) {
            int q = SPAD(p);
            float e = __expf(sDl[q] * a);
            h = e * h + sDlx[q] * (*rB);
            float y = h * (*rC);
            y += __shfl_xor(y, 1, 16);
            y += __shfl_xor(y, 2, 16);
            y += __shfl_xor(y, 4, 16);
            y += __shfl_xor(y, 8, 16);
            if (n == 0) yptr[p] = y;
            p += dp; rB += rstep; rC += rstep;
        }
    }
}

// ---- fused: combine + LN112 + gate + out-proj + residual + LN56; 16-px tiles, grid 256 ----
__global__ void __launch_bounds__(256) k_comb_proj(
        const float* __restrict__ ybuf, const float* __restrict__ xc,
        const float* __restrict__ zbuf, BP Dp, BP ow, BP ob, BP opw,
        const float* __restrict__ xin, BP nw, BP nbv,
        float* __restrict__ x_mid, float* __restrict__ xln) {
    int lane = threadIdx.x & 15;     // pixel
    int grp = threadIdx.x >> 4;      // 0..15
    int l0 = blockIdx.x * 16;
    __shared__ __align__(16) float sY[112 * 16];   // 7 KB
    __shared__ __align__(16) float sW[56 * 112];   // 25 KB
    __shared__ float sPa[16][16], sPb[16][16];
    __shared__ float sMu[16], sRs[16];

    float ps = 0.f, ps2 = 0.f;
    for (int d = grp * 7; d < grp * 7 + 7; ++d) {
        float Ds = Dp[d] + Dp[DI + d] + Dp[2 * DI + d] + Dp[3 * DI + d];
        float v = ybuf[(size_t)d * L4 + l0 + lane]
                + ybuf[(size_t)(DI + d) * L4 + l0 + lane]
                + ybuf[(size_t)(2 * DI + d) * L4 + l0 + lane]
                + ybuf[(size_t)(3 * DI + d) * L4 + l0 + lane]
                + Ds * xc[(size_t)d * L4 + l0 + lane];
        sY[d * 16 + lane] = v; ps += v; ps2 += v * v;
    }
    sPa[grp][lane] = ps; sPb[grp][lane] = ps2;
    for (int idx = threadIdx.x; idx < 56 * 112; idx += 256) sW[idx] = opw[idx];
    __syncthreads();
    if (threadIdx.x < 16) {
        float s = 0.f, s2 = 0.f;
        for (int g = 0; g < 16; ++g) { s += sPa[g][lane]; s2 += sPb[g][lane]; }
        float mu = s / 112.f;
        float var = fmaxf(s2 / 112.f - mu * mu, 0.f);
        sMu[lane] = mu; sRs[lane] = rsqrtf(var + 1e-5f);
    }
    __syncthreads();
    {
        float mu = sMu[lane], rs = sRs[lane];
        for (int d = grp * 7; d < grp * 7 + 7; ++d) {
            float v = (sY[d * 16 + lane] - mu) * rs * ow[d] + ob[d];
            float z = zbuf[(size_t)d * L4 + l0 + lane];
            sY[d * 16 + lane] = v * siluf(z);
        }
    }
    __syncthreads();

    // out-proj: grp handles outputs j = grp*4 .. grp*4+3 (mask j < 56)
    float acc[4] = {0.f, 0.f, 0.f, 0.f};
    #pragma unroll 2
    for (int ii = 0; ii < 112; ii += 4) {
        float s0 = sY[(ii + 0) * 16 + lane];
        float s1 = sY[(ii + 1) * 16 + lane];
        float s2 = sY[(ii + 2) * 16 + lane];
        float s3 = sY[(ii + 3) * 16 + lane];
        #pragma unroll
        for (int jj = 0; jj < 4; ++jj) {
            int j = grp * 4 + jj;
            if (j < 56) {
                const float4 wv = *(const float4*)&sW[j * 112 + ii];
                acc[jj] += s0 * wv.x + s1 * wv.y + s2 * wv.z + s3 * wv.w;
            }
        }
    }
    int l = l0 + lane;
    float vout[4];
    float ps3 = 0.f, ps4 = 0.f;
    #pragma unroll
    for (int jj = 0; jj < 4; ++jj) {
        int j = grp * 4 + jj;
        vout[jj] = 0.f;
        if (j < 56) {
            float v = acc[jj] + xin[(size_t)j * L4 + l];
            vout[jj] = v;
            x_mid[(size_t)j * L4 + l] = v;
            ps3 += v; ps4 += v * v;
        }
    }
    __syncthreads();
    sPa[grp][lane] = ps3; sPb[grp][lane] = ps4;
    __syncthreads();
    if (threadIdx.x < 16) {
        float s = 0.f, s2 = 0.f;
        for (int g = 0; g < 16; ++g) { s += sPa[g][lane]; s2 += sPb[g][lane]; }
        float mu = s / 56.f;
        float var = fmaxf(s2 / 56.f - mu * mu, 0.f);
        sMu[lane] = mu; sRs[lane] = rsqrtf(var + 1e-6f);
    }
    __syncthreads();
    {
        float mu = sMu[lane], rs = sRs[lane];
        #pragma unroll
        for (int jj = 0; jj < 4; ++jj) {
            int j = grp * 4 + jj;
            if (j < 56) xln[(size_t)j * L4 + l] = (vout[jj] - mu) * rs * nw[j] + nbv[j];
        }
    }
}

// ---- fused SAFM pools+depthwise: grid 224 (i=0 tiles) + 42 (i>=1 channels) ----
__global__ void __launch_bounds__(256) k_safm(
        const float* __restrict__ xln, BP mw, BP mb,
        float* __restrict__ s0, float* __restrict__ s1,
        float* __restrict__ s2, float* __restrict__ s3) {
    int b = blockIdx.x;
    if (b < 224) {
        int c = b >> 4;
        int tile = b & 15;
        int y0 = (tile >> 2) * 16, x0 = (tile & 3) * 16;
        __shared__ float sT[18 * 18];
        const float* sc = xln + (size_t)c * L4;
        for (int idx = threadIdx.x; idx < 324; idx += 256) {
            int iy = idx / 18, ix = idx - iy * 18;
            int gy = y0 - 1 + iy, gx = x0 - 1 + ix;
            sT[idx] = (gy >= 0 && gy < 64 && gx >= 0 && gx < 64) ? sc[gy * 64 + gx] : 0.f;
        }
        __syncthreads();
        int py = threadIdx.x >> 4, px = threadIdx.x & 15;
        BP wr = mw + c * 9;
        float acc = mb[c];
        #pragma unroll
        for (int ky = 0; ky < 3; ++ky)
            #pragma unroll
            for (int kx = 0; kx < 3; ++kx)
                acc += sT[(py + ky) * 18 + px + kx] * wr[ky * 3 + kx];
        s0[c * L4 + (y0 + py) * 64 + x0 + px] = acc;
    } else {
        int bb = b - 224;
        int i = bb / 14 + 1;
        int c = bb % 14;
        int S = 64 >> i;
        int f = 1 << i;
        __shared__ float sP[34 * 34];
        int W2 = S + 2;
        for (int idx = threadIdx.x; idx < W2 * W2; idx += 256) sP[idx] = 0.f;
        __syncthreads();
        const float* sc = xln + (size_t)(i * 14 + c) * L4;
        for (int cell = threadIdx.x; cell < S * S; cell += 256) {
            int y = cell / S, x = cell - y * S;
            float m = -3.4e38f;
            for (int dy = 0; dy < f; ++dy)
                for (int dx = 0; dx < f; ++dx)
                    m = fmaxf(m, sc[(y * f + dy) * 64 + x * f + dx]);
            sP[(y + 1) * W2 + x + 1] = m;
        }
        __syncthreads();
        BP wr = mw + (i * 14 + c) * 9;
        float bias = mb[i * 14 + c];
        float* dst = (i == 1) ? s1 : (i == 2) ? s2 : s3;
        for (int cell = threadIdx.x; cell < S * S; cell += 256) {
            int y = cell / S, x = cell - y * S;
            float acc = bias;
            #pragma unroll
            for (int ky = 0; ky < 3; ++ky)
                #pragma unroll
                for (int kx = 0; kx < 3; ++kx)
                    acc += sP[(y + ky) * W2 + x + kx] * wr[ky * 3 + kx];
            dst[c * S * S + cell] = acc;
        }
    }
}

// ---- SAFM aggregate 1x1 + gelu gate + residual, writes trunk slice ----
__global__ void k_aggr(const float* __restrict__ s0, const float* __restrict__ s1,
                       const float* __restrict__ s2, const float* __restrict__ s3,
                       const float* __restrict__ xln, const float* __restrict__ x_mid,
                       BP aw, BP ab, float* __restrict__ out) {
    int tid = blockIdx.x * blockDim.x + threadIdx.x;
    if (tid >= CC * L4) return;
    int c = tid >> 12, l = tid & 4095;
    int h = l >> 6, w = l & 63;
    int o1 = (h >> 1) * 32 + (w >> 1);
    int o2 = (h >> 2) * 16 + (w >> 2);
    int o3 = (h >> 3) * 8 + (w >> 3);
    float acc = bf(ab, c);
    BP wr = aw + c * 56;
    for (int cg = 0; cg < 14; ++cg) acc += s0[cg * 4096 + l]  * bf(wr, cg);
    for (int cg = 0; cg < 14; ++cg) acc += s1[cg * 1024 + o1] * bf(wr, 14 + cg);
    for (int cg = 0; cg < 14; ++cg) acc += s2[cg * 256 + o2]  * bf(wr, 28 + cg);
    for (int cg = 0; cg < 14; ++cg) acc += s3[cg * 64 + o3]   * bf(wr, 42 + cg);
    out[tid] = x_mid[tid] + geluf(acc) * xln[tid];
}

// ---- up conv 3x3 (56->27) + pixel shuffle x3, LDS-staged, fp32 output ----
__global__ void __launch_bounds__(256) k_up(
        const float* __restrict__ out_lr, BP uw, BP ub, float* __restrict__ out) {
    __shared__ float sIn[56 * 36];
    __shared__ float sW[27 * 56 * 9];
    int b = blockIdx.x;
    int y0 = (b >> 4) * 4, x0 = (b & 15) * 4;
    for (int idx = threadIdx.x; idx < 56 * 36; idx += 256) {
        int cc = idx / 36; int rem = idx - cc * 36; int iy = rem / 6, ix = rem - iy * 6;
        int gy = y0 - 1 + iy, gx = x0 - 1 + ix;
        sIn[idx] = (gy >= 0 && gy < 64 && gx >= 0 && gx < 64)
                 ? out_lr[(size_t)cc * L4 + gy * 64 + gx] : 0.f;
    }
    for (int idx = threadIdx.x; idx < 27 * 56 * 9; idx += 256) sW[idx] = uw[idx];
    __syncthreads();
    int px = threadIdx.x & 15;
    int og = threadIdx.x >> 4;
    int dy = px >> 2, dx = px & 3;
    for (int oo = 0; oo < 2; ++oo) {
        int o = og * 2 + oo;
        if (o >= 27) break;
        float acc = ub[o];
        const float* wb = &sW[o * 504];
        for (int cc = 0; cc < 56; ++cc) {
            const float* ib = &sIn[cc * 36 + dy * 6 + dx];
            const float* wc = wb + cc * 9;
            acc += ib[0] * wc[0] + ib[1] * wc[1] + ib[2] * wc[2]
                 + ib[6] * wc[3] + ib[7] * wc[4] + ib[8] * wc[5]
                 + ib[12] * wc[6] + ib[13] * wc[7] + ib[14] * wc[8];
        }
        int h = y0 + dy, wv = x0 + dx;
        int ch = o / 9, rr = (o % 9) / 3, ss = o % 3;
        out[ch * 36864 + (h * 3 + rr) * 192 + (wv * 3 + ss)] = acc;
    }
}

extern "C" void kernel_launch(void* const* d_in, const int* in_sizes, int n_in,
                              void* d_out, int out_size, void* d_ws, size_t ws_size,
                              hipStream_t stream) {
    BP in0  = (BP)d_in[0];
    BP in1  = (BP)d_in[1];
    BP in2  = (BP)d_in[2];
    BP in3  = (BP)d_in[3];
    BP in4  = (BP)d_in[4];
    BP in5  = (BP)d_in[5];
    BP in6  = (BP)d_in[6];
    BP in7  = (BP)d_in[7];
    BP in8  = (BP)d_in[8];
    BP in9  = (BP)d_in[9];
    BP in10 = (BP)d_in[10];
    BP in11 = (BP)d_in[11];
    BP in12 = (BP)d_in[12];
    BP in13 = (BP)d_in[13];
    BP in14 = (BP)d_in[14];
    BP in15 = (BP)d_in[15];
    BP in16 = (BP)d_in[16];
    BP in17 = (BP)d_in[17];
    BP in18 = (BP)d_in[18];
    BP in19 = (BP)d_in[19];
    BP in20 = (BP)d_in[20];
    BP in21 = (BP)d_in[21];
    BP in22 = (BP)d_in[22];
    BP in23 = (BP)d_in[23];
    BP in24 = (BP)d_in[24];
    BP in25 = (BP)d_in[25];
    BP in26 = (BP)d_in[26];
    BP in27 = (BP)d_in[27];
    BP in28 = (BP)d_in[28];
    BP in29 = (BP)d_in[29];
    BP in30 = (BP)d_in[30];
    BP in31 = (BP)d_in[31];

    float* ws = (float*)d_ws;
    float* trunk   = ws; ws += 560 * L4;
    float* out_fea = ws; ws += CC * L4;
    float* t0      = ws; ws += CC * L4;
    float* xz      = ws; ws += 224 * L4;
    float* xc      = ws; ws += DI * L4;
    float* pk      = ws; ws += 4 * 36 * L4;
    float* ybuf    = ws; ws += 4 * DI * L4;
    float* x_mid   = ws; ws += CC * L4;
    float* xln     = ws; ws += CC * L4;
    float* s0      = ws; ws += 14 * 4096;
    float* s1      = ws; ws += 14 * 1024;
    float* s2      = ws; ws += 14 * 256;
    float* s3      = ws; ws += 14 * 64;
    float* part    = ws; ws += 5 * 56 * L4;
    float* gB      = ws; ws += CC * L4;
    float* tbuf    = ws; ws += CC * L4;
    float* out_lr  = ws; ws += CC * L4;

    auto nb256 = [](int n) { return dim3((n + 255) / 256); };
    auto gemm_grid = [](int nout) { return dim3(64, (nout + 15) / 16); };

    // stem
    k_fea_pw<<<nb256(CC * L4), 256, 0, stream>>>(in0, in1, t0);
    k_dw3x3t<<<dim3(CC * 16), 256, 0, stream>>>(t0, in2, in3, out_fea, 0, nullptr);

    for (int nb = 0; nb < NBLK; ++nb) {
        const float* xin = (nb == 0) ? out_fea : trunk + (size_t)(nb - 1) * CC * L4;
        float* xout = trunk + (size_t)nb * CC * L4;
        BP ln1w = in4 + nb * 56,        ln1b = in5 + nb * 56;
        BP ipw  = in6 + nb * 224 * 56;
        BP cw   = in7 + nb * 112 * 9,   cb   = in8 + nb * 112;
        BP xpw  = in9 + nb * 4 * 36 * 112;
        BP dtw  = in10 + nb * 4 * 112 * 4, dtb = in11 + nb * 448;
        BP alog = in12 + nb * 448 * 16, Dp   = in13 + nb * 448;
        BP onw  = in14 + nb * 112,      onb  = in15 + nb * 112;
        BP opw  = in16 + nb * 56 * 112;
        BP nw   = in17 + nb * 56,       nbv  = in18 + nb * 56;
        BP mw   = in19 + nb * 4 * 14 * 9, mb = in20 + nb * 56;
        BP aw   = in21 + nb * 56 * 56,  ab   = in22 + nb * 56;

        k_gemm_ln<<<gemm_grid(224), 256, 0, stream>>>(xin, ln1w, ln1b, ipw, xz, 224);
        k_dw3x3t<<<dim3(DI * 16), 256, 0, stream>>>(xz, cw, cb, xc, 1, nullptr);
        k_xproj<<<dim3(128, 9), 256, 0, stream>>>(xc, xpw, pk);
        k_scan<<<dim3(4 * DI), 1024, 0, stream>>>(xc, pk, alog, dtw, dtb, ybuf);
        k_comb_proj<<<dim3(256), 256, 0, stream>>>(ybuf, xc, xz + 112 * L4, Dp, onw, onb, opw,
                                                   xin, nw, nbv, x_mid, xln);
        k_safm<<<dim3(266), 256, 0, stream>>>(xln, mw, mb, s0, s1, s2, s3);
        k_aggr<<<nb256(CC * L4), 256, 0, stream>>>(s0, s1, s2, s3, xln, x_mid, aw, ab, xout);
    }

    // tail
    k_c1<<<dim3(64, 4, 5), 256, 0, stream>>>(trunk, in23, part);
    k_ln56g<<<dim3(64), 256, 0, stream>>>(part, in24, in25, in26, gB);
    k_gemm<<<gemm_grid(56), 256, 0, stream>>>(gB, in27, nullptr, nullptr, tbuf, 56, 56);
    k_dw3x3t<<<dim3(CC * 16), 256, 0, stream>>>(tbuf, in28, in29, out_lr, 0, out_fea);
    k_up<<<dim3(256), 256, 0, stream>>>(out_lr, in30, in31, (float*)d_out);
}

// Round 13
// 1296.562 us; speedup vs baseline: 3.0595x; 1.0023x over previous
//
#include <hip/hip_runtime.h>
#include <hip/hip_bf16.h>

#define HW 64
#define L4 4096
#define CC 56
#define DI 112
#define DSN 16
#define NBLK 10

typedef const float* BP;

__device__ __forceinline__ float bf(BP p, int i) { return p[i]; }
__device__ __forceinline__ float siluf(float x) { return x / (1.f + __expf(-x)); }
__device__ __forceinline__ float geluf(float x) { return 0.5f * x * (1.f + erff(x * 0.70710678f)); }

// ---- stem: pointwise 3->56 ----
__global__ void k_fea_pw(BP x, BP w, float* __restrict__ t0) {
    int tid = blockIdx.x * blockDim.x + threadIdx.x;
    if (tid >= CC * L4) return;
    int c = tid >> 12, l = tid & 4095;
    float acc = 0.f;
    for (int i = 0; i < 3; ++i) acc += bf(x, i * L4 + l) * bf(w, c * 3 + i);
    t0[tid] = acc;
}

// ---- tiled depthwise 3x3 for 64x64 maps: grid = nch*16, block 256 (16x16 px) ----
__global__ void __launch_bounds__(256) k_dw3x3t(
        const float* __restrict__ src, BP w, BP bvec, float* __restrict__ dst,
        int act, const float* __restrict__ addsrc) {
    int c = blockIdx.x >> 4;
    int tile = blockIdx.x & 15;
    int y0 = (tile >> 2) * 16, x0 = (tile & 3) * 16;
    __shared__ float sT[18 * 18];
    const float* sc = src + (size_t)c * L4;
    for (int idx = threadIdx.x; idx < 324; idx += 256) {
        int iy = idx / 18, ix = idx - iy * 18;
        int gy = y0 - 1 + iy, gx = x0 - 1 + ix;
        sT[idx] = (gy >= 0 && gy < 64 && gx >= 0 && gx < 64) ? sc[gy * 64 + gx] : 0.f;
    }
    __syncthreads();
    int py = threadIdx.x >> 4, px = threadIdx.x & 15;
    BP wr = w + c * 9;
    float acc = bvec ? bvec[c] : 0.f;
    #pragma unroll
    for (int ky = 0; ky < 3; ++ky)
        #pragma unroll
        for (int kx = 0; kx < 3; ++kx)
            acc += sT[(py + ky) * 18 + px + kx] * wr[ky * 3 + kx];
    if (act) acc = siluf(acc);
    int l = (y0 + py) * 64 + x0 + px;
    if (addsrc) acc += addsrc[(size_t)c * L4 + l];
    dst[(size_t)c * L4 + l] = acc;
}

// ---- tail LN56 over sum of 5 split-K partials + bias, then gelu ----
__global__ void __launch_bounds__(256) k_ln56g(
        const float* __restrict__ part, BP bias, BP w, BP b, float* __restrict__ dst) {
    int lane = threadIdx.x & 63;
    int cg = threadIdx.x >> 6;
    int l0 = blockIdx.x * 64;
    __shared__ float sS[56 * 64];
    __shared__ float sPa[4][64], sPb[4][64];
    __shared__ float sMu[64], sRs[64];
    float ps = 0.f, ps2 = 0.f;
    for (int c = cg * 14; c < cg * 14 + 14; ++c) {
        float v = bias[c];
        #pragma unroll
        for (int z = 0; z < 5; ++z)
            v += part[(size_t)(z * 56 + c) * L4 + l0 + lane];
        sS[c * 64 + lane] = v; ps += v; ps2 += v * v;
    }
    sPa[cg][lane] = ps; sPb[cg][lane] = ps2;
    __syncthreads();
    if (threadIdx.x < 64) {
        float s = sPa[0][lane] + sPa[1][lane] + sPa[2][lane] + sPa[3][lane];
        float s2 = sPb[0][lane] + sPb[1][lane] + sPb[2][lane] + sPb[3][lane];
        float mu = s / 56.f;
        float var = fmaxf(s2 / 56.f - mu * mu, 0.f);
        sMu[lane] = mu; sRs[lane] = rsqrtf(var + 1e-6f);
    }
    __syncthreads();
    float mu = sMu[lane], rs = sRs[lane];
    for (int c = cg * 14; c < cg * 14 + 14; ++c) {
        float v = (sS[c * 64 + lane] - mu) * rs * w[c] + b[c];
        dst[(size_t)c * L4 + l0 + lane] = geluf(v);
    }
}

// ---- LDS-staged channel GEMM (tail c2; nin % 56 == 0) ----
__global__ void __launch_bounds__(256) k_gemm(
        const float* __restrict__ src, BP w, BP bvec, const float* __restrict__ addsrc,
        float* __restrict__ dst, int nin, int nout) {
    int lane = threadIdx.x & 63;
    int jg = threadIdx.x >> 6;
    int l0 = blockIdx.x * 64;
    int j0 = blockIdx.y * 16;
    __shared__ __align__(16) float sS[56 * 64];
    __shared__ __align__(16) float sw[16 * 56];
    float acc[4] = {0.f, 0.f, 0.f, 0.f};

    for (int i0 = 0; i0 < nin; i0 += 56) {
        __syncthreads();
        for (int idx = threadIdx.x; idx < 56 * 64; idx += 256) {
            int ii = idx >> 6, px = idx & 63;
            sS[idx] = src[(size_t)(i0 + ii) * L4 + l0 + px];
        }
        for (int idx = threadIdx.x; idx < 16 * 56; idx += 256) {
            int jj = idx / 56, ii = idx - jj * 56;
            int j = j0 + jj;
            sw[idx] = (j < nout) ? w[(size_t)j * nin + i0 + ii] : 0.f;
        }
        __syncthreads();
        #pragma unroll
        for (int ii = 0; ii < 56; ii += 4) {
            float s0 = sS[(ii + 0) * 64 + lane];
            float s1 = sS[(ii + 1) * 64 + lane];
            float s2 = sS[(ii + 2) * 64 + lane];
            float s3 = sS[(ii + 3) * 64 + lane];
            #pragma unroll
            for (int jj = 0; jj < 4; ++jj) {
                const float4 wv = *(const float4*)&sw[(jg * 4 + jj) * 56 + ii];
                acc[jj] += s0 * wv.x + s1 * wv.y + s2 * wv.z + s3 * wv.w;
            }
        }
    }
    int l = l0 + lane;
    #pragma unroll
    for (int jj = 0; jj < 4; ++jj) {
        int j = j0 + jg * 4 + jj;
        if (j >= nout) continue;
        float v = acc[jj];
        if (bvec) v += bf(bvec, j);
        size_t idx = (size_t)j * L4 + l;
        if (addsrc) v += addsrc[idx];
        dst[idx] = v;
    }
}

// ---- tail c1 560->56 split-K: grid (64, 4, 5) ----
__global__ void __launch_bounds__(256) k_c1(
        const float* __restrict__ src, BP w, float* __restrict__ part) {
    int lane = threadIdx.x & 63;
    int jg = threadIdx.x >> 6;
    int l0 = blockIdx.x * 64;
    int j0 = blockIdx.y * 16;
    int z = blockIdx.z;
    __shared__ __align__(16) float sS[56 * 64];
    __shared__ __align__(16) float sw[16 * 56];
    float acc[4] = {0.f, 0.f, 0.f, 0.f};

    for (int i0 = z * 112; i0 < z * 112 + 112; i0 += 56) {
        __syncthreads();
        for (int idx = threadIdx.x; idx < 56 * 64; idx += 256) {
            int ii = idx >> 6, px = idx & 63;
            sS[idx] = src[(size_t)(i0 + ii) * L4 + l0 + px];
        }
        for (int idx = threadIdx.x; idx < 16 * 56; idx += 256) {
            int jj = idx / 56, ii = idx - jj * 56;
            int j = j0 + jj;
            sw[idx] = (j < 56) ? w[(size_t)j * 560 + i0 + ii] : 0.f;
        }
        __syncthreads();
        #pragma unroll
        for (int ii = 0; ii < 56; ii += 4) {
            float s0 = sS[(ii + 0) * 64 + lane];
            float s1 = sS[(ii + 1) * 64 + lane];
            float s2 = sS[(ii + 2) * 64 + lane];
            float s3 = sS[(ii + 3) * 64 + lane];
            #pragma unroll
            for (int jj = 0; jj < 4; ++jj) {
                const float4 wv = *(const float4*)&sw[(jg * 4 + jj) * 56 + ii];
                acc[jj] += s0 * wv.x + s1 * wv.y + s2 * wv.z + s3 * wv.w;
            }
        }
    }
    int l = l0 + lane;
    #pragma unroll
    for (int jj = 0; jj < 4; ++jj) {
        int j = j0 + jg * 4 + jj;
        if (j < 56) part[(size_t)(z * 56 + j) * L4 + l] = acc[jj];
    }
}

// ---- x-projection 112->144, 32-px tiles, single K-chunk ----
__global__ void __launch_bounds__(256) k_xproj(
        const float* __restrict__ src, BP w, float* __restrict__ dst) {
    int lane = threadIdx.x & 31;
    int jg = threadIdx.x >> 5;
    int l0 = blockIdx.x * 32;
    int j0 = blockIdx.y * 16;
    __shared__ __align__(16) float sS[112 * 32];
    __shared__ __align__(16) float sw[16 * 112];
    float acc[2] = {0.f, 0.f};

    for (int idx = threadIdx.x; idx < 112 * 32; idx += 256) {
        int ii = idx >> 5, px = idx & 31;
        sS[idx] = src[(size_t)ii * L4 + l0 + px];
    }
    for (int idx = threadIdx.x; idx < 16 * 112; idx += 256) {
        int jj = idx / 112, ii = idx - jj * 112;
        sw[idx] = w[(size_t)(j0 + jj) * 112 + ii];
    }
    __syncthreads();
    #pragma unroll
    for (int ii = 0; ii < 112; ii += 4) {
        float s0 = sS[(ii + 0) * 32 + lane];
        float s1 = sS[(ii + 1) * 32 + lane];
        float s2 = sS[(ii + 2) * 32 + lane];
        float s3 = sS[(ii + 3) * 32 + lane];
        #pragma unroll
        for (int jj = 0; jj < 2; ++jj) {
            const float4 wv = *(const float4*)&sw[(jg * 2 + jj) * 112 + ii];
            acc[jj] += s0 * wv.x + s1 * wv.y + s2 * wv.z + s3 * wv.w;
        }
    }
    __syncthreads();
    #pragma unroll
    for (int jj = 0; jj < 2; ++jj)
        sS[(jg * 2 + jj) * 32 + lane] = acc[jj];
    __syncthreads();
    for (int idx = threadIdx.x; idx < 16 * 32; idx += 256) {
        int cidx = idx & 15, l2 = idx >> 4;
        int j = j0 + cidx;
        int k = j / 36, c = j - k * 36;
        dst[((size_t)k * L4 + l0 + l2) * 36 + c] = sS[cidx * 32 + l2];
    }
}

// ---- in-proj GEMM with fused LN (nin = 56, single K chunk) ----
__global__ void __launch_bounds__(256) k_gemm_ln(
        const float* __restrict__ src, BP lnw, BP lnb, BP w,
        float* __restrict__ dst, int nout) {
    int lane = threadIdx.x & 63;
    int jg = threadIdx.x >> 6;
    int l0 = blockIdx.x * 64;
    int j0 = blockIdx.y * 16;
    __shared__ __align__(16) float sS[56 * 64];
    __shared__ __align__(16) float sw[16 * 56];
    __shared__ float sLw[56], sLb[56];
    float acc[4] = {0.f, 0.f, 0.f, 0.f};

    for (int idx = threadIdx.x; idx < 56 * 64; idx += 256) {
        int ii = idx >> 6, px = idx & 63;
        sS[idx] = src[(size_t)ii * L4 + l0 + px];
    }
    for (int idx = threadIdx.x; idx < 16 * 56; idx += 256) {
        int jj = idx / 56, ii = idx - jj * 56;
        int j = j0 + jj;
        sw[idx] = (j < nout) ? w[(size_t)j * 56 + ii] : 0.f;
    }
    if (threadIdx.x < 56) { sLw[threadIdx.x] = lnw[threadIdx.x]; sLb[threadIdx.x] = lnb[threadIdx.x]; }
    __syncthreads();
    if (threadIdx.x < 64) {
        int px = threadIdx.x;
        float s = 0.f, s2 = 0.f;
        for (int ii = 0; ii < 56; ++ii) { float v = sS[ii * 64 + px]; s += v; s2 += v * v; }
        float mu = s / 56.f;
        float var = fmaxf(s2 / 56.f - mu * mu, 0.f);
        float rstd = rsqrtf(var + 1e-5f);
        for (int ii = 0; ii < 56; ++ii)
            sS[ii * 64 + px] = (sS[ii * 64 + px] - mu) * rstd * sLw[ii] + sLb[ii];
    }
    __syncthreads();
    #pragma unroll
    for (int ii = 0; ii < 56; ii += 4) {
        float s0 = sS[(ii + 0) * 64 + lane];
        float s1 = sS[(ii + 1) * 64 + lane];
        float s2 = sS[(ii + 2) * 64 + lane];
        float s3 = sS[(ii + 3) * 64 + lane];
        #pragma unroll
        for (int jj = 0; jj < 4; ++jj) {
            const float4 wv = *(const float4*)&sw[(jg * 4 + jj) * 56 + ii];
            acc[jj] += s0 * wv.x + s1 * wv.y + s2 * wv.z + s3 * wv.w;
        }
    }
    int l = l0 + lane;
    #pragma unroll
    for (int jj = 0; jj < 4; ++jj) {
        int j = j0 + jg * 4 + jj;
        if (j < nout) dst[(size_t)j * L4 + l] = acc[jj];
    }
}

// ---- chunked selective scan; batched loads, LDS-staged coalesced y store ----
#define SPAD(p) ((p) + ((p) >> 5))
__global__ void __launch_bounds__(1024, 8) k_scan(
        const float* __restrict__ xc, const float* __restrict__ pk,
        BP Alog, BP dtw, BP dtb, float* __restrict__ ybuf) {
    int pair = blockIdx.x;           // k*112+d
    int n = threadIdx.x & 15;        // state index
    int c = threadIdx.x >> 4;        // chunk index, 0..63
    int k = pair / DI, d = pair - k * DI;
    float a = -__expf(Alog[pair * DSN + n]);
    float w0 = dtw[pair * 4 + 0], w1 = dtw[pair * 4 + 1];
    float w2 = dtw[pair * 4 + 2], w3 = dtw[pair * 4 + 3];
    float db = dtb[pair];
    const float* xptr = xc + (size_t)d * L4;
    const float* pkk = pk + (size_t)k * L4 * 36;
    float* yptr = ybuf + (size_t)pair * L4;

    __shared__ float sDl[4224];
    __shared__ float sDlx[4224];
    __shared__ float sP[64 * 16];
    __shared__ float sHe[64 * 16];
    __shared__ float sY[64 * 65];    // y staged per (chunk, step), padded

    // phase 0: cooperative delta precompute (float4 row load)
    for (int p = threadIdx.x; p < L4; p += 1024) {
        const float4 r4 = *(const float4*)(pkk + (size_t)p * 36);
        float v = db + r4.x * w0 + r4.y * w1 + r4.z * w2 + r4.w * w3;
        float dl = fmaxf(v, 0.f) + __logf(1.f + __expf(-fabsf(v)));
        sDl[SPAD(p)] = dl;
        sDlx[SPAD(p)] = dl * xptr[p];
    }
    __syncthreads();

    int p0, dp;
    if (k == 0)      { p0 = c * 64;        dp = 1;   }
    else if (k == 1) { p0 = c;             dp = 64;  }
    else if (k == 2) { p0 = 4095 - c * 64; dp = -1;  }
    else             { p0 = 4095 - c;      dp = -64; }
    long rstep = (long)dp * 36;

    // phase 1: local chunk scan, 4-deep load batching
    float h = 0.f, P = 1.f;
    {
        int p = p0;
        const float* rB = pkk + (size_t)p0 * 36 + 4 + n;
        for (int jb = 0; jb < 64; jb += 4) {
            float Bv[4], ev[4], dxv[4];
            #pragma unroll
            for (int u = 0; u < 4; ++u) {
                int q = SPAD(p + u * dp);
                Bv[u] = rB[u * rstep];
                ev[u] = __expf(sDl[q] * a);
                dxv[u] = sDlx[q];
            }
            #pragma unroll
            for (int u = 0; u < 4; ++u) {
                h = ev[u] * h + dxv[u] * Bv[u];
                P *= ev[u];
            }
            p += 4 * dp; rB += 4 * rstep;
        }
    }
    int idx = c * 16 + n;
    sP[idx] = P;
    sHe[idx] = h;
    __syncthreads();

    // phase 2: Kogge-Stone inclusive scan over chunks
    for (int off = 1; off < 64; off <<= 1) {
        float pC = sP[idx], hC = sHe[idx];
        float pL = 0.f, hL = 0.f;
        if (c >= off) { pL = sP[idx - off * 16]; hL = sHe[idx - off * 16]; }
        __syncthreads();
        if (c >= off) { sP[idx] = pC * pL; sHe[idx] = pC * hL + hC; }
        __syncthreads();
    }

    // phase 3: re-scan with carry, stage y in LDS
    h = (c > 0) ? sHe[idx - 16] : 0.f;
    {
        int p = p0;
        const float* rB = pkk + (size_t)p0 * 36 + 4 + n;
        const float* rC = pkk + (size_t)p0 * 36 + 20 + n;
        for (int jb = 0; jb < 64; jb += 4) {
            float Bv[4], Cv[4], ev[4], dxv[4];
            #pragma unroll
            for (int u = 0; u < 4; ++u) {
                int q = SPAD(p + u * dp);
                Bv[u] = rB[u * rstep];
                Cv[u] = rC[u * rstep];
                ev[u] = __expf(sDl[q] * a);
                dxv[u] = sDlx[q];
            }
            #pragma unroll
            for (int u = 0; u < 4; ++u) {
                h = ev[u] * h + dxv[u] * Bv[u];
                float y = h * Cv[u];
                y += __shfl_xor(y, 1, 16);
                y += __shfl_xor(y, 2, 16);
                y += __shfl_xor(y, 4, 16);
                y += __shfl_xor(y, 8, 16);
                if (n == 0) sY[c * 65 + jb + u] = y;
            }
            p += 4 * dp; rB += 4 * rstep; rC += 4 * rstep;
        }
    }
    __syncthreads();

    // epilogue: coalesced y store
    for (int pp = threadIdx.x; pp < L4; pp += 1024) {
        int q = (k >= 2) ? (4095 - pp) : pp;
        int cc, jj;
        if (k & 1) { cc = q & 63; jj = q >> 6; }
        else       { cc = q >> 6; jj = q & 63; }
        yptr[pp] = sY[cc * 65 + jj];
    }
}

// ---- fused: combine + LN112 + gate + out-proj + residual + LN56; 16-px tiles ----
__global__ void __launch_bounds__(256) k_comb_proj(
        const float* __restrict__ ybuf, const float* __restrict__ xc,
        const float* __restrict__ zbuf, BP Dp, BP ow, BP ob, BP opw,
        const float* __restrict__ xin, BP nw, BP nbv,
        float* __restrict__ x_mid, float* __restrict__ xln) {
    int lane = threadIdx.x & 15;
    int grp = threadIdx.x >> 4;
    int l0 = blockIdx.x * 16;
    __shared__ __align__(16) float sY[112 * 16];
    __shared__ __align__(16) float sW[56 * 112];
    __shared__ float sPa[16][16], sPb[16][16];
    __shared__ float sMu[16], sRs[16];

    float ps = 0.f, ps2 = 0.f;
    for (int d = grp * 7; d < grp * 7 + 7; ++d) {
        float Ds = Dp[d] + Dp[DI + d] + Dp[2 * DI + d] + Dp[3 * DI + d];
        float v = ybuf[(size_t)d * L4 + l0 + lane]
                + ybuf[(size_t)(DI + d) * L4 + l0 + lane]
                + ybuf[(size_t)(2 * DI + d) * L4 + l0 + lane]
                + ybuf[(size_t)(3 * DI + d) * L4 + l0 + lane]
                + Ds * xc[(size_t)d * L4 + l0 + lane];
        sY[d * 16 + lane] = v; ps += v; ps2 += v * v;
    }
    sPa[grp][lane] = ps; sPb[grp][lane] = ps2;
    for (int idx = threadIdx.x; idx < 56 * 112; idx += 256) sW[idx] = opw[idx];
    __syncthreads();
    if (threadIdx.x < 16) {
        float s = 0.f, s2 = 0.f;
        for (int g = 0; g < 16; ++g) { s += sPa[g][lane]; s2 += sPb[g][lane]; }
        float mu = s / 112.f;
        float var = fmaxf(s2 / 112.f - mu * mu, 0.f);
        sMu[lane] = mu; sRs[lane] = rsqrtf(var + 1e-5f);
    }
    __syncthreads();
    {
        float mu = sMu[lane], rs = sRs[lane];
        for (int d = grp * 7; d < grp * 7 + 7; ++d) {
            float v = (sY[d * 16 + lane] - mu) * rs * ow[d] + ob[d];
            float z = zbuf[(size_t)d * L4 + l0 + lane];
            sY[d * 16 + lane] = v * siluf(z);
        }
    }
    __syncthreads();

    float acc[4] = {0.f, 0.f, 0.f, 0.f};
    #pragma unroll 2
    for (int ii = 0; ii < 112; ii += 4) {
        float s0 = sY[(ii + 0) * 16 + lane];
        float s1 = sY[(ii + 1) * 16 + lane];
        float s2 = sY[(ii + 2) * 16 + lane];
        float s3 = sY[(ii + 3) * 16 + lane];
        #pragma unroll
        for (int jj = 0; jj < 4; ++jj) {
            int j = grp * 4 + jj;
            if (j < 56) {
                const float4 wv = *(const float4*)&sW[j * 112 + ii];
                acc[jj] += s0 * wv.x + s1 * wv.y + s2 * wv.z + s3 * wv.w;
            }
        }
    }
    int l = l0 + lane;
    float vout[4];
    float ps3 = 0.f, ps4 = 0.f;
    #pragma unroll
    for (int jj = 0; jj < 4; ++jj) {
        int j = grp * 4 + jj;
        vout[jj] = 0.f;
        if (j < 56) {
            float v = acc[jj] + xin[(size_t)j * L4 + l];
            vout[jj] = v;
            x_mid[(size_t)j * L4 + l] = v;
            ps3 += v; ps4 += v * v;
        }
    }
    __syncthreads();
    sPa[grp][lane] = ps3; sPb[grp][lane] = ps4;
    __syncthreads();
    if (threadIdx.x < 16) {
        float s = 0.f, s2 = 0.f;
        for (int g = 0; g < 16; ++g) { s += sPa[g][lane]; s2 += sPb[g][lane]; }
        float mu = s / 56.f;
        float var = fmaxf(s2 / 56.f - mu * mu, 0.f);
        sMu[lane] = mu; sRs[lane] = rsqrtf(var + 1e-6f);
    }
    __syncthreads();
    {
        float mu = sMu[lane], rs = sRs[lane];
        #pragma unroll
        for (int jj = 0; jj < 4; ++jj) {
            int j = grp * 4 + jj;
            if (j < 56) xln[(size_t)j * L4 + l] = (vout[jj] - mu) * rs * nw[j] + nbv[j];
        }
    }
}

// ---- fused SAFM pools+depthwise: grid 224 (i=0 tiles) + 42 (i>=1 channels) ----
__global__ void __launch_bounds__(256) k_safm(
        const float* __restrict__ xln, BP mw, BP mb,
        float* __restrict__ s0, float* __restrict__ s1,
        float* __restrict__ s2, float* __restrict__ s3) {
    int b = blockIdx.x;
    if (b < 224) {
        int c = b >> 4;
        int tile = b & 15;
        int y0 = (tile >> 2) * 16, x0 = (tile & 3) * 16;
        __shared__ float sT[18 * 18];
        const float* sc = xln + (size_t)c * L4;
        for (int idx = threadIdx.x; idx < 324; idx += 256) {
            int iy = idx / 18, ix = idx - iy * 18;
            int gy = y0 - 1 + iy, gx = x0 - 1 + ix;
            sT[idx] = (gy >= 0 && gy < 64 && gx >= 0 && gx < 64) ? sc[gy * 64 + gx] : 0.f;
        }
        __syncthreads();
        int py = threadIdx.x >> 4, px = threadIdx.x & 15;
        BP wr = mw + c * 9;
        float acc = mb[c];
        #pragma unroll
        for (int ky = 0; ky < 3; ++ky)
            #pragma unroll
            for (int kx = 0; kx < 3; ++kx)
                acc += sT[(py + ky) * 18 + px + kx] * wr[ky * 3 + kx];
        s0[c * L4 + (y0 + py) * 64 + x0 + px] = acc;
    } else {
        int bb = b - 224;
        int i = bb / 14 + 1;
        int c = bb % 14;
        int S = 64 >> i;
        int f = 1 << i;
        __shared__ float sP[34 * 34];
        int W2 = S + 2;
        for (int idx = threadIdx.x; idx < W2 * W2; idx += 256) sP[idx] = 0.f;
        __syncthreads();
        const float* sc = xln + (size_t)(i * 14 + c) * L4;
        for (int cell = threadIdx.x; cell < S * S; cell += 256) {
            int y = cell / S, x = cell - y * S;
            float m = -3.4e38f;
            for (int dy = 0; dy < f; ++dy)
                for (int dx = 0; dx < f; ++dx)
                    m = fmaxf(m, sc[(y * f + dy) * 64 + x * f + dx]);
            sP[(y + 1) * W2 + x + 1] = m;
        }
        __syncthreads();
        BP wr = mw + (i * 14 + c) * 9;
        float bias = mb[i * 14 + c];
        float* dst = (i == 1) ? s1 : (i == 2) ? s2 : s3;
        for (int cell = threadIdx.x; cell < S * S; cell += 256) {
            int y = cell / S, x = cell - y * S;
            float acc = bias;
            #pragma unroll
            for (int ky = 0; ky < 3; ++ky)
                #pragma unroll
                for (int kx = 0; kx < 3; ++kx)
                    acc += sP[(y + ky) * W2 + x + kx] * wr[ky * 3 + kx];
            dst[c * S * S + cell] = acc;
        }
    }
}

// ---- SAFM aggregate 1x1 + gelu gate + residual, writes trunk slice ----
__global__ void k_aggr(const float* __restrict__ s0, const float* __restrict__ s1,
                       const float* __restrict__ s2, const float* __restrict__ s3,
                       const float* __restrict__ xln, const float* __restrict__ x_mid,
                       BP aw, BP ab, float* __restrict__ out) {
    int tid = blockIdx.x * blockDim.x + threadIdx.x;
    if (tid >= CC * L4) return;
    int c = tid >> 12, l = tid & 4095;
    int h = l >> 6, w = l & 63;
    int o1 = (h >> 1) * 32 + (w >> 1);
    int o2 = (h >> 2) * 16 + (w >> 2);
    int o3 = (h >> 3) * 8 + (w >> 3);
    float acc = bf(ab, c);
    BP wr = aw + c * 56;
    for (int cg = 0; cg < 14; ++cg) acc += s0[cg * 4096 + l]  * bf(wr, cg);
    for (int cg = 0; cg < 14; ++cg) acc += s1[cg * 1024 + o1] * bf(wr, 14 + cg);
    for (int cg = 0; cg < 14; ++cg) acc += s2[cg * 256 + o2]  * bf(wr, 28 + cg);
    for (int cg = 0; cg < 14; ++cg) acc += s3[cg * 64 + o3]   * bf(wr, 42 + cg);
    out[tid] = x_mid[tid] + geluf(acc) * xln[tid];
}

// ---- up conv 3x3 (56->27) + pixel shuffle x3, LDS-staged, fp32 output ----
__global__ void __launch_bounds__(256) k_up(
        const float* __restrict__ out_lr, BP uw, BP ub, float* __restrict__ out) {
    __shared__ float sIn[56 * 36];
    __shared__ float sW[27 * 56 * 9];
    int b = blockIdx.x;
    int y0 = (b >> 4) * 4, x0 = (b & 15) * 4;
    for (int idx = threadIdx.x; idx < 56 * 36; idx += 256) {
        int cc = idx / 36; int rem = idx - cc * 36; int iy = rem / 6, ix = rem - iy * 6;
        int gy = y0 - 1 + iy, gx = x0 - 1 + ix;
        sIn[idx] = (gy >= 0 && gy < 64 && gx >= 0 && gx < 64)
                 ? out_lr[(size_t)cc * L4 + gy * 64 + gx] : 0.f;
    }
    for (int idx = threadIdx.x; idx < 27 * 56 * 9; idx += 256) sW[idx] = uw[idx];
    __syncthreads();
    int px = threadIdx.x & 15;
    int og = threadIdx.x >> 4;
    int dy = px >> 2, dx = px & 3;
    for (int oo = 0; oo < 2; ++oo) {
        int o = og * 2 + oo;
        if (o >= 27) break;
        float acc = ub[o];
        const float* wb = &sW[o * 504];
        for (int cc = 0; cc < 56; ++cc) {
            const float* ib = &sIn[cc * 36 + dy * 6 + dx];
            const float* wc = wb + cc * 9;
            acc += ib[0] * wc[0] + ib[1] * wc[1] + ib[2] * wc[2]
                 + ib[6] * wc[3] + ib[7] * wc[4] + ib[8] * wc[5]
                 + ib[12] * wc[6] + ib[13] * wc[7] + ib[14] * wc[8];
        }
        int h = y0 + dy, wv = x0 + dx;
        int ch = o / 9, rr = (o % 9) / 3, ss = o % 3;
        out[ch * 36864 + (h * 3 + rr) * 192 + (wv * 3 + ss)] = acc;
    }
}

extern "C" void kernel_launch(void* const* d_in, const int* in_sizes, int n_in,
                              void* d_out, int out_size, void* d_ws, size_t ws_size,
                              hipStream_t stream) {
    BP in0  = (BP)d_in[0];
    BP in1  = (BP)d_in[1];
    BP in2  = (BP)d_in[2];
    BP in3  = (BP)d_in[3];
    BP in4  = (BP)d_in[4];
    BP in5  = (BP)d_in[5];
    BP in6  = (BP)d_in[6];
    BP in7  = (BP)d_in[7];
    BP in8  = (BP)d_in[8];
    BP in9  = (BP)d_in[9];
    BP in10 = (BP)d_in[10];
    BP in11 = (BP)d_in[11];
    BP in12 = (BP)d_in[12];
    BP in13 = (BP)d_in[13];
    BP in14 = (BP)d_in[14];
    BP in15 = (BP)d_in[15];
    BP in16 = (BP)d_in[16];
    BP in17 = (BP)d_in[17];
    BP in18 = (BP)d_in[18];
    BP in19 = (BP)d_in[19];
    BP in20 = (BP)d_in[20];
    BP in21 = (BP)d_in[21];
    BP in22 = (BP)d_in[22];
    BP in23 = (BP)d_in[23];
    BP in24 = (BP)d_in[24];
    BP in25 = (BP)d_in[25];
    BP in26 = (BP)d_in[26];
    BP in27 = (BP)d_in[27];
    BP in28 = (BP)d_in[28];
    BP in29 = (BP)d_in[29];
    BP in30 = (BP)d_in[30];
    BP in31 = (BP)d_in[31];

    float* ws = (float*)d_ws;
    float* trunk   = ws; ws += 560 * L4;
    float* out_fea = ws; ws += CC * L4;
    float* t0      = ws; ws += CC * L4;
    float* xz      = ws; ws += 224 * L4;
    float* xc      = ws; ws += DI * L4;
    float* pk      = ws; ws += 4 * 36 * L4;
    float* ybuf    = ws; ws += 4 * DI * L4;
    float* x_mid   = ws; ws += CC * L4;
    float* xln     = ws; ws += CC * L4;
    float* s0      = ws; ws += 14 * 4096;
    float* s1      = ws; ws += 14 * 1024;
    float* s2      = ws; ws += 14 * 256;
    float* s3      = ws; ws += 14 * 64;
    float* part    = ws; ws += 5 * 56 * L4;
    float* gB      = ws; ws += CC * L4;
    float* tbuf    = ws; ws += CC * L4;
    float* out_lr  = ws; ws += CC * L4;

    auto nb256 = [](int n) { return dim3((n + 255) / 256); };
    auto gemm_grid = [](int nout) { return dim3(64, (nout + 15) / 16); };

    // stem
    k_fea_pw<<<nb256(CC * L4), 256, 0, stream>>>(in0, in1, t0);
    k_dw3x3t<<<dim3(CC * 16), 256, 0, stream>>>(t0, in2, in3, out_fea, 0, nullptr);

    for (int nb = 0; nb < NBLK; ++nb) {
        const float* xin = (nb == 0) ? out_fea : trunk + (size_t)(nb - 1) * CC * L4;
        float* xout = trunk + (size_t)nb * CC * L4;
        BP ln1w = in4 + nb * 56,        ln1b = in5 + nb * 56;
        BP ipw  = in6 + nb * 224 * 56;
        BP cw   = in7 + nb * 112 * 9,   cb   = in8 + nb * 112;
        BP xpw  = in9 + nb * 4 * 36 * 112;
        BP dtw  = in10 + nb * 4 * 112 * 4, dtb = in11 + nb * 448;
        BP alog = in12 + nb * 448 * 16, Dp   = in13 + nb * 448;
        BP onw  = in14 + nb * 112,      onb  = in15 + nb * 112;
        BP opw  = in16 + nb * 56 * 112;
        BP nw   = in17 + nb * 56,       nbv  = in18 + nb * 56;
        BP mw   = in19 + nb * 4 * 14 * 9, mb = in20 + nb * 56;
        BP aw   = in21 + nb * 56 * 56,  ab   = in22 + nb * 56;

        k_gemm_ln<<<gemm_grid(224), 256, 0, stream>>>(xin, ln1w, ln1b, ipw, xz, 224);
        k_dw3x3t<<<dim3(DI * 16), 256, 0, stream>>>(xz, cw, cb, xc, 1, nullptr);
        k_xproj<<<dim3(128, 9), 256, 0, stream>>>(xc, xpw, pk);
        k_scan<<<dim3(4 * DI), 1024, 0, stream>>>(xc, pk, alog, dtw, dtb, ybuf);
        k_comb_proj<<<dim3(256), 256, 0, stream>>>(ybuf, xc, xz + 112 * L4, Dp, onw, onb, opw,
                                                   xin, nw, nbv, x_mid, xln);
        k_safm<<<dim3(266), 256, 0, stream>>>(xln, mw, mb, s0, s1, s2, s3);
        k_aggr<<<nb256(CC * L4), 256, 0, stream>>>(s0, s1, s2, s3, xln, x_mid, aw, ab, xout);
    }

    // tail
    k_c1<<<dim3(64, 4, 5), 256, 0, stream>>>(trunk, in23, part);
    k_ln56g<<<dim3(64), 256, 0, stream>>>(part, in24, in25, in26, gB);
    k_gemm<<<gemm_grid(56), 256, 0, stream>>>(gB, in27, nullptr, nullptr, tbuf, 56, 56);
    k_dw3x3t<<<dim3(CC * 16), 256, 0, stream>>>(tbuf, in28, in29, out_lr, 0, out_fea);
    k_up<<<dim3(256), 256, 0, stream>>>(out_lr, in30, in31, (float*)d_out);
}

// Round 14
// 1157.998 us; speedup vs baseline: 3.4256x; 1.1197x over previous
//
#include <hip/hip_runtime.h>
#include <hip/hip_bf16.h>

#define HW 64
#define L4 4096
#define CC 56
#define DI 112
#define DSN 16
#define NBLK 10

typedef const float* BP;

__device__ __forceinline__ float bf(BP p, int i) { return p[i]; }
__device__ __forceinline__ float siluf(float x) { return x / (1.f + __expf(-x)); }
__device__ __forceinline__ float geluf(float x) { return 0.5f * x * (1.f + erff(x * 0.70710678f)); }

// ---- stem: pointwise 3->56 ----
__global__ void k_fea_pw(BP x, BP w, float* __restrict__ t0) {
    int tid = blockIdx.x * blockDim.x + threadIdx.x;
    if (tid >= CC * L4) return;
    int c = tid >> 12, l = tid & 4095;
    float acc = 0.f;
    for (int i = 0; i < 3; ++i) acc += bf(x, i * L4 + l) * bf(w, c * 3 + i);
    t0[tid] = acc;
}

// ---- tiled depthwise 3x3 for 64x64 maps: grid = nch*16, block 256 (16x16 px) ----
__global__ void __launch_bounds__(256) k_dw3x3t(
        const float* __restrict__ src, BP w, BP bvec, float* __restrict__ dst,
        int act, const float* __restrict__ addsrc) {
    int c = blockIdx.x >> 4;
    int tile = blockIdx.x & 15;
    int y0 = (tile >> 2) * 16, x0 = (tile & 3) * 16;
    __shared__ float sT[18 * 18];
    const float* sc = src + (size_t)c * L4;
    for (int idx = threadIdx.x; idx < 324; idx += 256) {
        int iy = idx / 18, ix = idx - iy * 18;
        int gy = y0 - 1 + iy, gx = x0 - 1 + ix;
        sT[idx] = (gy >= 0 && gy < 64 && gx >= 0 && gx < 64) ? sc[gy * 64 + gx] : 0.f;
    }
    __syncthreads();
    int py = threadIdx.x >> 4, px = threadIdx.x & 15;
    BP wr = w + c * 9;
    float acc = bvec ? bvec[c] : 0.f;
    #pragma unroll
    for (int ky = 0; ky < 3; ++ky)
        #pragma unroll
        for (int kx = 0; kx < 3; ++kx)
            acc += sT[(py + ky) * 18 + px + kx] * wr[ky * 3 + kx];
    if (act) acc = siluf(acc);
    int l = (y0 + py) * 64 + x0 + px;
    if (addsrc) acc += addsrc[(size_t)c * L4 + l];
    dst[(size_t)c * L4 + l] = acc;
}

// ---- tail LN56 over sum of 5 split-K partials + bias, then gelu ----
__global__ void __launch_bounds__(256) k_ln56g(
        const float* __restrict__ part, BP bias, BP w, BP b, float* __restrict__ dst) {
    int lane = threadIdx.x & 63;
    int cg = threadIdx.x >> 6;
    int l0 = blockIdx.x * 64;
    __shared__ float sS[56 * 64];
    __shared__ float sPa[4][64], sPb[4][64];
    __shared__ float sMu[64], sRs[64];
    float ps = 0.f, ps2 = 0.f;
    for (int c = cg * 14; c < cg * 14 + 14; ++c) {
        float v = bias[c];
        #pragma unroll
        for (int z = 0; z < 5; ++z)
            v += part[(size_t)(z * 56 + c) * L4 + l0 + lane];
        sS[c * 64 + lane] = v; ps += v; ps2 += v * v;
    }
    sPa[cg][lane] = ps; sPb[cg][lane] = ps2;
    __syncthreads();
    if (threadIdx.x < 64) {
        float s = sPa[0][lane] + sPa[1][lane] + sPa[2][lane] + sPa[3][lane];
        float s2 = sPb[0][lane] + sPb[1][lane] + sPb[2][lane] + sPb[3][lane];
        float mu = s / 56.f;
        float var = fmaxf(s2 / 56.f - mu * mu, 0.f);
        sMu[lane] = mu; sRs[lane] = rsqrtf(var + 1e-6f);
    }
    __syncthreads();
    float mu = sMu[lane], rs = sRs[lane];
    for (int c = cg * 14; c < cg * 14 + 14; ++c) {
        float v = (sS[c * 64 + lane] - mu) * rs * w[c] + b[c];
        dst[(size_t)c * L4 + l0 + lane] = geluf(v);
    }
}

// ---- LDS-staged channel GEMM (tail c2; nin % 56 == 0) ----
__global__ void __launch_bounds__(256) k_gemm(
        const float* __restrict__ src, BP w, BP bvec, const float* __restrict__ addsrc,
        float* __restrict__ dst, int nin, int nout) {
    int lane = threadIdx.x & 63;
    int jg = threadIdx.x >> 6;
    int l0 = blockIdx.x * 64;
    int j0 = blockIdx.y * 16;
    __shared__ __align__(16) float sS[56 * 64];
    __shared__ __align__(16) float sw[16 * 56];
    float acc[4] = {0.f, 0.f, 0.f, 0.f};

    for (int i0 = 0; i0 < nin; i0 += 56) {
        __syncthreads();
        for (int idx = threadIdx.x; idx < 56 * 64; idx += 256) {
            int ii = idx >> 6, px = idx & 63;
            sS[idx] = src[(size_t)(i0 + ii) * L4 + l0 + px];
        }
        for (int idx = threadIdx.x; idx < 16 * 56; idx += 256) {
            int jj = idx / 56, ii = idx - jj * 56;
            int j = j0 + jj;
            sw[idx] = (j < nout) ? w[(size_t)j * nin + i0 + ii] : 0.f;
        }
        __syncthreads();
        #pragma unroll
        for (int ii = 0; ii < 56; ii += 4) {
            float s0 = sS[(ii + 0) * 64 + lane];
            float s1 = sS[(ii + 1) * 64 + lane];
            float s2 = sS[(ii + 2) * 64 + lane];
            float s3 = sS[(ii + 3) * 64 + lane];
            #pragma unroll
            for (int jj = 0; jj < 4; ++jj) {
                const float4 wv = *(const float4*)&sw[(jg * 4 + jj) * 56 + ii];
                acc[jj] += s0 * wv.x + s1 * wv.y + s2 * wv.z + s3 * wv.w;
            }
        }
    }
    int l = l0 + lane;
    #pragma unroll
    for (int jj = 0; jj < 4; ++jj) {
        int j = j0 + jg * 4 + jj;
        if (j >= nout) continue;
        float v = acc[jj];
        if (bvec) v += bf(bvec, j);
        size_t idx = (size_t)j * L4 + l;
        if (addsrc) v += addsrc[idx];
        dst[idx] = v;
    }
}

// ---- tail c1 560->56 split-K: grid (64, 4, 5) ----
__global__ void __launch_bounds__(256) k_c1(
        const float* __restrict__ src, BP w, float* __restrict__ part) {
    int lane = threadIdx.x & 63;
    int jg = threadIdx.x >> 6;
    int l0 = blockIdx.x * 64;
    int j0 = blockIdx.y * 16;
    int z = blockIdx.z;
    __shared__ __align__(16) float sS[56 * 64];
    __shared__ __align__(16) float sw[16 * 56];
    float acc[4] = {0.f, 0.f, 0.f, 0.f};

    for (int i0 = z * 112; i0 < z * 112 + 112; i0 += 56) {
        __syncthreads();
        for (int idx = threadIdx.x; idx < 56 * 64; idx += 256) {
            int ii = idx >> 6, px = idx & 63;
            sS[idx] = src[(size_t)(i0 + ii) * L4 + l0 + px];
        }
        for (int idx = threadIdx.x; idx < 16 * 56; idx += 256) {
            int jj = idx / 56, ii = idx - jj * 56;
            int j = j0 + jj;
            sw[idx] = (j < 56) ? w[(size_t)j * 560 + i0 + ii] : 0.f;
        }
        __syncthreads();
        #pragma unroll
        for (int ii = 0; ii < 56; ii += 4) {
            float s0 = sS[(ii + 0) * 64 + lane];
            float s1 = sS[(ii + 1) * 64 + lane];
            float s2 = sS[(ii + 2) * 64 + lane];
            float s3 = sS[(ii + 3) * 64 + lane];
            #pragma unroll
            for (int jj = 0; jj < 4; ++jj) {
                const float4 wv = *(const float4*)&sw[(jg * 4 + jj) * 56 + ii];
                acc[jj] += s0 * wv.x + s1 * wv.y + s2 * wv.z + s3 * wv.w;
            }
        }
    }
    int l = l0 + lane;
    #pragma unroll
    for (int jj = 0; jj < 4; ++jj) {
        int j = j0 + jg * 4 + jj;
        if (j < 56) part[(size_t)(z * 56 + j) * L4 + l] = acc[jj];
    }
}

// ---- x-projection 112->144, 32-px tiles, single K-chunk ----
__global__ void __launch_bounds__(256) k_xproj(
        const float* __restrict__ src, BP w, float* __restrict__ dst) {
    int lane = threadIdx.x & 31;
    int jg = threadIdx.x >> 5;
    int l0 = blockIdx.x * 32;
    int j0 = blockIdx.y * 16;
    __shared__ __align__(16) float sS[112 * 32];
    __shared__ __align__(16) float sw[16 * 112];
    float acc[2] = {0.f, 0.f};

    for (int idx = threadIdx.x; idx < 112 * 32; idx += 256) {
        int ii = idx >> 5, px = idx & 31;
        sS[idx] = src[(size_t)ii * L4 + l0 + px];
    }
    for (int idx = threadIdx.x; idx < 16 * 112; idx += 256) {
        int jj = idx / 112, ii = idx - jj * 112;
        sw[idx] = w[(size_t)(j0 + jj) * 112 + ii];
    }
    __syncthreads();
    #pragma unroll
    for (int ii = 0; ii < 112; ii += 4) {
        float s0 = sS[(ii + 0) * 32 + lane];
        float s1 = sS[(ii + 1) * 32 + lane];
        float s2 = sS[(ii + 2) * 32 + lane];
        float s3 = sS[(ii + 3) * 32 + lane];
        #pragma unroll
        for (int jj = 0; jj < 2; ++jj) {
            const float4 wv = *(const float4*)&sw[(jg * 2 + jj) * 112 + ii];
            acc[jj] += s0 * wv.x + s1 * wv.y + s2 * wv.z + s3 * wv.w;
        }
    }
    __syncthreads();
    #pragma unroll
    for (int jj = 0; jj < 2; ++jj)
        sS[(jg * 2 + jj) * 32 + lane] = acc[jj];
    __syncthreads();
    for (int idx = threadIdx.x; idx < 16 * 32; idx += 256) {
        int cidx = idx & 15, l2 = idx >> 4;
        int j = j0 + cidx;
        int k = j / 36, c = j - k * 36;
        dst[((size_t)k * L4 + l0 + l2) * 36 + c] = sS[cidx * 32 + l2];
    }
}

// ---- in-proj GEMM with fused LN (nin = 56, single K chunk) ----
__global__ void __launch_bounds__(256) k_gemm_ln(
        const float* __restrict__ src, BP lnw, BP lnb, BP w,
        float* __restrict__ dst, int nout) {
    int lane = threadIdx.x & 63;
    int jg = threadIdx.x >> 6;
    int l0 = blockIdx.x * 64;
    int j0 = blockIdx.y * 16;
    __shared__ __align__(16) float sS[56 * 64];
    __shared__ __align__(16) float sw[16 * 56];
    __shared__ float sLw[56], sLb[56];
    float acc[4] = {0.f, 0.f, 0.f, 0.f};

    for (int idx = threadIdx.x; idx < 56 * 64; idx += 256) {
        int ii = idx >> 6, px = idx & 63;
        sS[idx] = src[(size_t)ii * L4 + l0 + px];
    }
    for (int idx = threadIdx.x; idx < 16 * 56; idx += 256) {
        int jj = idx / 56, ii = idx - jj * 56;
        int j = j0 + jj;
        sw[idx] = (j < nout) ? w[(size_t)j * 56 + ii] : 0.f;
    }
    if (threadIdx.x < 56) { sLw[threadIdx.x] = lnw[threadIdx.x]; sLb[threadIdx.x] = lnb[threadIdx.x]; }
    __syncthreads();
    if (threadIdx.x < 64) {
        int px = threadIdx.x;
        float s = 0.f, s2 = 0.f;
        for (int ii = 0; ii < 56; ++ii) { float v = sS[ii * 64 + px]; s += v; s2 += v * v; }
        float mu = s / 56.f;
        float var = fmaxf(s2 / 56.f - mu * mu, 0.f);
        float rstd = rsqrtf(var + 1e-5f);
        for (int ii = 0; ii < 56; ++ii)
            sS[ii * 64 + px] = (sS[ii * 64 + px] - mu) * rstd * sLw[ii] + sLb[ii];
    }
    __syncthreads();
    #pragma unroll
    for (int ii = 0; ii < 56; ii += 4) {
        float s0 = sS[(ii + 0) * 64 + lane];
        float s1 = sS[(ii + 1) * 64 + lane];
        float s2 = sS[(ii + 2) * 64 + lane];
        float s3 = sS[(ii + 3) * 64 + lane];
        #pragma unroll
        for (int jj = 0; jj < 4; ++jj) {
            const float4 wv = *(const float4*)&sw[(jg * 4 + jj) * 56 + ii];
            acc[jj] += s0 * wv.x + s1 * wv.y + s2 * wv.z + s3 * wv.w;
        }
    }
    int l = l0 + lane;
    #pragma unroll
    for (int jj = 0; jj < 4; ++jj) {
        int j = j0 + jg * 4 + jj;
        if (j < nout) dst[(size_t)j * L4 + l] = acc[jj];
    }
}

// ---- chunked selective scan: 4 states/lane, 4 lanes/chunk, 256-thread blocks ----
#define SPAD(p) ((p) + ((p) >> 5))
__global__ void __launch_bounds__(256) k_scan(
        const float* __restrict__ xc, const float* __restrict__ pk,
        BP Alog, BP dtw, BP dtb, float* __restrict__ ybuf) {
    int pair = blockIdx.x;           // k*112+d
    int s = threadIdx.x & 3;         // state quad (states s*4 .. s*4+3)
    int c = threadIdx.x >> 2;        // chunk index, 0..63
    int k = pair / DI, d = pair - k * DI;
    const float4 al = *(const float4*)(Alog + pair * DSN + s * 4);
    float a0 = -__expf(al.x), a1 = -__expf(al.y), a2 = -__expf(al.z), a3 = -__expf(al.w);
    const float4 wdt = *(const float4*)(dtw + pair * 4);
    float db = dtb[pair];
    const float* xptr = xc + (size_t)d * L4;
    const float* pkk = pk + (size_t)k * L4 * 36;
    float* yptr = ybuf + (size_t)pair * L4;

    __shared__ float sDl[4224];
    __shared__ float sDlx[4224];
    __shared__ float sP[64 * 16];
    __shared__ float sHe[64 * 16];

    // phase 0: cooperative delta precompute (16 per thread)
    for (int p = threadIdx.x; p < L4; p += 256) {
        const float4 r4 = *(const float4*)(pkk + (size_t)p * 36);
        float v = db + r4.x * wdt.x + r4.y * wdt.y + r4.z * wdt.z + r4.w * wdt.w;
        float dl = fmaxf(v, 0.f) + __logf(1.f + __expf(-fabsf(v)));
        sDl[SPAD(p)] = dl;
        sDlx[SPAD(p)] = dl * xptr[p];
    }
    __syncthreads();

    int p0, dp;
    if (k == 0)      { p0 = c * 64;        dp = 1;   }
    else if (k == 1) { p0 = c;             dp = 64;  }
    else if (k == 2) { p0 = 4095 - c * 64; dp = -1;  }
    else             { p0 = 4095 - c;      dp = -64; }
    long rstep = (long)dp * 36;

    // phase 1: local chunk scan, 4-deep batched loads, 4 states in registers
    float h0 = 0.f, h1 = 0.f, h2 = 0.f, h3 = 0.f;
    float P0 = 1.f, P1 = 1.f, P2 = 1.f, P3 = 1.f;
    {
        int p = p0;
        const float* rB = pkk + (size_t)p0 * 36 + 4 + s * 4;
        for (int jb = 0; jb < 64; jb += 4) {
            float4 Bv[4]; float dlv[4], dxv[4];
            #pragma unroll
            for (int u = 0; u < 4; ++u) {
                Bv[u] = *(const float4*)(rB + u * rstep);
                int q = SPAD(p + u * dp);
                dlv[u] = sDl[q]; dxv[u] = sDlx[q];
            }
            #pragma unroll
            for (int u = 0; u < 4; ++u) {
                float e0 = __expf(dlv[u] * a0), e1 = __expf(dlv[u] * a1);
                float e2 = __expf(dlv[u] * a2), e3 = __expf(dlv[u] * a3);
                h0 = e0 * h0 + dxv[u] * Bv[u].x; P0 *= e0;
                h1 = e1 * h1 + dxv[u] * Bv[u].y; P1 *= e1;
                h2 = e2 * h2 + dxv[u] * Bv[u].z; P2 *= e2;
                h3 = e3 * h3 + dxv[u] * Bv[u].w; P3 *= e3;
            }
            p += 4 * dp; rB += 4 * rstep;
        }
    }
    int base = c * 16 + s * 4;
    sP[base + 0] = P0; sHe[base + 0] = h0;
    sP[base + 1] = P1; sHe[base + 1] = h1;
    sP[base + 2] = P2; sHe[base + 2] = h2;
    sP[base + 3] = P3; sHe[base + 3] = h3;
    __syncthreads();

    // phase 2: Kogge-Stone inclusive scan over chunks (4 states per thread)
    for (int off = 1; off < 64; off <<= 1) {
        float pC[4], hC[4], pL[4] = {0.f,0.f,0.f,0.f}, hL[4] = {0.f,0.f,0.f,0.f};
        #pragma unroll
        for (int u = 0; u < 4; ++u) { pC[u] = sP[base + u]; hC[u] = sHe[base + u]; }
        if (c >= off) {
            #pragma unroll
            for (int u = 0; u < 4; ++u) { pL[u] = sP[base - off * 16 + u]; hL[u] = sHe[base - off * 16 + u]; }
        }
        __syncthreads();
        if (c >= off) {
            #pragma unroll
            for (int u = 0; u < 4; ++u) { sP[base + u] = pC[u] * pL[u]; sHe[base + u] = pC[u] * hL[u] + hC[u]; }
        }
        __syncthreads();
    }

    // phase 3: re-scan with carry (exclusive prefix), emit y
    if (c > 0) {
        h0 = sHe[base - 16 + 0]; h1 = sHe[base - 16 + 1];
        h2 = sHe[base - 16 + 2]; h3 = sHe[base - 16 + 3];
    } else { h0 = h1 = h2 = h3 = 0.f; }
    {
        int p = p0;
        const float* rB = pkk + (size_t)p0 * 36 + 4 + s * 4;
        const float* rC = pkk + (size_t)p0 * 36 + 20 + s * 4;
        for (int jb = 0; jb < 64; jb += 4) {
            float4 Bv[4], Cv[4]; float dlv[4], dxv[4];
            #pragma unroll
            for (int u = 0; u < 4; ++u) {
                Bv[u] = *(const float4*)(rB + u * rstep);
                Cv[u] = *(const float4*)(rC + u * rstep);
                int q = SPAD(p + u * dp);
                dlv[u] = sDl[q]; dxv[u] = sDlx[q];
            }
            #pragma unroll
            for (int u = 0; u < 4; ++u) {
                float e0 = __expf(dlv[u] * a0), e1 = __expf(dlv[u] * a1);
                float e2 = __expf(dlv[u] * a2), e3 = __expf(dlv[u] * a3);
                h0 = e0 * h0 + dxv[u] * Bv[u].x;
                h1 = e1 * h1 + dxv[u] * Bv[u].y;
                h2 = e2 * h2 + dxv[u] * Bv[u].z;
                h3 = e3 * h3 + dxv[u] * Bv[u].w;
                float y = h0 * Cv[u].x + h1 * Cv[u].y + h2 * Cv[u].z + h3 * Cv[u].w;
                y += __shfl_xor(y, 1, 4);
                y += __shfl_xor(y, 2, 4);
                if (s == 0) yptr[p + u * dp] = y;
            }
            p += 4 * dp; rB += 4 * rstep; rC += 4 * rstep;
        }
    }
}

// ---- fused: combine + LN112 + gate + out-proj + residual + LN56; 16-px tiles ----
__global__ void __launch_bounds__(256) k_comb_proj(
        const float* __restrict__ ybuf, const float* __restrict__ xc,
        const float* __restrict__ zbuf, BP Dp, BP ow, BP ob, BP opw,
        const float* __restrict__ xin, BP nw, BP nbv,
        float* __restrict__ x_mid, float* __restrict__ xln) {
    int lane = threadIdx.x & 15;
    int grp = threadIdx.x >> 4;
    int l0 = blockIdx.x * 16;
    __shared__ __align__(16) float sY[112 * 16];
    __shared__ __align__(16) float sW[56 * 112];
    __shared__ float sPa[16][16], sPb[16][16];
    __shared__ float sMu[16], sRs[16];

    float ps = 0.f, ps2 = 0.f;
    for (int d = grp * 7; d < grp * 7 + 7; ++d) {
        float Ds = Dp[d] + Dp[DI + d] + Dp[2 * DI + d] + Dp[3 * DI + d];
        float v = ybuf[(size_t)d * L4 + l0 + lane]
                + ybuf[(size_t)(DI + d) * L4 + l0 + lane]
                + ybuf[(size_t)(2 * DI + d) * L4 + l0 + lane]
                + ybuf[(size_t)(3 * DI + d) * L4 + l0 + lane]
                + Ds * xc[(size_t)d * L4 + l0 + lane];
        sY[d * 16 + lane] = v; ps += v; ps2 += v * v;
    }
    sPa[grp][lane] = ps; sPb[grp][lane] = ps2;
    for (int idx = threadIdx.x; idx < 56 * 112; idx += 256) sW[idx] = opw[idx];
    __syncthreads();
    if (threadIdx.x < 16) {
        float s = 0.f, s2 = 0.f;
        for (int g = 0; g < 16; ++g) { s += sPa[g][lane]; s2 += sPb[g][lane]; }
        float mu = s / 112.f;
        float var = fmaxf(s2 / 112.f - mu * mu, 0.f);
        sMu[lane] = mu; sRs[lane] = rsqrtf(var + 1e-5f);
    }
    __syncthreads();
    {
        float mu = sMu[lane], rs = sRs[lane];
        for (int d = grp * 7; d < grp * 7 + 7; ++d) {
            float v = (sY[d * 16 + lane] - mu) * rs * ow[d] + ob[d];
            float z = zbuf[(size_t)d * L4 + l0 + lane];
            sY[d * 16 + lane] = v * siluf(z);
        }
    }
    __syncthreads();

    float acc[4] = {0.f, 0.f, 0.f, 0.f};
    #pragma unroll 2
    for (int ii = 0; ii < 112; ii += 4) {
        float s0 = sY[(ii + 0) * 16 + lane];
        float s1 = sY[(ii + 1) * 16 + lane];
        float s2 = sY[(ii + 2) * 16 + lane];
        float s3 = sY[(ii + 3) * 16 + lane];
        #pragma unroll
        for (int jj = 0; jj < 4; ++jj) {
            int j = grp * 4 + jj;
            if (j < 56) {
                const float4 wv = *(const float4*)&sW[j * 112 + ii];
                acc[jj] += s0 * wv.x + s1 * wv.y + s2 * wv.z + s3 * wv.w;
            }
        }
    }
    int l = l0 + lane;
    float vout[4];
    float ps3 = 0.f, ps4 = 0.f;
    #pragma unroll
    for (int jj = 0; jj < 4; ++jj) {
        int j = grp * 4 + jj;
        vout[jj] = 0.f;
        if (j < 56) {
            float v = acc[jj] + xin[(size_t)j * L4 + l];
            vout[jj] = v;
            x_mid[(size_t)j * L4 + l] = v;
            ps3 += v; ps4 += v * v;
        }
    }
    __syncthreads();
    sPa[grp][lane] = ps3; sPb[grp][lane] = ps4;
    __syncthreads();
    if (threadIdx.x < 16) {
        float s = 0.f, s2 = 0.f;
        for (int g = 0; g < 16; ++g) { s += sPa[g][lane]; s2 += sPb[g][lane]; }
        float mu = s / 56.f;
        float var = fmaxf(s2 / 56.f - mu * mu, 0.f);
        sMu[lane] = mu; sRs[lane] = rsqrtf(var + 1e-6f);
    }
    __syncthreads();
    {
        float mu = sMu[lane], rs = sRs[lane];
        #pragma unroll
        for (int jj = 0; jj < 4; ++jj) {
            int j = grp * 4 + jj;
            if (j < 56) xln[(size_t)j * L4 + l] = (vout[jj] - mu) * rs * nw[j] + nbv[j];
        }
    }
}

// ---- fused SAFM pools+depthwise: grid 224 (i=0 tiles) + 42 (i>=1 channels) ----
__global__ void __launch_bounds__(256) k_safm(
        const float* __restrict__ xln, BP mw, BP mb,
        float* __restrict__ s0, float* __restrict__ s1,
        float* __restrict__ s2, float* __restrict__ s3) {
    int b = blockIdx.x;
    if (b < 224) {
        int c = b >> 4;
        int tile = b & 15;
        int y0 = (tile >> 2) * 16, x0 = (tile & 3) * 16;
        __shared__ float sT[18 * 18];
        const float* sc = xln + (size_t)c * L4;
        for (int idx = threadIdx.x; idx < 324; idx += 256) {
            int iy = idx / 18, ix = idx - iy * 18;
            int gy = y0 - 1 + iy, gx = x0 - 1 + ix;
            sT[idx] = (gy >= 0 && gy < 64 && gx >= 0 && gx < 64) ? sc[gy * 64 + gx] : 0.f;
        }
        __syncthreads();
        int py = threadIdx.x >> 4, px = threadIdx.x & 15;
        BP wr = mw + c * 9;
        float acc = mb[c];
        #pragma unroll
        for (int ky = 0; ky < 3; ++ky)
            #pragma unroll
            for (int kx = 0; kx < 3; ++kx)
                acc += sT[(py + ky) * 18 + px + kx] * wr[ky * 3 + kx];
        s0[c * L4 + (y0 + py) * 64 + x0 + px] = acc;
    } else {
        int bb = b - 224;
        int i = bb / 14 + 1;
        int c = bb % 14;
        int S = 64 >> i;
        int f = 1 << i;
        __shared__ float sP[34 * 34];
        int W2 = S + 2;
        for (int idx = threadIdx.x; idx < W2 * W2; idx += 256) sP[idx] = 0.f;
        __syncthreads();
        const float* sc = xln + (size_t)(i * 14 + c) * L4;
        for (int cell = threadIdx.x; cell < S * S; cell += 256) {
            int y = cell / S, x = cell - y * S;
            float m = -3.4e38f;
            for (int dy = 0; dy < f; ++dy)
                for (int dx = 0; dx < f; ++dx)
                    m = fmaxf(m, sc[(y * f + dy) * 64 + x * f + dx]);
            sP[(y + 1) * W2 + x + 1] = m;
        }
        __syncthreads();
        BP wr = mw + (i * 14 + c) * 9;
        float bias = mb[i * 14 + c];
        float* dst = (i == 1) ? s1 : (i == 2) ? s2 : s3;
        for (int cell = threadIdx.x; cell < S * S; cell += 256) {
            int y = cell / S, x = cell - y * S;
            float acc = bias;
            #pragma unroll
            for (int ky = 0; ky < 3; ++ky)
                #pragma unroll
                for (int kx = 0; kx < 3; ++kx)
                    acc += sP[(y + ky) * W2 + x + kx] * wr[ky * 3 + kx];
            dst[c * S * S + cell] = acc;
        }
    }
}

// ---- SAFM aggregate 1x1 + gelu gate + residual, writes trunk slice ----
__global__ void k_aggr(const float* __restrict__ s0, const float* __restrict__ s1,
                       const float* __restrict__ s2, const float* __restrict__ s3,
                       const float* __restrict__ xln, const float* __restrict__ x_mid,
                       BP aw, BP ab, float* __restrict__ out) {
    int tid = blockIdx.x * blockDim.x + threadIdx.x;
    if (tid >= CC * L4) return;
    int c = tid >> 12, l = tid & 4095;
    int h = l >> 6, w = l & 63;
    int o1 = (h >> 1) * 32 + (w >> 1);
    int o2 = (h >> 2) * 16 + (w >> 2);
    int o3 = (h >> 3) * 8 + (w >> 3);
    float acc = bf(ab, c);
    BP wr = aw + c * 56;
    for (int cg = 0; cg < 14; ++cg) acc += s0[cg * 4096 + l]  * bf(wr, cg);
    for (int cg = 0; cg < 14; ++cg) acc += s1[cg * 1024 + o1] * bf(wr, 14 + cg);
    for (int cg = 0; cg < 14; ++cg) acc += s2[cg * 256 + o2]  * bf(wr, 28 + cg);
    for (int cg = 0; cg < 14; ++cg) acc += s3[cg * 64 + o3]   * bf(wr, 42 + cg);
    out[tid] = x_mid[tid] + geluf(acc) * xln[tid];
}

// ---- up conv 3x3 (56->27) + pixel shuffle x3, LDS-staged, fp32 output ----
__global__ void __launch_bounds__(256) k_up(
        const float* __restrict__ out_lr, BP uw, BP ub, float* __restrict__ out) {
    __shared__ float sIn[56 * 36];
    __shared__ float sW[27 * 56 * 9];
    int b = blockIdx.x;
    int y0 = (b >> 4) * 4, x0 = (b & 15) * 4;
    for (int idx = threadIdx.x; idx < 56 * 36; idx += 256) {
        int cc = idx / 36; int rem = idx - cc * 36; int iy = rem / 6, ix = rem - iy * 6;
        int gy = y0 - 1 + iy, gx = x0 - 1 + ix;
        sIn[idx] = (gy >= 0 && gy < 64 && gx >= 0 && gx < 64)
                 ? out_lr[(size_t)cc * L4 + gy * 64 + gx] : 0.f;
    }
    for (int idx = threadIdx.x; idx < 27 * 56 * 9; idx += 256) sW[idx] = uw[idx];
    __syncthreads();
    int px = threadIdx.x & 15;
    int og = threadIdx.x >> 4;
    int dy = px >> 2, dx = px & 3;
    for (int oo = 0; oo < 2; ++oo) {
        int o = og * 2 + oo;
        if (o >= 27) break;
        float acc = ub[o];
        const float* wb = &sW[o * 504];
        for (int cc = 0; cc < 56; ++cc) {
            const float* ib = &sIn[cc * 36 + dy * 6 + dx];
            const float* wc = wb + cc * 9;
            acc += ib[0] * wc[0] + ib[1] * wc[1] + ib[2] * wc[2]
                 + ib[6] * wc[3] + ib[7] * wc[4] + ib[8] * wc[5]
                 + ib[12] * wc[6] + ib[13] * wc[7] + ib[14] * wc[8];
        }
        int h = y0 + dy, wv = x0 + dx;
        int ch = o / 9, rr = (o % 9) / 3, ss = o % 3;
        out[ch * 36864 + (h * 3 + rr) * 192 + (wv * 3 + ss)] = acc;
    }
}

extern "C" void kernel_launch(void* const* d_in, const int* in_sizes, int n_in,
                              void* d_out, int out_size, void* d_ws, size_t ws_size,
                              hipStream_t stream) {
    BP in0  = (BP)d_in[0];
    BP in1  = (BP)d_in[1];
    BP in2  = (BP)d_in[2];
    BP in3  = (BP)d_in[3];
    BP in4  = (BP)d_in[4];
    BP in5  = (BP)d_in[5];
    BP in6  = (BP)d_in[6];
    BP in7  = (BP)d_in[7];
    BP in8  = (BP)d_in[8];
    BP in9  = (BP)d_in[9];
    BP in10 = (BP)d_in[10];
    BP in11 = (BP)d_in[11];
    BP in12 = (BP)d_in[12];
    BP in13 = (BP)d_in[13];
    BP in14 = (BP)d_in[14];
    BP in15 = (BP)d_in[15];
    BP in16 = (BP)d_in[16];
    BP in17 = (BP)d_in[17];
    BP in18 = (BP)d_in[18];
    BP in19 = (BP)d_in[19];
    BP in20 = (BP)d_in[20];
    BP in21 = (BP)d_in[21];
    BP in22 = (BP)d_in[22];
    BP in23 = (BP)d_in[23];
    BP in24 = (BP)d_in[24];
    BP in25 = (BP)d_in[25];
    BP in26 = (BP)d_in[26];
    BP in27 = (BP)d_in[27];
    BP in28 = (BP)d_in[28];
    BP in29 = (BP)d_in[29];
    BP in30 = (BP)d_in[30];
    BP in31 = (BP)d_in[31];

    float* ws = (float*)d_ws;
    float* trunk   = ws; ws += 560 * L4;
    float* out_fea = ws; ws += CC * L4;
    float* t0      = ws; ws += CC * L4;
    float* xz      = ws; ws += 224 * L4;
    float* xc      = ws; ws += DI * L4;
    float* pk      = ws; ws += 4 * 36 * L4;
    float* ybuf    = ws; ws += 4 * DI * L4;
    float* x_mid   = ws; ws += CC * L4;
    float* xln     = ws; ws += CC * L4;
    float* s0      = ws; ws += 14 * 4096;
    float* s1      = ws; ws += 14 * 1024;
    float* s2      = ws; ws += 14 * 256;
    float* s3      = ws; ws += 14 * 64;
    float* part    = ws; ws += 5 * 56 * L4;
    float* gB      = ws; ws += CC * L4;
    float* tbuf    = ws; ws += CC * L4;
    float* out_lr  = ws; ws += CC * L4;

    auto nb256 = [](int n) { return dim3((n + 255) / 256); };
    auto gemm_grid = [](int nout) { return dim3(64, (nout + 15) / 16); };

    // stem
    k_fea_pw<<<nb256(CC * L4), 256, 0, stream>>>(in0, in1, t0);
    k_dw3x3t<<<dim3(CC * 16), 256, 0, stream>>>(t0, in2, in3, out_fea, 0, nullptr);

    for (int nb = 0; nb < NBLK; ++nb) {
        const float* xin = (nb == 0) ? out_fea : trunk + (size_t)(nb - 1) * CC * L4;
        float* xout = trunk + (size_t)nb * CC * L4;
        BP ln1w = in4 + nb * 56,        ln1b = in5 + nb * 56;
        BP ipw  = in6 + nb * 224 * 56;
        BP cw   = in7 + nb * 112 * 9,   cb   = in8 + nb * 112;
        BP xpw  = in9 + nb * 4 * 36 * 112;
        BP dtw  = in10 + nb * 4 * 112 * 4, dtb = in11 + nb * 448;
        BP alog = in12 + nb * 448 * 16, Dp   = in13 + nb * 448;
        BP onw  = in14 + nb * 112,      onb  = in15 + nb * 112;
        BP opw  = in16 + nb * 56 * 112;
        BP nw   = in17 + nb * 56,       nbv  = in18 + nb * 56;
        BP mw   = in19 + nb * 4 * 14 * 9, mb = in20 + nb * 56;
        BP aw   = in21 + nb * 56 * 56,  ab   = in22 + nb * 56;

        k_gemm_ln<<<gemm_grid(224), 256, 0, stream>>>(xin, ln1w, ln1b, ipw, xz, 224);
        k_dw3x3t<<<dim3(DI * 16), 256, 0, stream>>>(xz, cw, cb, xc, 1, nullptr);
        k_xproj<<<dim3(128, 9), 256, 0, stream>>>(xc, xpw, pk);
        k_scan<<<dim3(4 * DI), 256, 0, stream>>>(xc, pk, alog, dtw, dtb, ybuf);
        k_comb_proj<<<dim3(256), 256, 0, stream>>>(ybuf, xc, xz + 112 * L4, Dp, onw, onb, opw,
                                                   xin, nw, nbv, x_mid, xln);
        k_safm<<<dim3(266), 256, 0, stream>>>(xln, mw, mb, s0, s1, s2, s3);
        k_aggr<<<nb256(CC * L4), 256, 0, stream>>>(s0, s1, s2, s3, xln, x_mid, aw, ab, xout);
    }

    // tail
    k_c1<<<dim3(64, 4, 5), 256, 0, stream>>>(trunk, in23, part);
    k_ln56g<<<dim3(64), 256, 0, stream>>>(part, in24, in25, in26, gB);
    k_gemm<<<gemm_grid(56), 256, 0, stream>>>(gB, in27, nullptr, nullptr, tbuf, 56, 56);
    k_dw3x3t<<<dim3(CC * 16), 256, 0, stream>>>(tbuf, in28, in29, out_lr, 0, out_fea);
    k_up<<<dim3(256), 256, 0, stream>>>(out_lr, in30, in31, (float*)d_out);
}